// Round 3
// baseline (753.821 us; speedup 1.0000x reference)
//
#include <hip/hip_runtime.h>
#include <hip/hip_bf16.h>

typedef __hip_bfloat16 bf16;

#define HD 16
#define TK 128
#define KP 20            // attn LDS pitch: 16 dims + 4 pad, keeps float4 16B-aligned
#define CT8 32           // flat_attn8 tile positions per wave-chunk
#define MINIT (-1e30f)

__device__ __forceinline__ float b2f(bf16 v){ return __bfloat162float(v); }
__device__ __forceinline__ float gelu_f(float x){ return 0.5f*x*(1.0f+erff(x*0.70710678118654752f)); }
__device__ __forceinline__ float rdv(const void* p, size_t i, bool bf){
  return bf ? b2f(((const bf16*)p)[i]) : ((const float*)p)[i];
}

// ---------------- dtype detector (proven) ----------------
__global__ void detect_k(const void* __restrict__ x, float* __restrict__ flag){
  if (threadIdx.x == 0 && blockIdx.x == 0){
    const float* xf = (const float*)x;
    const bf16*  xb = (const bf16*)x;
    double sF = 0.0, sB = 0.0;
    for (int i = 0; i < 512; i++){ float v = fabsf(xf[i]);     if (!(v < 1e30f)) v = 1e30f; sF += v; }
    for (int i = 0; i < 1024; i++){ float v = fabsf(b2f(xb[i])); if (!(v < 1e30f)) v = 1e30f; sB += v; }
    float mF = (float)(sF/512.0), mB = (float)(sB/1024.0);
    float dF = fabsf(logf(fmaxf(mF, 1e-30f)));
    float dB = fabsf(logf(fmaxf(mB, 1e-30f)));
    *flag = (dB <= dF) ? 1.0f : 0.0f;
  }
}

// ---------------- input -> fp32 convert (proven) ----------------
__global__ void cvt_k(const void* __restrict__ in, float* __restrict__ out, int n,
                      const float* __restrict__ flagp){
  bool bf = *flagp > 0.5f;
  int i = blockIdx.x*blockDim.x + threadIdx.x;
  if (i < n) out[i] = rdv(in, i, bf);
}

// ---------------- wave-split LayerNorm (proven R18) ----------------
__global__ __launch_bounds__(256) void ln2dw_k(
    const float* __restrict__ x, const void* __restrict__ g,
    const void* __restrict__ b, float* __restrict__ y,
    int C, int HW, const float* __restrict__ flagp)
{
  __shared__ float redS[4][64];
  __shared__ float redQ[4][64];
  bool bf = *flagp > 0.5f;
  int t = threadIdx.x, pix = t & 63, sub = t >> 6;
  int p  = blockIdx.x*64 + pix;
  int bb = blockIdx.y;
  const float* xb = x + (size_t)bb*C*HW + p;
  float xv[32];
  float s = 0.f, s2 = 0.f;
  #pragma unroll
  for (int i = 0; i < 32; i++){
    float v = xb[(size_t)(sub*32 + i)*HW];
    xv[i] = v; s += v; s2 += v*v;
  }
  redS[sub][pix] = s; redQ[sub][pix] = s2;
  __syncthreads();
  float st = redS[0][pix] + redS[1][pix] + redS[2][pix] + redS[3][pix];
  float qt = redQ[0][pix] + redQ[1][pix] + redQ[2][pix] + redQ[3][pix];
  float mu  = st / (float)C;
  float var = fmaxf(qt / (float)C - mu*mu, 0.f);
  float inv = rsqrtf(var + 1e-5f);
  float* yb = y + (size_t)bb*C*HW + p;
  #pragma unroll
  for (int i = 0; i < 32; i++){
    int c = sub*32 + i;
    yb[(size_t)c*HW] = (xv[i] - mu)*inv*rdv(g, c, bf) + rdv(b, c, bf);
  }
}

// ---------------- K pre-normalization: k <- k/max(||k||,eps), per 16-dim head group ----------------
__global__ void normk_k(float* __restrict__ KV, long kbs, int koff, int NK){
  int p = blockIdx.x*blockDim.x + threadIdx.x;
  if (p >= NK) return;
  int h = blockIdx.y, bb = blockIdx.z;
  float* base = KV + (size_t)bb*kbs + (size_t)(koff + h*16)*NK + p;
  float v[16]; float s = 0.f;
  #pragma unroll
  for (int d = 0; d < 16; d++){ v[d] = base[(size_t)d*NK]; s += v[d]*v[d]; }
  float iv = 1.f / fmaxf(sqrtf(s), 1e-12f);
  #pragma unroll
  for (int d = 0; d < 16; d++) base[(size_t)d*NK] = v[d]*iv;
}

// ---------------- generic scalar 1x1 conv (proven; small NP cases) ----------------
__global__ void conv1x1_k(const float* __restrict__ in1, long in1_bs, int C1,
                          const float* __restrict__ in2, long in2_bs, int C2,
                          const void* __restrict__ w, const void* __restrict__ bias,
                          const float* __restrict__ res,
                          void* __restrict__ out, int to_out, int O, int NP, int act,
                          const float* __restrict__ flagp){
  bool bf = *flagp > 0.5f;
  int p = blockIdx.x*blockDim.x + threadIdx.x;
  if (p >= NP) return;
  int o = blockIdx.y, bb = blockIdx.z;
  size_t wrow = (size_t)o*(C1 + C2);
  float acc = bias ? rdv(bias, o, bf) : 0.f;
  const float* i1 = in1 + (size_t)bb*in1_bs + p;
  for (int c = 0; c < C1; c++) acc += rdv(w, wrow + c, bf) * i1[(size_t)c*NP];
  if (in2){
    const float* i2 = in2 + (size_t)bb*in2_bs + p;
    for (int c = 0; c < C2; c++) acc += rdv(w, wrow + C1 + c, bf) * i2[(size_t)c*NP];
  }
  if (act == 1) acc = gelu_f(acc);
  if (res) acc += res[((size_t)bb*O + o)*NP + p];
  size_t oi = ((size_t)bb*O + o)*NP + p;
  if (to_out){
    if (bf) ((bf16*)out)[oi] = __float2bfloat16(acc);
    else    ((float*)out)[oi] = acc;
  } else {
    ((float*)out)[oi] = acc;
  }
}

// ---------------- LDS-tiled conv GEMM (proven R17/R18 form) ----------------
__global__ __launch_bounds__(256) void convtile_k(
    const float* __restrict__ in1, long in1_bs, int C1,
    const float* __restrict__ in2, long in2_bs, int C2,
    const void* __restrict__ w, const void* __restrict__ bias,
    const float* __restrict__ res, void* __restrict__ out, int to_out,
    int O, int NP, int act, const float* __restrict__ flagp)
{
  __shared__ __align__(16) float Xs[128*64];
  __shared__ __align__(16) float Wt[128*64];
  bool bf = *flagp > 0.5f;
  int tid = threadIdx.x;
  int p0 = blockIdx.x*64, o0 = blockIdx.y*64, bb = blockIdx.z;
  int CW = C1 + C2;
  int to = (tid >> 4)*4;
  int tp = (tid & 15)*4;
  float a[4][4];
  #pragma unroll
  for (int k = 0; k < 4; k++)
    #pragma unroll
    for (int j = 0; j < 4; j++) a[k][j] = 0.f;
  for (int cc = 0; cc < CW; cc += 128){
    for (int idx = tid; idx < 128*64; idx += 256){
      int c = idx >> 6, j = idx & 63;
      int gc = cc + c;
      float v;
      if (gc < C1) v = in1[(size_t)bb*in1_bs + (size_t)gc*NP + p0 + j];
      else         v = in2[(size_t)bb*in2_bs + (size_t)(gc - C1)*NP + p0 + j];
      Xs[idx] = v;
    }
    for (int idx = tid; idx < 128*64; idx += 256){
      int c = idx >> 6, i = idx & 63;
      Wt[idx] = rdv(w, (size_t)(o0 + i)*CW + cc + c, bf);
    }
    __syncthreads();
    for (int c = 0; c < 128; c++){
      float4 wv = *(const float4*)&Wt[c*64 + to];
      float4 xv = *(const float4*)&Xs[c*64 + tp];
      a[0][0] += wv.x*xv.x; a[0][1] += wv.x*xv.y; a[0][2] += wv.x*xv.z; a[0][3] += wv.x*xv.w;
      a[1][0] += wv.y*xv.x; a[1][1] += wv.y*xv.y; a[1][2] += wv.y*xv.z; a[1][3] += wv.y*xv.w;
      a[2][0] += wv.z*xv.x; a[2][1] += wv.z*xv.y; a[2][2] += wv.z*xv.z; a[2][3] += wv.z*xv.w;
      a[3][0] += wv.w*xv.x; a[3][1] += wv.w*xv.y; a[3][2] += wv.w*xv.z; a[3][3] += wv.w*xv.w;
    }
    __syncthreads();
  }
  #pragma unroll
  for (int k = 0; k < 4; k++){
    int o = o0 + to + k;
    size_t orow = ((size_t)bb*O + o)*NP + p0 + tp;
    float bv = bias ? rdv(bias, o, bf) : 0.f;
    float v0 = a[k][0] + bv, v1 = a[k][1] + bv, v2 = a[k][2] + bv, v3 = a[k][3] + bv;
    if (act == 1){ v0 = gelu_f(v0); v1 = gelu_f(v1); v2 = gelu_f(v2); v3 = gelu_f(v3); }
    if (res){
      float4 r = *(const float4*)&res[orow];
      v0 += r.x; v1 += r.y; v2 += r.z; v3 += r.w;
    }
    if (to_out && bf){
      bf16* ob = (bf16*)out + orow;
      ob[0] = __float2bfloat16(v0); ob[1] = __float2bfloat16(v1);
      ob[2] = __float2bfloat16(v2); ob[3] = __float2bfloat16(v3);
    } else {
      float4 v; v.x = v0; v.y = v1; v.z = v2; v.w = v3;
      *(float4*)((float*)out + orow) = v;
    }
  }
}

// ---------------- flat cosine attention, 8-wave split-K, 144 queries/block ----------------
// R21: same structure as R20 (grid.x=16 -> 256 blocks = 1/CU uniform; Qpl=2.25).
// Single change: __launch_bounds__(512, 2) — 8 waves/block = 2 waves/SIMD exactly, raising
// the VGPR cap to 256. R20's (512) default capped at 76 VGPRs and the ~146 live floats
// (qn[3][16]+acc[3][16]+temps) were AGPR-spilled: measured VALU cycles were 2.0x the useful
// instruction count (accvgpr_read/write around every accumulate). No spill -> LDS-pipe-bound
// (~18.4K b128 broadcasts/CU x ~12cyc ~= 92us floor).
// Hard requirement: NQ == 2304, NK % 256 == 0 (local attn only).
__global__ __launch_bounds__(512, 2) void flat_attn8_k(
    const float* __restrict__ Q, long qbs, int qoff,
    const float* __restrict__ KV, long kbs, int koff, int voff,
    float* __restrict__ Out, long obs, int NQ, int NK, float scale)
{
  __shared__ __align__(16) float S[2*8*CT8*KP];   // Ks = S[0..5119], Vs = S[5120..10239]
  const int VOF = 8*CT8*KP;
  int t = threadIdx.x, lane = t & 63, wv = t >> 6;   // 8 waves
  int h = blockIdx.y, bb = blockIdx.z;
  int qb = blockIdx.x*144;
  int qidx[3];
  qidx[0] = qb + lane;
  qidx[1] = qb + 64 + lane;
  qidx[2] = qb + 128 + (lane & 15);   // valid output only for lane<16; computed by all lanes
  float qn[3][16]; float acc[3][16]; float lsum[3];
  #pragma unroll
  for (int qq = 0; qq < 3; qq++){
    float s = 0.f;
    #pragma unroll
    for (int d = 0; d < 16; d++){
      qn[qq][d] = Q[(size_t)bb*qbs + (size_t)(qoff + h*16 + d)*NQ + qidx[qq]];
      s += qn[qq][d]*qn[qq][d];
    }
    float inv = scale / fmaxf(sqrtf(s), 1e-12f);
    #pragma unroll
    for (int d = 0; d < 16; d++){ qn[qq][d] *= inv; acc[qq][d] = 0.f; }
    lsum[qq] = 0.f;
  }
  int chunk = NK >> 3;
  const float* kvb = KV + (size_t)bb*kbs;
  for (int t0 = 0; t0 < chunk; t0 += CT8){
    __syncthreads();                       // previous tile fully consumed
    for (int i = t; i < 8*CT8*16; i += 512){
      int w2 = i >> 9;                     // slab
      int r  = i & 511;
      int pos = r & 31, d = r >> 5;
      size_t g = (size_t)(h*16 + d)*NK + (size_t)w2*chunk + t0 + pos;
      S[w2*CT8*KP + pos*KP + d]       = kvb[(size_t)koff*NK + g];
      S[VOF + w2*CT8*KP + pos*KP + d] = kvb[(size_t)voff*NK + g];
    }
    __syncthreads();
    const float* ks = &S[wv*CT8*KP];
    const float* vs = &S[VOF + wv*CT8*KP];
    for (int p2 = 0; p2 < CT8; p2++){
      float4 a  = *(const float4*)&ks[p2*KP];
      float4 b4 = *(const float4*)&ks[p2*KP + 4];
      float4 c4 = *(const float4*)&ks[p2*KP + 8];
      float4 d4 = *(const float4*)&ks[p2*KP + 12];
      float4 va = *(const float4*)&vs[p2*KP];
      float4 vb = *(const float4*)&vs[p2*KP + 4];
      float4 vc = *(const float4*)&vs[p2*KP + 8];
      float4 vd = *(const float4*)&vs[p2*KP + 12];
      #pragma unroll
      for (int qq = 0; qq < 3; qq++){
        float dot = qn[qq][0]*a.x  + qn[qq][1]*a.y  + qn[qq][2]*a.z  + qn[qq][3]*a.w
                  + qn[qq][4]*b4.x + qn[qq][5]*b4.y + qn[qq][6]*b4.z + qn[qq][7]*b4.w
                  + qn[qq][8]*c4.x + qn[qq][9]*c4.y + qn[qq][10]*c4.z+ qn[qq][11]*c4.w
                  + qn[qq][12]*d4.x+ qn[qq][13]*d4.y+ qn[qq][14]*d4.z+ qn[qq][15]*d4.w;
        float pp = __expf(dot);            // K pre-normalized: dot IS the logit
        lsum[qq] += pp;
        acc[qq][0] += pp*va.x; acc[qq][1] += pp*va.y; acc[qq][2] += pp*va.z; acc[qq][3] += pp*va.w;
        acc[qq][4] += pp*vb.x; acc[qq][5] += pp*vb.y; acc[qq][6] += pp*vb.z; acc[qq][7] += pp*vb.w;
        acc[qq][8] += pp*vc.x; acc[qq][9] += pp*vc.y; acc[qq][10]+= pp*vc.z; acc[qq][11]+= pp*vc.w;
        acc[qq][12]+= pp*vd.x; acc[qq][13]+= pp*vd.y; acc[qq][14]+= pp*vd.z; acc[qq][15]+= pp*vd.w;
      }
    }
  }
  // combine 8 wave-partials per query group: 3 rounds through LDS (512 slots * 17 <= 10240)
  __syncthreads();
  #pragma unroll
  for (int qq = 0; qq < 3; qq++){
    int slot = wv*64 + lane;
    #pragma unroll
    for (int d = 0; d < 16; d++) S[slot*17 + d] = acc[qq][d];
    S[slot*17 + 16] = lsum[qq];
    __syncthreads();
    if (wv == qq && (qq < 2 || lane < 16)){
      float lt = 0.f; float at[16];
      #pragma unroll
      for (int d = 0; d < 16; d++) at[d] = 0.f;
      #pragma unroll
      for (int w2 = 0; w2 < 8; w2++){
        const float* p0 = &S[(w2*64 + lane)*17];
        lt += p0[16];
        #pragma unroll
        for (int d = 0; d < 16; d++) at[d] += p0[d];
      }
      float li = 1.f / fmaxf(lt, 1e-30f);
      int qi = qidx[qq];
      #pragma unroll
      for (int d = 0; d < 16; d++)
        Out[(size_t)bb*obs + (size_t)(h*16 + d)*NQ + qi] = at[d]*li;
    }
    __syncthreads();
  }
}

// ---------------- attn4, no-max (global attn NK=144 and xw attention NK=16) ----------------
__global__ __launch_bounds__(256) void attn4_k(
    const float* __restrict__ Q, long qbs, int qoff,
    const float* __restrict__ KV, long kbs, int koff, int voff,
    float* __restrict__ Out, long obs, int NQ, int NK, float scale)
{
  __shared__ __align__(16) float Ks[TK*KP];
  __shared__ __align__(16) float Vs[TK*KP];
  int tid = threadIdx.x;
  int sub = tid & 3;
  int h = blockIdx.y, bb = blockIdx.z;
  int qi = blockIdx.x*64 + (tid >> 2);
  bool qv = qi < NQ;
  float qn[4] = {0,0,0,0}, acc[4] = {0,0,0,0};
  float l = 0.f;
  if (qv){
    float s = 0.f;
    #pragma unroll
    for (int j = 0; j < 4; j++){
      qn[j] = Q[(size_t)bb*qbs + (size_t)(qoff + h*16 + sub*4 + j)*NQ + qi];
      s += qn[j]*qn[j];
    }
    s += __shfl_xor(s, 1); s += __shfl_xor(s, 2);
    float inv = scale / fmaxf(sqrtf(s), 1e-12f);
    #pragma unroll
    for (int j = 0; j < 4; j++) qn[j] *= inv;
  }
  for (int k0 = 0; k0 < NK; k0 += TK){
    int lim = min(TK, NK - k0);
    for (int i = tid; i < 16*TK; i += 256){
      int pos = i & (TK-1), d = i >> 7;
      if (pos < lim){
        Ks[pos*KP + d] = KV[(size_t)bb*kbs + (size_t)(koff + h*16 + d)*NK + k0 + pos];
        Vs[pos*KP + d] = KV[(size_t)bb*kbs + (size_t)(voff + h*16 + d)*NK + k0 + pos];
      }
    }
    __syncthreads();
    for (int pos = 0; pos < lim; pos++){
      float4 k4 = *(const float4*)&Ks[pos*KP + sub*4];
      float dd = qn[0]*k4.x + qn[1]*k4.y + qn[2]*k4.z + qn[3]*k4.w;
      dd += __shfl_xor(dd, 1); dd += __shfl_xor(dd, 2);
      float pp = __expf(dd);
      l += pp;
      float4 v4 = *(const float4*)&Vs[pos*KP + sub*4];
      acc[0] += pp*v4.x;
      acc[1] += pp*v4.y;
      acc[2] += pp*v4.z;
      acc[3] += pp*v4.w;
    }
    __syncthreads();
  }
  if (qv){
    float li = 1.f / fmaxf(l, 1e-30f);
    #pragma unroll
    for (int j = 0; j < 4; j++)
      Out[(size_t)bb*obs + (size_t)(h*16 + sub*4 + j)*NQ + qi] = acc[j]*li;
  }
}

// ---------------- latent-read attention, split-K partials ----------------
__global__ void latpart_k(const float* __restrict__ ql, const float* __restrict__ kvx,
                          long kbs, float* __restrict__ part, int NK, int S){
  int s = blockIdx.x, h = blockIdx.y, bb = blockIdx.z;
  int t = threadIdx.x;
  int q = t & 15, sub = (t >> 4) & 3;
  float qn[16]; float ss = 0.f;
  #pragma unroll
  for (int d = 0; d < 16; d++){
    qn[d] = ql[(size_t)bb*2048 + (size_t)(h*16+d)*16 + q];
    ss += qn[d]*qn[d];
  }
  float inv = 0.25f / fmaxf(sqrtf(ss), 1e-12f);
  #pragma unroll
  for (int d = 0; d < 16; d++) qn[d] *= inv;
  float l = 0.f, acc[16];
  #pragma unroll
  for (int d = 0; d < 16; d++) acc[d] = 0.f;
  int chunk = NK / S, c4 = chunk >> 2;
  int k0 = s*chunk + sub*c4, k1 = k0 + c4;
  const float* kb = kvx + (size_t)bb*kbs;
  for (int pos = k0; pos < k1; pos++){
    float dot = 0.f;
    #pragma unroll
    for (int d = 0; d < 16; d++) dot += qn[d]*kb[(size_t)(h*16+d)*NK + pos];
    float pp = __expf(dot);
    l += pp;
    #pragma unroll
    for (int d = 0; d < 16; d++)
      acc[d] += pp*kb[(size_t)(128 + h*16+d)*NK + pos];
  }
  l += __shfl_xor(l, 16); l += __shfl_xor(l, 32);
  #pragma unroll
  for (int d = 0; d < 16; d++){
    acc[d] += __shfl_xor(acc[d], 16);
    acc[d] += __shfl_xor(acc[d], 32);
  }
  if ((t >> 4) == 0){
    size_t idx = (size_t)((((bb*8 + h)*16 + q)*S) + s)*18;
    part[idx] = l;
    #pragma unroll
    for (int d = 0; d < 16; d++) part[idx+1+d] = acc[d];
  }
}

__global__ void latcomb_k(const float* __restrict__ part, float* __restrict__ latr, int S){
  int t = threadIdx.x;
  int q = t & 15, h = (t >> 4) & 7, bb = t >> 7;
  size_t base = (size_t)(((bb*8 + h)*16 + q)*S)*18;
  float L = 0.f, acc[16];
  #pragma unroll
  for (int d = 0; d < 16; d++) acc[d] = 0.f;
  for (int s = 0; s < S; s++){
    const float* ps = part + base + (size_t)s*18;
    L += ps[0];
    #pragma unroll
    for (int d = 0; d < 16; d++) acc[d] += ps[1+d];
  }
  float li = 1.f / fmaxf(L, 1e-30f);
  #pragma unroll
  for (int d = 0; d < 16; d++)
    latr[(size_t)bb*2048 + (size_t)(h*16+d)*16 + q] = acc[d]*li;
}

// ---------------- 4x4 mean pool (proven) ----------------
__global__ void pool4_k(const float* __restrict__ xn, float* __restrict__ xc){
  int i = blockIdx.x*blockDim.x + threadIdx.x;
  if (i >= 2*128*144) return;
  int pc = i % 144; int bc = i / 144;
  int hc = pc / 12, wc = pc % 12;
  const float* s = xn + (size_t)bc*2304 + hc*4*48 + wc*4;
  float acc = 0.f;
  #pragma unroll
  for (int r = 0; r < 4; r++)
    #pragma unroll
    for (int c2 = 0; c2 < 4; c2++) acc += s[r*48 + c2];
  xc[i] = acc * 0.0625f;
}

// ---------------- bilinear upsample 12->48 (proven) ----------------
__global__ void ups_k(const float* __restrict__ g, float* __restrict__ out){
  int i = blockIdx.x*blockDim.x + threadIdx.x;
  if (i >= 2*128*2304) return;
  int p = i % 2304; int bc = i / 2304;
  int h = p / 48, w = p % 48;
  float sh = h*0.25f - 0.375f;
  float sw = w*0.25f - 0.375f;
  float fh0 = floorf(sh), fw0 = floorf(sw);
  float fh = sh - fh0, fw = sw - fw0;
  int h0 = (int)fh0, w0 = (int)fw0;
  int h0c = min(11, max(0, h0)),   h1c = min(11, max(0, h0+1));
  int w0c = min(11, max(0, w0)),   w1c = min(11, max(0, w0+1));
  const float* s = g + (size_t)bc*144;
  float v00 = s[h0c*12 + w0c], v01 = s[h0c*12 + w1c];
  float v10 = s[h1c*12 + w0c], v11 = s[h1c*12 + w1c];
  out[i] = (1.f-fh)*((1.f-fw)*v00 + fw*v01) + fh*((1.f-fw)*v10 + fw*v11);
}

extern "C" void kernel_launch(void* const* d_in, const int* in_sizes, int n_in,
                              void* d_out, int out_size, void* d_ws, size_t ws_size,
                              hipStream_t stream){
  const int B = 2, C = 128, HW = 2304;
  const void* x_in        = d_in[0];
  const void* g1          = d_in[1];
  const void* b1          = d_in[2];
  const void* loc_qkv_w   = d_in[3];
  const void* loc_proj_w  = d_in[4];
  const void* loc_proj_b  = d_in[5];
  const void* glob_qkv_w  = d_in[6];
  const void* glob_proj_w = d_in[7];
  const void* glob_proj_b = d_in[8];
  const void* fuse_w1     = d_in[9];
  const void* fuse_b1     = d_in[10];
  const void* fuse_w2     = d_in[11];
  const void* fuse_b2     = d_in[12];
  const void* glat        = d_in[13];
  const void* blat        = d_in[14];
  const void* latents     = d_in[15];
  const void* qlat_w      = d_in[16];
  const void* kvx_w       = d_in[17];
  const void* qx_w        = d_in[18];
  const void* kvlat_w     = d_in[19];
  const void* lat_proj_w  = d_in[20];
  const void* lat_proj_b  = d_in[21];
  const void* g2          = d_in[22];
  const void* b2          = d_in[23];
  const void* ffn_w1      = d_in[24];
  const void* ffn_b1      = d_in[25];
  const void* ffn_w2      = d_in[26];
  const void* ffn_b2      = d_in[27];

  // ---- workspace layout VERBATIM (R8..R18) ----
  float* ws = (float*)d_ws;
  float* P  = ws + 0;
  float* N  = ws + 589824;
  float* A  = ws + 1179648;
  float* Q  = ws + 1769472;
  float* FLAG = ws + 4128768;

  float* qkv   = Q;                 // 1,769,472
  float* L     = Q + 1769472;       // 589,824
  float* xc    = Q;
  float* qkvc  = Q + 36864;
  float* gatt  = Q + 147456;
  float* gproj = Q + 184320;
  float* kvx   = Q;                 // 1,179,648
  float* latf  = Q + 1179648;
  float* qlat  = Q + 1181696;
  float* latr  = Q + 1185792;
  float* kvlat = Q + 1189888;
  float* part  = Q + 1198080;       // 221,184 (S=48)
  float* ffh   = Q;                 // 2,359,296

  dim3 blk(256);
  dim3 blk512(512);

  detect_k<<<1, 64, 0, stream>>>(x_in, FLAG);
  cvt_k<<<2304, blk, 0, stream>>>(x_in, P, 589824, FLAG);

  // ---- BioAttentionFusion branch ----
  ln2dw_k<<<dim3(36,B), blk, 0, stream>>>(P, g1, b1, N, C, HW, FLAG);
  convtile_k<<<dim3(36,6,B), blk, 0, stream>>>(N,(long)C*HW,C, nullptr,0,0, loc_qkv_w,nullptr,nullptr, qkv,0,384,HW,0, FLAG);
  normk_k<<<dim3(9,8,B), blk, 0, stream>>>(qkv, (long)384*HW, 128, HW);
  flat_attn8_k<<<dim3(16,8,B), blk512, 0, stream>>>(qkv,(long)384*HW,0, qkv,(long)384*HW,128,256, A,(long)C*HW, HW,HW,0.25f);
  convtile_k<<<dim3(36,2,B), blk, 0, stream>>>(A,(long)C*HW,C, nullptr,0,0, loc_proj_w,loc_proj_b,nullptr, L,0,C,HW,0, FLAG);
  pool4_k<<<144, blk, 0, stream>>>(N, xc);
  conv1x1_k<<<dim3(1,384,B), blk, 0, stream>>>(xc,(long)C*144,C, nullptr,0,0, glob_qkv_w,nullptr,nullptr, qkvc,0,384,144,0, FLAG);
  normk_k<<<dim3(1,8,B), blk, 0, stream>>>(qkvc, (long)384*144, 128, 144);
  attn4_k<<<dim3(3,8,B), blk, 0, stream>>>(qkvc,(long)384*144,0, qkvc,(long)384*144,128,256, gatt,(long)C*144, 144,144,0.25f);
  conv1x1_k<<<dim3(1,128,B), blk, 0, stream>>>(gatt,(long)C*144,C, nullptr,0,0, glob_proj_w,glob_proj_b,nullptr, gproj,0,C,144,0, FLAG);
  ups_k<<<2304, blk, 0, stream>>>(gproj, A);                                          // A = upsampled global
  convtile_k<<<dim3(36,2,B), blk, 0, stream>>>(L,(long)C*HW,C, A,(long)C*HW,C, fuse_w1,fuse_b1,nullptr, N,0,C,HW,1, FLAG);  // N = gelu(fuse1)
  convtile_k<<<dim3(36,2,B), blk, 0, stream>>>(N,(long)C*HW,C, nullptr,0,0, fuse_w2,fuse_b2,P, P,0,C,HW,0, FLAG);           // P = x + f

  // ---- LatentMixer branch ----
  ln2dw_k<<<dim3(36,B), blk, 0, stream>>>(P, glat, blat, N, C, HW, FLAG);
  convtile_k<<<dim3(36,4,B), blk, 0, stream>>>(N,(long)C*HW,C, nullptr,0,0, kvx_w,nullptr,nullptr, kvx,0,256,HW,0, FLAG);
  normk_k<<<dim3(9,8,B), blk, 0, stream>>>(kvx, (long)256*HW, 0, HW);
  convtile_k<<<dim3(36,2,B), blk, 0, stream>>>(N,(long)C*HW,C, nullptr,0,0, qx_w,nullptr,nullptr, A,0,C,HW,0, FLAG);        // A = qx
  cvt_k<<<8, blk, 0, stream>>>(latents, latf, 2048, FLAG);
  conv1x1_k<<<dim3(1,128,B), blk, 0, stream>>>(latf,0L,C, nullptr,0,0, qlat_w,nullptr,nullptr, qlat,0,C,16,0, FLAG);
  latpart_k<<<dim3(48,8,B), 64, 0, stream>>>(qlat, kvx, (long)256*HW, part, HW, 48);
  latcomb_k<<<1, blk, 0, stream>>>(part, latr, 48);
  conv1x1_k<<<dim3(1,256,B), blk, 0, stream>>>(latr,(long)C*16,C, nullptr,0,0, kvlat_w,nullptr,nullptr, kvlat,0,256,16,0, FLAG);
  normk_k<<<dim3(1,8,B), blk, 0, stream>>>(kvlat, (long)256*16, 0, 16);
  attn4_k<<<dim3(36,8,B), blk, 0, stream>>>(A,(long)C*HW,0, kvlat,(long)256*16,0,128, N,(long)C*HW, HW,16,0.25f);           // N = xw
  convtile_k<<<dim3(36,2,B), blk, 0, stream>>>(N,(long)C*HW,C, nullptr,0,0, lat_proj_w,lat_proj_b,P, P,0,C,HW,0, FLAG);     // P = x2

  // ---- FFN branch ----
  ln2dw_k<<<dim3(36,B), blk, 0, stream>>>(P, g2, b2, N, C, HW, FLAG);
  convtile_k<<<dim3(36,8,B), blk, 0, stream>>>(N,(long)C*HW,C, nullptr,0,0, ffn_w1,ffn_b1,nullptr, ffh,0,512,HW,1, FLAG);
  convtile_k<<<dim3(36,2,B), blk, 0, stream>>>(ffh,(long)512*HW,512, nullptr,0,0, ffn_w2,ffn_b2,P, d_out,1,C,HW,0, FLAG);
}

// Round 4
// 641.174 us; speedup vs baseline: 1.1757x; 1.1757x over previous
//
#include <hip/hip_runtime.h>
#include <hip/hip_bf16.h>

typedef __hip_bfloat16 bf16;
typedef _Float16 f16;
typedef _Float16 f16x4 __attribute__((ext_vector_type(4)));
typedef float f32x4 __attribute__((ext_vector_type(4)));

#define HD 16
#define TK 128
#define KP 20            // attn LDS pitch: 16 dims + 4 pad, keeps float4 16B-aligned
#define MINIT (-1e30f)

__device__ __forceinline__ float b2f(bf16 v){ return __bfloat162float(v); }
__device__ __forceinline__ float gelu_f(float x){ return 0.5f*x*(1.0f+erff(x*0.70710678118654752f)); }
__device__ __forceinline__ float rdv(const void* p, size_t i, bool bf){
  return bf ? b2f(((const bf16*)p)[i]) : ((const float*)p)[i];
}

// ---------------- dtype detector (proven) ----------------
__global__ void detect_k(const void* __restrict__ x, float* __restrict__ flag){
  if (threadIdx.x == 0 && blockIdx.x == 0){
    const float* xf = (const float*)x;
    const bf16*  xb = (const bf16*)x;
    double sF = 0.0, sB = 0.0;
    for (int i = 0; i < 512; i++){ float v = fabsf(xf[i]);     if (!(v < 1e30f)) v = 1e30f; sF += v; }
    for (int i = 0; i < 1024; i++){ float v = fabsf(b2f(xb[i])); if (!(v < 1e30f)) v = 1e30f; sB += v; }
    float mF = (float)(sF/512.0), mB = (float)(sB/1024.0);
    float dF = fabsf(logf(fmaxf(mF, 1e-30f)));
    float dB = fabsf(logf(fmaxf(mB, 1e-30f)));
    *flag = (dB <= dF) ? 1.0f : 0.0f;
  }
}

// ---------------- input -> fp32 convert (proven) ----------------
__global__ void cvt_k(const void* __restrict__ in, float* __restrict__ out, int n,
                      const float* __restrict__ flagp){
  bool bf = *flagp > 0.5f;
  int i = blockIdx.x*blockDim.x + threadIdx.x;
  if (i < n) out[i] = rdv(in, i, bf);
}

// ---------------- wave-split LayerNorm (proven R18) ----------------
__global__ __launch_bounds__(256) void ln2dw_k(
    const float* __restrict__ x, const void* __restrict__ g,
    const void* __restrict__ b, float* __restrict__ y,
    int C, int HW, const float* __restrict__ flagp)
{
  __shared__ float redS[4][64];
  __shared__ float redQ[4][64];
  bool bf = *flagp > 0.5f;
  int t = threadIdx.x, pix = t & 63, sub = t >> 6;
  int p  = blockIdx.x*64 + pix;
  int bb = blockIdx.y;
  const float* xb = x + (size_t)bb*C*HW + p;
  float xv[32];
  float s = 0.f, s2 = 0.f;
  #pragma unroll
  for (int i = 0; i < 32; i++){
    float v = xb[(size_t)(sub*32 + i)*HW];
    xv[i] = v; s += v; s2 += v*v;
  }
  redS[sub][pix] = s; redQ[sub][pix] = s2;
  __syncthreads();
  float st = redS[0][pix] + redS[1][pix] + redS[2][pix] + redS[3][pix];
  float qt = redQ[0][pix] + redQ[1][pix] + redQ[2][pix] + redQ[3][pix];
  float mu  = st / (float)C;
  float var = fmaxf(qt / (float)C - mu*mu, 0.f);
  float inv = rsqrtf(var + 1e-5f);
  float* yb = y + (size_t)bb*C*HW + p;
  #pragma unroll
  for (int i = 0; i < 32; i++){
    int c = sub*32 + i;
    yb[(size_t)c*HW] = (xv[i] - mu)*inv*rdv(g, c, bf) + rdv(b, c, bf);
  }
}

// ---------------- K pre-normalization: k <- k/max(||k||,eps), per 16-dim head group ----------------
__global__ void normk_k(float* __restrict__ KV, long kbs, int koff, int NK){
  int p = blockIdx.x*blockDim.x + threadIdx.x;
  if (p >= NK) return;
  int h = blockIdx.y, bb = blockIdx.z;
  float* base = KV + (size_t)bb*kbs + (size_t)(koff + h*16)*NK + p;
  float v[16]; float s = 0.f;
  #pragma unroll
  for (int d = 0; d < 16; d++){ v[d] = base[(size_t)d*NK]; s += v[d]*v[d]; }
  float iv = 1.f / fmaxf(sqrtf(s), 1e-12f);
  #pragma unroll
  for (int d = 0; d < 16; d++) base[(size_t)d*NK] = v[d]*iv;
}

// ---------------- generic scalar 1x1 conv (proven; small NP cases) ----------------
__global__ void conv1x1_k(const float* __restrict__ in1, long in1_bs, int C1,
                          const float* __restrict__ in2, long in2_bs, int C2,
                          const void* __restrict__ w, const void* __restrict__ bias,
                          const float* __restrict__ res,
                          void* __restrict__ out, int to_out, int O, int NP, int act,
                          const float* __restrict__ flagp){
  bool bf = *flagp > 0.5f;
  int p = blockIdx.x*blockDim.x + threadIdx.x;
  if (p >= NP) return;
  int o = blockIdx.y, bb = blockIdx.z;
  size_t wrow = (size_t)o*(C1 + C2);
  float acc = bias ? rdv(bias, o, bf) : 0.f;
  const float* i1 = in1 + (size_t)bb*in1_bs + p;
  for (int c = 0; c < C1; c++) acc += rdv(w, wrow + c, bf) * i1[(size_t)c*NP];
  if (in2){
    const float* i2 = in2 + (size_t)bb*in2_bs + p;
    for (int c = 0; c < C2; c++) acc += rdv(w, wrow + C1 + c, bf) * i2[(size_t)c*NP];
  }
  if (act == 1) acc = gelu_f(acc);
  if (res) acc += res[((size_t)bb*O + o)*NP + p];
  size_t oi = ((size_t)bb*O + o)*NP + p;
  if (to_out){
    if (bf) ((bf16*)out)[oi] = __float2bfloat16(acc);
    else    ((float*)out)[oi] = acc;
  } else {
    ((float*)out)[oi] = acc;
  }
}

// ---------------- LDS-tiled conv GEMM (proven R17/R18 form) ----------------
__global__ __launch_bounds__(256) void convtile_k(
    const float* __restrict__ in1, long in1_bs, int C1,
    const float* __restrict__ in2, long in2_bs, int C2,
    const void* __restrict__ w, const void* __restrict__ bias,
    const float* __restrict__ res, void* __restrict__ out, int to_out,
    int O, int NP, int act, const float* __restrict__ flagp)
{
  __shared__ __align__(16) float Xs[128*64];
  __shared__ __align__(16) float Wt[128*64];
  bool bf = *flagp > 0.5f;
  int tid = threadIdx.x;
  int p0 = blockIdx.x*64, o0 = blockIdx.y*64, bb = blockIdx.z;
  int CW = C1 + C2;
  int to = (tid >> 4)*4;
  int tp = (tid & 15)*4;
  float a[4][4];
  #pragma unroll
  for (int k = 0; k < 4; k++)
    #pragma unroll
    for (int j = 0; j < 4; j++) a[k][j] = 0.f;
  for (int cc = 0; cc < CW; cc += 128){
    for (int idx = tid; idx < 128*64; idx += 256){
      int c = idx >> 6, j = idx & 63;
      int gc = cc + c;
      float v;
      if (gc < C1) v = in1[(size_t)bb*in1_bs + (size_t)gc*NP + p0 + j];
      else         v = in2[(size_t)bb*in2_bs + (size_t)(gc - C1)*NP + p0 + j];
      Xs[idx] = v;
    }
    for (int idx = tid; idx < 128*64; idx += 256){
      int c = idx >> 6, i = idx & 63;
      Wt[idx] = rdv(w, (size_t)(o0 + i)*CW + cc + c, bf);
    }
    __syncthreads();
    for (int c = 0; c < 128; c++){
      float4 wv = *(const float4*)&Wt[c*64 + to];
      float4 xv = *(const float4*)&Xs[c*64 + tp];
      a[0][0] += wv.x*xv.x; a[0][1] += wv.x*xv.y; a[0][2] += wv.x*xv.z; a[0][3] += wv.x*xv.w;
      a[1][0] += wv.y*xv.x; a[1][1] += wv.y*xv.y; a[1][2] += wv.y*xv.z; a[1][3] += wv.y*xv.w;
      a[2][0] += wv.z*xv.x; a[2][1] += wv.z*xv.y; a[2][2] += wv.z*xv.z; a[2][3] += wv.z*xv.w;
      a[3][0] += wv.w*xv.x; a[3][1] += wv.w*xv.y; a[3][2] += wv.w*xv.z; a[3][3] += wv.w*xv.w;
    }
    __syncthreads();
  }
  #pragma unroll
  for (int k = 0; k < 4; k++){
    int o = o0 + to + k;
    size_t orow = ((size_t)bb*O + o)*NP + p0 + tp;
    float bv = bias ? rdv(bias, o, bf) : 0.f;
    float v0 = a[k][0] + bv, v1 = a[k][1] + bv, v2 = a[k][2] + bv, v3 = a[k][3] + bv;
    if (act == 1){ v0 = gelu_f(v0); v1 = gelu_f(v1); v2 = gelu_f(v2); v3 = gelu_f(v3); }
    if (res){
      float4 r = *(const float4*)&res[orow];
      v0 += r.x; v1 += r.y; v2 += r.z; v3 += r.w;
    }
    if (to_out && bf){
      bf16* ob = (bf16*)out + orow;
      ob[0] = __float2bfloat16(v0); ob[1] = __float2bfloat16(v1);
      ob[2] = __float2bfloat16(v2); ob[3] = __float2bfloat16(v3);
    } else {
      float4 v; v.x = v0; v.y = v1; v.z = v2; v.w = v3;
      *(float4*)((float*)out + orow) = v;
    }
  }
}

// ---------------- MFMA flash cosine attention (local attn, d=16) ----------------
// R22: MfmaUtil was 0.0 while VALU burned 248K cyc/SIMD on dot products. Rewrite with
// v_mfma_f32_16x16x16_f16 using the swapped-operand trick: S^T = mfma(A=K[pos,d], B=Q^T[d,q])
// gives C layout (row=pos=(lane>>4)*4+r, col=q=lane&15) == B-fragment layout of the PV MFMA
// (k=pos, n=q) -> P feeds PV with ZERO cross-lane movement. V channel-major == V^T, so the
// PV A-frag is one contiguous float4. No-max softmax (|logit|<=0.25). K pre-normalized.
// Geometry: 64 queries/block (4 q-tiles), 8 waves split NK (NK/8 positions each, 16/step).
// Requirements: NQ % 64 == 0, NK % 128 == 0.
__global__ __launch_bounds__(512) void flat_mfma_k(
    const float* __restrict__ Q, long qbs, int qoff,
    const float* __restrict__ KV, long kbs, int koff, int voff,
    float* __restrict__ Out, long obs, int NQ, int NK, float scale)
{
  __shared__ float OS[8*4*16*17];   // [wave][qt][q][d] pitch 17
  __shared__ float LS[8*4*16];      // [wave][qt][q]
  int t = threadIdx.x, lane = t & 63, wv = t >> 6;
  int h = blockIdx.y, bb = blockIdx.z;
  int qb = blockIdx.x*64;
  int lm = lane & 15, lg = lane >> 4;          // m/n index, k-group
  const float* qp  = Q  + (size_t)bb*qbs;
  const float* kvb = KV + (size_t)bb*kbs;
  // Q B-frags: per q-tile qt, lane holds q = qb+qt*16+lm, d = lg*4+i; normalized * scale
  f16x4 qf[4];
  #pragma unroll
  for (int qt = 0; qt < 4; qt++){
    float qv[4]; float ss = 0.f;
    #pragma unroll
    for (int i = 0; i < 4; i++){
      qv[i] = qp[(size_t)(qoff + h*16 + lg*4 + i)*NQ + qb + qt*16 + lm];
      ss += qv[i]*qv[i];
    }
    ss += __shfl_xor(ss, 16); ss += __shfl_xor(ss, 32);
    float inv = scale / fmaxf(sqrtf(ss), 1e-12f);
    #pragma unroll
    for (int i = 0; i < 4; i++) qf[qt][i] = (f16)(qv[i]*inv);
  }
  f32x4 of[4];
  float ls[4];
  #pragma unroll
  for (int qt = 0; qt < 4; qt++){
    of[qt][0]=0.f; of[qt][1]=0.f; of[qt][2]=0.f; of[qt][3]=0.f; ls[qt]=0.f;
  }
  int chunk = NK >> 3;
  int p0 = wv*chunk, p1 = p0 + chunk;
  const float* kc = kvb + (size_t)(koff + h*16)*NK;
  const float* vc = kvb + (size_t)(voff + h*16)*NK;
  for (int pos = p0; pos < p1; pos += 16){
    // K A-frag: m=pos+lm, k=d=lg*4+i  (4 coalesced 64B row-segments per load)
    f16x4 kf;
    #pragma unroll
    for (int i = 0; i < 4; i++)
      kf[i] = (f16)kc[(size_t)(lg*4 + i)*NK + pos + lm];
    // V^T A-frag: m=d=lm, k=pos+lg*4+i  (contiguous float4)
    float4 vvv = *(const float4*)&vc[(size_t)lm*NK + pos + lg*4];
    f16x4 vf; vf[0]=(f16)vvv.x; vf[1]=(f16)vvv.y; vf[2]=(f16)vvv.z; vf[3]=(f16)vvv.w;
    #pragma unroll
    for (int qt = 0; qt < 4; qt++){
      f32x4 s; s[0]=0.f; s[1]=0.f; s[2]=0.f; s[3]=0.f;
      s = __builtin_amdgcn_mfma_f32_16x16x16f16(kf, qf[qt], s, 0, 0, 0);
      f16x4 pf;
      #pragma unroll
      for (int r = 0; r < 4; r++){
        float pp = __expf(s[r]);       // K unit, Q pre-scaled: s IS the logit
        ls[qt] += pp;
        pf[r] = (f16)pp;
      }
      of[qt] = __builtin_amdgcn_mfma_f32_16x16x16f16(vf, pf, of[qt], 0, 0, 0);
    }
  }
  // combine 8 wave K-split partials through LDS
  #pragma unroll
  for (int qt = 0; qt < 4; qt++){
    ls[qt] += __shfl_xor(ls[qt], 16);
    ls[qt] += __shfl_xor(ls[qt], 32);
    #pragma unroll
    for (int r = 0; r < 4; r++)
      OS[((wv*4 + qt)*16 + lm)*17 + lg*4 + r] = of[qt][r];
    if (lg == 0) LS[(wv*4 + qt)*16 + lm] = ls[qt];
  }
  __syncthreads();
  // 1024 outputs (64 q x 16 d); each thread reduces 2
  #pragma unroll
  for (int rep = 0; rep < 2; rep++){
    int o = t + rep*512;
    int d = o >> 6, qq = o & 63;
    int qt = qq >> 4, q = qq & 15;
    float acc = 0.f, lsum = 0.f;
    #pragma unroll
    for (int w = 0; w < 8; w++){
      acc  += OS[((w*4 + qt)*16 + q)*17 + d];
      lsum += LS[(w*4 + qt)*16 + q];
    }
    Out[(size_t)bb*obs + (size_t)(h*16 + d)*NQ + qb + qq] = acc / fmaxf(lsum, 1e-30f);
  }
}

// ---------------- attn4, no-max (global attn NK=144 and xw attention NK=16) ----------------
__global__ __launch_bounds__(256) void attn4_k(
    const float* __restrict__ Q, long qbs, int qoff,
    const float* __restrict__ KV, long kbs, int koff, int voff,
    float* __restrict__ Out, long obs, int NQ, int NK, float scale)
{
  __shared__ __align__(16) float Ks[TK*KP];
  __shared__ __align__(16) float Vs[TK*KP];
  int tid = threadIdx.x;
  int sub = tid & 3;
  int h = blockIdx.y, bb = blockIdx.z;
  int qi = blockIdx.x*64 + (tid >> 2);
  bool qv = qi < NQ;
  float qn[4] = {0,0,0,0}, acc[4] = {0,0,0,0};
  float l = 0.f;
  if (qv){
    float s = 0.f;
    #pragma unroll
    for (int j = 0; j < 4; j++){
      qn[j] = Q[(size_t)bb*qbs + (size_t)(qoff + h*16 + sub*4 + j)*NQ + qi];
      s += qn[j]*qn[j];
    }
    s += __shfl_xor(s, 1); s += __shfl_xor(s, 2);
    float inv = scale / fmaxf(sqrtf(s), 1e-12f);
    #pragma unroll
    for (int j = 0; j < 4; j++) qn[j] *= inv;
  }
  for (int k0 = 0; k0 < NK; k0 += TK){
    int lim = min(TK, NK - k0);
    for (int i = tid; i < 16*TK; i += 256){
      int pos = i & (TK-1), d = i >> 7;
      if (pos < lim){
        Ks[pos*KP + d] = KV[(size_t)bb*kbs + (size_t)(koff + h*16 + d)*NK + k0 + pos];
        Vs[pos*KP + d] = KV[(size_t)bb*kbs + (size_t)(voff + h*16 + d)*NK + k0 + pos];
      }
    }
    __syncthreads();
    for (int pos = 0; pos < lim; pos++){
      float4 k4 = *(const float4*)&Ks[pos*KP + sub*4];
      float dd = qn[0]*k4.x + qn[1]*k4.y + qn[2]*k4.z + qn[3]*k4.w;
      dd += __shfl_xor(dd, 1); dd += __shfl_xor(dd, 2);
      float pp = __expf(dd);
      l += pp;
      float4 v4 = *(const float4*)&Vs[pos*KP + sub*4];
      acc[0] += pp*v4.x;
      acc[1] += pp*v4.y;
      acc[2] += pp*v4.z;
      acc[3] += pp*v4.w;
    }
    __syncthreads();
  }
  if (qv){
    float li = 1.f / fmaxf(l, 1e-30f);
    #pragma unroll
    for (int j = 0; j < 4; j++)
      Out[(size_t)bb*obs + (size_t)(h*16 + sub*4 + j)*NQ + qi] = acc[j]*li;
  }
}

// ---------------- latent-read attention, split-K partials ----------------
__global__ void latpart_k(const float* __restrict__ ql, const float* __restrict__ kvx,
                          long kbs, float* __restrict__ part, int NK, int S){
  int s = blockIdx.x, h = blockIdx.y, bb = blockIdx.z;
  int t = threadIdx.x;
  int q = t & 15, sub = (t >> 4) & 3;
  float qn[16]; float ss = 0.f;
  #pragma unroll
  for (int d = 0; d < 16; d++){
    qn[d] = ql[(size_t)bb*2048 + (size_t)(h*16+d)*16 + q];
    ss += qn[d]*qn[d];
  }
  float inv = 0.25f / fmaxf(sqrtf(ss), 1e-12f);
  #pragma unroll
  for (int d = 0; d < 16; d++) qn[d] *= inv;
  float l = 0.f, acc[16];
  #pragma unroll
  for (int d = 0; d < 16; d++) acc[d] = 0.f;
  int chunk = NK / S, c4 = chunk >> 2;
  int k0 = s*chunk + sub*c4, k1 = k0 + c4;
  const float* kb = kvx + (size_t)bb*kbs;
  for (int pos = k0; pos < k1; pos++){
    float dot = 0.f;
    #pragma unroll
    for (int d = 0; d < 16; d++) dot += qn[d]*kb[(size_t)(h*16+d)*NK + pos];
    float pp = __expf(dot);
    l += pp;
    #pragma unroll
    for (int d = 0; d < 16; d++)
      acc[d] += pp*kb[(size_t)(128 + h*16+d)*NK + pos];
  }
  l += __shfl_xor(l, 16); l += __shfl_xor(l, 32);
  #pragma unroll
  for (int d = 0; d < 16; d++){
    acc[d] += __shfl_xor(acc[d], 16);
    acc[d] += __shfl_xor(acc[d], 32);
  }
  if ((t >> 4) == 0){
    size_t idx = (size_t)((((bb*8 + h)*16 + q)*S) + s)*18;
    part[idx] = l;
    #pragma unroll
    for (int d = 0; d < 16; d++) part[idx+1+d] = acc[d];
  }
}

__global__ void latcomb_k(const float* __restrict__ part, float* __restrict__ latr, int S){
  int t = threadIdx.x;
  int q = t & 15, h = (t >> 4) & 7, bb = t >> 7;
  size_t base = (size_t)(((bb*8 + h)*16 + q)*S)*18;
  float L = 0.f, acc[16];
  #pragma unroll
  for (int d = 0; d < 16; d++) acc[d] = 0.f;
  for (int s = 0; s < S; s++){
    const float* ps = part + base + (size_t)s*18;
    L += ps[0];
    #pragma unroll
    for (int d = 0; d < 16; d++) acc[d] += ps[1+d];
  }
  float li = 1.f / fmaxf(L, 1e-30f);
  #pragma unroll
  for (int d = 0; d < 16; d++)
    latr[(size_t)bb*2048 + (size_t)(h*16+d)*16 + q] = acc[d]*li;
}

// ---------------- 4x4 mean pool (proven) ----------------
__global__ void pool4_k(const float* __restrict__ xn, float* __restrict__ xc){
  int i = blockIdx.x*blockDim.x + threadIdx.x;
  if (i >= 2*128*144) return;
  int pc = i % 144; int bc = i / 144;
  int hc = pc / 12, wc = pc % 12;
  const float* s = xn + (size_t)bc*2304 + hc*4*48 + wc*4;
  float acc = 0.f;
  #pragma unroll
  for (int r = 0; r < 4; r++)
    #pragma unroll
    for (int c2 = 0; c2 < 4; c2++) acc += s[r*48 + c2];
  xc[i] = acc * 0.0625f;
}

// ---------------- bilinear upsample 12->48 (proven) ----------------
__global__ void ups_k(const float* __restrict__ g, float* __restrict__ out){
  int i = blockIdx.x*blockDim.x + threadIdx.x;
  if (i >= 2*128*2304) return;
  int p = i % 2304; int bc = i / 2304;
  int h = p / 48, w = p % 48;
  float sh = h*0.25f - 0.375f;
  float sw = w*0.25f - 0.375f;
  float fh0 = floorf(sh), fw0 = floorf(sw);
  float fh = sh - fh0, fw = sw - fw0;
  int h0 = (int)fh0, w0 = (int)fw0;
  int h0c = min(11, max(0, h0)),   h1c = min(11, max(0, h0+1));
  int w0c = min(11, max(0, w0)),   w1c = min(11, max(0, w0+1));
  const float* s = g + (size_t)bc*144;
  float v00 = s[h0c*12 + w0c], v01 = s[h0c*12 + w1c];
  float v10 = s[h1c*12 + w0c], v11 = s[h1c*12 + w1c];
  out[i] = (1.f-fh)*((1.f-fw)*v00 + fw*v01) + fh*((1.f-fw)*v10 + fw*v11);
}

extern "C" void kernel_launch(void* const* d_in, const int* in_sizes, int n_in,
                              void* d_out, int out_size, void* d_ws, size_t ws_size,
                              hipStream_t stream){
  const int B = 2, C = 128, HW = 2304;
  const void* x_in        = d_in[0];
  const void* g1          = d_in[1];
  const void* b1          = d_in[2];
  const void* loc_qkv_w   = d_in[3];
  const void* loc_proj_w  = d_in[4];
  const void* loc_proj_b  = d_in[5];
  const void* glob_qkv_w  = d_in[6];
  const void* glob_proj_w = d_in[7];
  const void* glob_proj_b = d_in[8];
  const void* fuse_w1     = d_in[9];
  const void* fuse_b1     = d_in[10];
  const void* fuse_w2     = d_in[11];
  const void* fuse_b2     = d_in[12];
  const void* glat        = d_in[13];
  const void* blat        = d_in[14];
  const void* latents     = d_in[15];
  const void* qlat_w      = d_in[16];
  const void* kvx_w       = d_in[17];
  const void* qx_w        = d_in[18];
  const void* kvlat_w     = d_in[19];
  const void* lat_proj_w  = d_in[20];
  const void* lat_proj_b  = d_in[21];
  const void* g2          = d_in[22];
  const void* b2          = d_in[23];
  const void* ffn_w1      = d_in[24];
  const void* ffn_b1      = d_in[25];
  const void* ffn_w2      = d_in[26];
  const void* ffn_b2      = d_in[27];

  // ---- workspace layout VERBATIM (R8..R18) ----
  float* ws = (float*)d_ws;
  float* P  = ws + 0;
  float* N  = ws + 589824;
  float* A  = ws + 1179648;
  float* Q  = ws + 1769472;
  float* FLAG = ws + 4128768;

  float* qkv   = Q;                 // 1,769,472
  float* L     = Q + 1769472;       // 589,824
  float* xc    = Q;
  float* qkvc  = Q + 36864;
  float* gatt  = Q + 147456;
  float* gproj = Q + 184320;
  float* kvx   = Q;                 // 1,179,648
  float* latf  = Q + 1179648;
  float* qlat  = Q + 1181696;
  float* latr  = Q + 1185792;
  float* kvlat = Q + 1189888;
  float* part  = Q + 1198080;       // 221,184 (S=48)
  float* ffh   = Q;                 // 2,359,296

  dim3 blk(256);
  dim3 blk512(512);

  detect_k<<<1, 64, 0, stream>>>(x_in, FLAG);
  cvt_k<<<2304, blk, 0, stream>>>(x_in, P, 589824, FLAG);

  // ---- BioAttentionFusion branch ----
  ln2dw_k<<<dim3(36,B), blk, 0, stream>>>(P, g1, b1, N, C, HW, FLAG);
  convtile_k<<<dim3(36,6,B), blk, 0, stream>>>(N,(long)C*HW,C, nullptr,0,0, loc_qkv_w,nullptr,nullptr, qkv,0,384,HW,0, FLAG);
  normk_k<<<dim3(9,8,B), blk, 0, stream>>>(qkv, (long)384*HW, 128, HW);
  flat_mfma_k<<<dim3(36,8,B), blk512, 0, stream>>>(qkv,(long)384*HW,0, qkv,(long)384*HW,128,256, A,(long)C*HW, HW,HW,0.25f);
  convtile_k<<<dim3(36,2,B), blk, 0, stream>>>(A,(long)C*HW,C, nullptr,0,0, loc_proj_w,loc_proj_b,nullptr, L,0,C,HW,0, FLAG);
  pool4_k<<<144, blk, 0, stream>>>(N, xc);
  conv1x1_k<<<dim3(1,384,B), blk, 0, stream>>>(xc,(long)C*144,C, nullptr,0,0, glob_qkv_w,nullptr,nullptr, qkvc,0,384,144,0, FLAG);
  normk_k<<<dim3(1,8,B), blk, 0, stream>>>(qkvc, (long)384*144, 128, 144);
  attn4_k<<<dim3(3,8,B), blk, 0, stream>>>(qkvc,(long)384*144,0, qkvc,(long)384*144,128,256, gatt,(long)C*144, 144,144,0.25f);
  conv1x1_k<<<dim3(1,128,B), blk, 0, stream>>>(gatt,(long)C*144,C, nullptr,0,0, glob_proj_w,glob_proj_b,nullptr, gproj,0,C,144,0, FLAG);
  ups_k<<<2304, blk, 0, stream>>>(gproj, A);                                          // A = upsampled global
  convtile_k<<<dim3(36,2,B), blk, 0, stream>>>(L,(long)C*HW,C, A,(long)C*HW,C, fuse_w1,fuse_b1,nullptr, N,0,C,HW,1, FLAG);  // N = gelu(fuse1)
  convtile_k<<<dim3(36,2,B), blk, 0, stream>>>(N,(long)C*HW,C, nullptr,0,0, fuse_w2,fuse_b2,P, P,0,C,HW,0, FLAG);           // P = x + f

  // ---- LatentMixer branch ----
  ln2dw_k<<<dim3(36,B), blk, 0, stream>>>(P, glat, blat, N, C, HW, FLAG);
  convtile_k<<<dim3(36,4,B), blk, 0, stream>>>(N,(long)C*HW,C, nullptr,0,0, kvx_w,nullptr,nullptr, kvx,0,256,HW,0, FLAG);
  normk_k<<<dim3(9,8,B), blk, 0, stream>>>(kvx, (long)256*HW, 0, HW);
  convtile_k<<<dim3(36,2,B), blk, 0, stream>>>(N,(long)C*HW,C, nullptr,0,0, qx_w,nullptr,nullptr, A,0,C,HW,0, FLAG);        // A = qx
  cvt_k<<<8, blk, 0, stream>>>(latents, latf, 2048, FLAG);
  conv1x1_k<<<dim3(1,128,B), blk, 0, stream>>>(latf,0L,C, nullptr,0,0, qlat_w,nullptr,nullptr, qlat,0,C,16,0, FLAG);
  latpart_k<<<dim3(48,8,B), 64, 0, stream>>>(qlat, kvx, (long)256*HW, part, HW, 48);
  latcomb_k<<<1, blk, 0, stream>>>(part, latr, 48);
  conv1x1_k<<<dim3(1,256,B), blk, 0, stream>>>(latr,(long)C*16,C, nullptr,0,0, kvlat_w,nullptr,nullptr, kvlat,0,256,16,0, FLAG);
  normk_k<<<dim3(1,8,B), blk, 0, stream>>>(kvlat, (long)256*16, 0, 16);
  attn4_k<<<dim3(36,8,B), blk, 0, stream>>>(A,(long)C*HW,0, kvlat,(long)256*16,0,128, N,(long)C*HW, HW,16,0.25f);           // N = xw
  convtile_k<<<dim3(36,2,B), blk, 0, stream>>>(N,(long)C*HW,C, nullptr,0,0, lat_proj_w,lat_proj_b,P, P,0,C,HW,0, FLAG);     // P = x2

  // ---- FFN branch ----
  ln2dw_k<<<dim3(36,B), blk, 0, stream>>>(P, g2, b2, N, C, HW, FLAG);
  convtile_k<<<dim3(36,8,B), blk, 0, stream>>>(N,(long)C*HW,C, nullptr,0,0, ffn_w1,ffn_b1,nullptr, ffh,0,512,HW,1, FLAG);
  convtile_k<<<dim3(36,2,B), blk, 0, stream>>>(ffh,(long)512*HW,512, nullptr,0,0, ffn_w2,ffn_b2,P, d_out,1,C,HW,0, FLAG);
}

// Round 5
// 613.009 us; speedup vs baseline: 1.2297x; 1.0459x over previous
//
#include <hip/hip_runtime.h>
#include <hip/hip_bf16.h>

typedef __hip_bfloat16 bf16;
typedef _Float16 f16;
typedef _Float16 f16x4 __attribute__((ext_vector_type(4)));
typedef float f32x4 __attribute__((ext_vector_type(4)));

#define HD 16
#define TK 128
#define KP 20            // attn LDS pitch: 16 dims + 4 pad, keeps float4 16B-aligned
#define MINIT (-1e30f)

__device__ __forceinline__ float b2f(bf16 v){ return __bfloat162float(v); }
__device__ __forceinline__ float gelu_f(float x){ return 0.5f*x*(1.0f+erff(x*0.70710678118654752f)); }
__device__ __forceinline__ float rdv(const void* p, size_t i, bool bf){
  return bf ? b2f(((const bf16*)p)[i]) : ((const float*)p)[i];
}
__device__ __forceinline__ float4 ld4f(const void* p, size_t i, bool bf){
  if (bf){
    const bf16* q = (const bf16*)p + i;
    return make_float4(b2f(q[0]), b2f(q[1]), b2f(q[2]), b2f(q[3]));
  }
  return *(const float4*)((const float*)p + i);
}

// ---------------- dtype detector (proven) ----------------
__global__ void detect_k(const void* __restrict__ x, float* __restrict__ flag){
  if (threadIdx.x == 0 && blockIdx.x == 0){
    const float* xf = (const float*)x;
    const bf16*  xb = (const bf16*)x;
    double sF = 0.0, sB = 0.0;
    for (int i = 0; i < 512; i++){ float v = fabsf(xf[i]);     if (!(v < 1e30f)) v = 1e30f; sF += v; }
    for (int i = 0; i < 1024; i++){ float v = fabsf(b2f(xb[i])); if (!(v < 1e30f)) v = 1e30f; sB += v; }
    float mF = (float)(sF/512.0), mB = (float)(sB/1024.0);
    float dF = fabsf(logf(fmaxf(mF, 1e-30f)));
    float dB = fabsf(logf(fmaxf(mB, 1e-30f)));
    *flag = (dB <= dF) ? 1.0f : 0.0f;
  }
}

// ---------------- input -> fp32 convert (proven) ----------------
__global__ void cvt_k(const void* __restrict__ in, float* __restrict__ out, int n,
                      const float* __restrict__ flagp){
  bool bf = *flagp > 0.5f;
  int i = blockIdx.x*blockDim.x + threadIdx.x;
  if (i < n) out[i] = rdv(in, i, bf);
}

// ---------------- wave-split LayerNorm (proven R18) ----------------
__global__ __launch_bounds__(256) void ln2dw_k(
    const float* __restrict__ x, const void* __restrict__ g,
    const void* __restrict__ b, float* __restrict__ y,
    int C, int HW, const float* __restrict__ flagp)
{
  __shared__ float redS[4][64];
  __shared__ float redQ[4][64];
  bool bf = *flagp > 0.5f;
  int t = threadIdx.x, pix = t & 63, sub = t >> 6;
  int p  = blockIdx.x*64 + pix;
  int bb = blockIdx.y;
  const float* xb = x + (size_t)bb*C*HW + p;
  float xv[32];
  float s = 0.f, s2 = 0.f;
  #pragma unroll
  for (int i = 0; i < 32; i++){
    float v = xb[(size_t)(sub*32 + i)*HW];
    xv[i] = v; s += v; s2 += v*v;
  }
  redS[sub][pix] = s; redQ[sub][pix] = s2;
  __syncthreads();
  float st = redS[0][pix] + redS[1][pix] + redS[2][pix] + redS[3][pix];
  float qt = redQ[0][pix] + redQ[1][pix] + redQ[2][pix] + redQ[3][pix];
  float mu  = st / (float)C;
  float var = fmaxf(qt / (float)C - mu*mu, 0.f);
  float inv = rsqrtf(var + 1e-5f);
  float* yb = y + (size_t)bb*C*HW + p;
  #pragma unroll
  for (int i = 0; i < 32; i++){
    int c = sub*32 + i;
    yb[(size_t)c*HW] = (xv[i] - mu)*inv*rdv(g, c, bf) + rdv(b, c, bf);
  }
}

// ---------------- K pre-normalization: k <- k/max(||k||,eps), per 16-dim head group ----------------
__global__ void normk_k(float* __restrict__ KV, long kbs, int koff, int NK){
  int p = blockIdx.x*blockDim.x + threadIdx.x;
  if (p >= NK) return;
  int h = blockIdx.y, bb = blockIdx.z;
  float* base = KV + (size_t)bb*kbs + (size_t)(koff + h*16)*NK + p;
  float v[16]; float s = 0.f;
  #pragma unroll
  for (int d = 0; d < 16; d++){ v[d] = base[(size_t)d*NK]; s += v[d]*v[d]; }
  float iv = 1.f / fmaxf(sqrtf(s), 1e-12f);
  #pragma unroll
  for (int d = 0; d < 16; d++) base[(size_t)d*NK] = v[d]*iv;
}

// ---------------- generic scalar 1x1 conv (proven; small NP cases) ----------------
__global__ void conv1x1_k(const float* __restrict__ in1, long in1_bs, int C1,
                          const float* __restrict__ in2, long in2_bs, int C2,
                          const void* __restrict__ w, const void* __restrict__ bias,
                          const float* __restrict__ res,
                          void* __restrict__ out, int to_out, int O, int NP, int act,
                          const float* __restrict__ flagp){
  bool bf = *flagp > 0.5f;
  int p = blockIdx.x*blockDim.x + threadIdx.x;
  if (p >= NP) return;
  int o = blockIdx.y, bb = blockIdx.z;
  size_t wrow = (size_t)o*(C1 + C2);
  float acc = bias ? rdv(bias, o, bf) : 0.f;
  const float* i1 = in1 + (size_t)bb*in1_bs + p;
  for (int c = 0; c < C1; c++) acc += rdv(w, wrow + c, bf) * i1[(size_t)c*NP];
  if (in2){
    const float* i2 = in2 + (size_t)bb*in2_bs + p;
    for (int c = 0; c < C2; c++) acc += rdv(w, wrow + C1 + c, bf) * i2[(size_t)c*NP];
  }
  if (act == 1) acc = gelu_f(acc);
  if (res) acc += res[((size_t)bb*O + o)*NP + p];
  size_t oi = ((size_t)bb*O + o)*NP + p;
  if (to_out){
    if (bf) ((bf16*)out)[oi] = __float2bfloat16(acc);
    else    ((float*)out)[oi] = acc;
  } else {
    ((float*)out)[oi] = acc;
  }
}

// ---------------- MFMA 1x1-conv GEMM (R23) ----------------
// out[o][p] = sum_c W[o][c] * X[c][p] via v_mfma_f32_16x16x16_f16 (fragment layout HW-verified
// by flat_mfma_k): A = W (m=o: lane&15 row, k=c: contiguous float4), B = X (k=c, n=p: lanes
// 0-15 read contiguous 64B), D (col=p=lane&15, row=o=(lane>>4)*4+r) -> coalesced stores.
// One 64-thread block computes 64o x 16p: no LDS, no barriers, ~40 VGPR, grid (NP/16, O/64, B)
// = 576..2304 single-wave blocks (vs convtile's 144 4-wave blocks at 5.8% occupancy, 53us).
// f32 accumulate; f16 input rounding ~1e-4 (weights*acts ~0.02), far under 2^-7 tolerance.
// Requirements: NP % 16 == 0, O % 64 == 0, CW % 16 == 0.
__global__ __launch_bounds__(64) void convmfma_k(
    const float* __restrict__ in1, long in1_bs, int C1,
    const float* __restrict__ in2, long in2_bs, int C2,
    const void* __restrict__ w, const void* __restrict__ bias,
    const float* __restrict__ res, void* __restrict__ out, int to_out,
    int O, int NP, int act, const float* __restrict__ flagp)
{
  bool bf = *flagp > 0.5f;
  int lane = threadIdx.x;
  int lm = lane & 15, lg = lane >> 4;
  int p0 = blockIdx.x*16, o0 = blockIdx.y*64, bb = blockIdx.z;
  int CW = C1 + C2;
  f32x4 d[4];
  #pragma unroll
  for (int ot = 0; ot < 4; ot++){ d[ot][0]=0.f; d[ot][1]=0.f; d[ot][2]=0.f; d[ot][3]=0.f; }
  const float* x1 = in1 + (size_t)bb*in1_bs + p0 + lm;
  const float* x2 = in2 ? (in2 + (size_t)bb*in2_bs + p0 + lm) : nullptr;
  #pragma unroll 4
  for (int kc = 0; kc < CW; kc += 16){
    f16x4 xb;
    #pragma unroll
    for (int i = 0; i < 4; i++){
      int c = kc + lg*4 + i;
      float v = (c < C1) ? x1[(size_t)c*NP] : x2[(size_t)(c - C1)*NP];
      xb[i] = (f16)v;
    }
    #pragma unroll
    for (int ot = 0; ot < 4; ot++){
      float4 wv = ld4f(w, (size_t)(o0 + ot*16 + lm)*CW + kc + lg*4, bf);
      f16x4 wa; wa[0]=(f16)wv.x; wa[1]=(f16)wv.y; wa[2]=(f16)wv.z; wa[3]=(f16)wv.w;
      d[ot] = __builtin_amdgcn_mfma_f32_16x16x16f16(wa, xb, d[ot], 0, 0, 0);
    }
  }
  #pragma unroll
  for (int ot = 0; ot < 4; ot++){
    #pragma unroll
    for (int r = 0; r < 4; r++){
      int o = o0 + ot*16 + lg*4 + r;
      float v = d[ot][r] + (bias ? rdv(bias, o, bf) : 0.f);
      if (act == 1) v = gelu_f(v);
      size_t oi = ((size_t)bb*O + o)*NP + p0 + lm;
      if (res) v += res[oi];
      if (to_out && bf) ((bf16*)out)[oi] = __float2bfloat16(v);
      else              ((float*)out)[oi] = v;
    }
  }
}

// ---------------- MFMA flash cosine attention (local attn, d=16) ----------------
// R22 (proven): S^T = mfma(A=K, B=Q^T); C layout == PV B-frag layout -> P feeds PV with zero
// cross-lane movement. V channel-major == V^T. No-max softmax. K pre-normalized.
__global__ __launch_bounds__(512) void flat_mfma_k(
    const float* __restrict__ Q, long qbs, int qoff,
    const float* __restrict__ KV, long kbs, int koff, int voff,
    float* __restrict__ Out, long obs, int NQ, int NK, float scale)
{
  __shared__ float OS[8*4*16*17];   // [wave][qt][q][d] pitch 17
  __shared__ float LS[8*4*16];      // [wave][qt][q]
  int t = threadIdx.x, lane = t & 63, wv = t >> 6;
  int h = blockIdx.y, bb = blockIdx.z;
  int qb = blockIdx.x*64;
  int lm = lane & 15, lg = lane >> 4;          // m/n index, k-group
  const float* qp  = Q  + (size_t)bb*qbs;
  const float* kvb = KV + (size_t)bb*kbs;
  f16x4 qf[4];
  #pragma unroll
  for (int qt = 0; qt < 4; qt++){
    float qv[4]; float ss = 0.f;
    #pragma unroll
    for (int i = 0; i < 4; i++){
      qv[i] = qp[(size_t)(qoff + h*16 + lg*4 + i)*NQ + qb + qt*16 + lm];
      ss += qv[i]*qv[i];
    }
    ss += __shfl_xor(ss, 16); ss += __shfl_xor(ss, 32);
    float inv = scale / fmaxf(sqrtf(ss), 1e-12f);
    #pragma unroll
    for (int i = 0; i < 4; i++) qf[qt][i] = (f16)(qv[i]*inv);
  }
  f32x4 of[4];
  float ls[4];
  #pragma unroll
  for (int qt = 0; qt < 4; qt++){
    of[qt][0]=0.f; of[qt][1]=0.f; of[qt][2]=0.f; of[qt][3]=0.f; ls[qt]=0.f;
  }
  int chunk = NK >> 3;
  int p0 = wv*chunk, p1 = p0 + chunk;
  const float* kc = kvb + (size_t)(koff + h*16)*NK;
  const float* vc = kvb + (size_t)(voff + h*16)*NK;
  for (int pos = p0; pos < p1; pos += 16){
    f16x4 kf;
    #pragma unroll
    for (int i = 0; i < 4; i++)
      kf[i] = (f16)kc[(size_t)(lg*4 + i)*NK + pos + lm];
    float4 vvv = *(const float4*)&vc[(size_t)lm*NK + pos + lg*4];
    f16x4 vf; vf[0]=(f16)vvv.x; vf[1]=(f16)vvv.y; vf[2]=(f16)vvv.z; vf[3]=(f16)vvv.w;
    #pragma unroll
    for (int qt = 0; qt < 4; qt++){
      f32x4 s; s[0]=0.f; s[1]=0.f; s[2]=0.f; s[3]=0.f;
      s = __builtin_amdgcn_mfma_f32_16x16x16f16(kf, qf[qt], s, 0, 0, 0);
      f16x4 pf;
      #pragma unroll
      for (int r = 0; r < 4; r++){
        float pp = __expf(s[r]);
        ls[qt] += pp;
        pf[r] = (f16)pp;
      }
      of[qt] = __builtin_amdgcn_mfma_f32_16x16x16f16(vf, pf, of[qt], 0, 0, 0);
    }
  }
  #pragma unroll
  for (int qt = 0; qt < 4; qt++){
    ls[qt] += __shfl_xor(ls[qt], 16);
    ls[qt] += __shfl_xor(ls[qt], 32);
    #pragma unroll
    for (int r = 0; r < 4; r++)
      OS[((wv*4 + qt)*16 + lm)*17 + lg*4 + r] = of[qt][r];
    if (lg == 0) LS[(wv*4 + qt)*16 + lm] = ls[qt];
  }
  __syncthreads();
  #pragma unroll
  for (int rep = 0; rep < 2; rep++){
    int o = t + rep*512;
    int d = o >> 6, qq = o & 63;
    int qt = qq >> 4, q = qq & 15;
    float acc = 0.f, lsum = 0.f;
    #pragma unroll
    for (int w = 0; w < 8; w++){
      acc  += OS[((w*4 + qt)*16 + q)*17 + d];
      lsum += LS[(w*4 + qt)*16 + q];
    }
    Out[(size_t)bb*obs + (size_t)(h*16 + d)*NQ + qb + qq] = acc / fmaxf(lsum, 1e-30f);
  }
}

// ---------------- attn4, no-max (global attn NK=144 and xw attention NK=16) ----------------
__global__ __launch_bounds__(256) void attn4_k(
    const float* __restrict__ Q, long qbs, int qoff,
    const float* __restrict__ KV, long kbs, int koff, int voff,
    float* __restrict__ Out, long obs, int NQ, int NK, float scale)
{
  __shared__ __align__(16) float Ks[TK*KP];
  __shared__ __align__(16) float Vs[TK*KP];
  int tid = threadIdx.x;
  int sub = tid & 3;
  int h = blockIdx.y, bb = blockIdx.z;
  int qi = blockIdx.x*64 + (tid >> 2);
  bool qv = qi < NQ;
  float qn[4] = {0,0,0,0}, acc[4] = {0,0,0,0};
  float l = 0.f;
  if (qv){
    float s = 0.f;
    #pragma unroll
    for (int j = 0; j < 4; j++){
      qn[j] = Q[(size_t)bb*qbs + (size_t)(qoff + h*16 + sub*4 + j)*NQ + qi];
      s += qn[j]*qn[j];
    }
    s += __shfl_xor(s, 1); s += __shfl_xor(s, 2);
    float inv = scale / fmaxf(sqrtf(s), 1e-12f);
    #pragma unroll
    for (int j = 0; j < 4; j++) qn[j] *= inv;
  }
  for (int k0 = 0; k0 < NK; k0 += TK){
    int lim = min(TK, NK - k0);
    for (int i = tid; i < 16*TK; i += 256){
      int pos = i & (TK-1), d = i >> 7;
      if (pos < lim){
        Ks[pos*KP + d] = KV[(size_t)bb*kbs + (size_t)(koff + h*16 + d)*NK + k0 + pos];
        Vs[pos*KP + d] = KV[(size_t)bb*kbs + (size_t)(voff + h*16 + d)*NK + k0 + pos];
      }
    }
    __syncthreads();
    for (int pos = 0; pos < lim; pos++){
      float4 k4 = *(const float4*)&Ks[pos*KP + sub*4];
      float dd = qn[0]*k4.x + qn[1]*k4.y + qn[2]*k4.z + qn[3]*k4.w;
      dd += __shfl_xor(dd, 1); dd += __shfl_xor(dd, 2);
      float pp = __expf(dd);
      l += pp;
      float4 v4 = *(const float4*)&Vs[pos*KP + sub*4];
      acc[0] += pp*v4.x;
      acc[1] += pp*v4.y;
      acc[2] += pp*v4.z;
      acc[3] += pp*v4.w;
    }
    __syncthreads();
  }
  if (qv){
    float li = 1.f / fmaxf(l, 1e-30f);
    #pragma unroll
    for (int j = 0; j < 4; j++)
      Out[(size_t)bb*obs + (size_t)(h*16 + sub*4 + j)*NQ + qi] = acc[j]*li;
  }
}

// ---------------- latent-read attention, split-K partials ----------------
__global__ void latpart_k(const float* __restrict__ ql, const float* __restrict__ kvx,
                          long kbs, float* __restrict__ part, int NK, int S){
  int s = blockIdx.x, h = blockIdx.y, bb = blockIdx.z;
  int t = threadIdx.x;
  int q = t & 15, sub = (t >> 4) & 3;
  float qn[16]; float ss = 0.f;
  #pragma unroll
  for (int d = 0; d < 16; d++){
    qn[d] = ql[(size_t)bb*2048 + (size_t)(h*16+d)*16 + q];
    ss += qn[d]*qn[d];
  }
  float inv = 0.25f / fmaxf(sqrtf(ss), 1e-12f);
  #pragma unroll
  for (int d = 0; d < 16; d++) qn[d] *= inv;
  float l = 0.f, acc[16];
  #pragma unroll
  for (int d = 0; d < 16; d++) acc[d] = 0.f;
  int chunk = NK / S, c4 = chunk >> 2;
  int k0 = s*chunk + sub*c4, k1 = k0 + c4;
  const float* kb = kvx + (size_t)bb*kbs;
  for (int pos = k0; pos < k1; pos++){
    float dot = 0.f;
    #pragma unroll
    for (int d = 0; d < 16; d++) dot += qn[d]*kb[(size_t)(h*16+d)*NK + pos];
    float pp = __expf(dot);
    l += pp;
    #pragma unroll
    for (int d = 0; d < 16; d++)
      acc[d] += pp*kb[(size_t)(128 + h*16+d)*NK + pos];
  }
  l += __shfl_xor(l, 16); l += __shfl_xor(l, 32);
  #pragma unroll
  for (int d = 0; d < 16; d++){
    acc[d] += __shfl_xor(acc[d], 16);
    acc[d] += __shfl_xor(acc[d], 32);
  }
  if ((t >> 4) == 0){
    size_t idx = (size_t)((((bb*8 + h)*16 + q)*S) + s)*18;
    part[idx] = l;
    #pragma unroll
    for (int d = 0; d < 16; d++) part[idx+1+d] = acc[d];
  }
}

__global__ void latcomb_k(const float* __restrict__ part, float* __restrict__ latr, int S){
  int t = threadIdx.x;
  int q = t & 15, h = (t >> 4) & 7, bb = t >> 7;
  size_t base = (size_t)(((bb*8 + h)*16 + q)*S)*18;
  float L = 0.f, acc[16];
  #pragma unroll
  for (int d = 0; d < 16; d++) acc[d] = 0.f;
  for (int s = 0; s < S; s++){
    const float* ps = part + base + (size_t)s*18;
    L += ps[0];
    #pragma unroll
    for (int d = 0; d < 16; d++) acc[d] += ps[1+d];
  }
  float li = 1.f / fmaxf(L, 1e-30f);
  #pragma unroll
  for (int d = 0; d < 16; d++)
    latr[(size_t)bb*2048 + (size_t)(h*16+d)*16 + q] = acc[d]*li;
}

// ---------------- 4x4 mean pool (proven) ----------------
__global__ void pool4_k(const float* __restrict__ xn, float* __restrict__ xc){
  int i = blockIdx.x*blockDim.x + threadIdx.x;
  if (i >= 2*128*144) return;
  int pc = i % 144; int bc = i / 144;
  int hc = pc / 12, wc = pc % 12;
  const float* s = xn + (size_t)bc*2304 + hc*4*48 + wc*4;
  float acc = 0.f;
  #pragma unroll
  for (int r = 0; r < 4; r++)
    #pragma unroll
    for (int c2 = 0; c2 < 4; c2++) acc += s[r*48 + c2];
  xc[i] = acc * 0.0625f;
}

// ---------------- bilinear upsample 12->48 (proven) ----------------
__global__ void ups_k(const float* __restrict__ g, float* __restrict__ out){
  int i = blockIdx.x*blockDim.x + threadIdx.x;
  if (i >= 2*128*2304) return;
  int p = i % 2304; int bc = i / 2304;
  int h = p / 48, w = p % 48;
  float sh = h*0.25f - 0.375f;
  float sw = w*0.25f - 0.375f;
  float fh0 = floorf(sh), fw0 = floorf(sw);
  float fh = sh - fh0, fw = sw - fw0;
  int h0 = (int)fh0, w0 = (int)fw0;
  int h0c = min(11, max(0, h0)),   h1c = min(11, max(0, h0+1));
  int w0c = min(11, max(0, w0)),   w1c = min(11, max(0, w0+1));
  const float* s = g + (size_t)bc*144;
  float v00 = s[h0c*12 + w0c], v01 = s[h0c*12 + w1c];
  float v10 = s[h1c*12 + w0c], v11 = s[h1c*12 + w1c];
  out[i] = (1.f-fh)*((1.f-fw)*v00 + fw*v01) + fh*((1.f-fw)*v10 + fw*v11);
}

extern "C" void kernel_launch(void* const* d_in, const int* in_sizes, int n_in,
                              void* d_out, int out_size, void* d_ws, size_t ws_size,
                              hipStream_t stream){
  const int B = 2, C = 128, HW = 2304;
  const void* x_in        = d_in[0];
  const void* g1          = d_in[1];
  const void* b1          = d_in[2];
  const void* loc_qkv_w   = d_in[3];
  const void* loc_proj_w  = d_in[4];
  const void* loc_proj_b  = d_in[5];
  const void* glob_qkv_w  = d_in[6];
  const void* glob_proj_w = d_in[7];
  const void* glob_proj_b = d_in[8];
  const void* fuse_w1     = d_in[9];
  const void* fuse_b1     = d_in[10];
  const void* fuse_w2     = d_in[11];
  const void* fuse_b2     = d_in[12];
  const void* glat        = d_in[13];
  const void* blat        = d_in[14];
  const void* latents     = d_in[15];
  const void* qlat_w      = d_in[16];
  const void* kvx_w       = d_in[17];
  const void* qx_w        = d_in[18];
  const void* kvlat_w     = d_in[19];
  const void* lat_proj_w  = d_in[20];
  const void* lat_proj_b  = d_in[21];
  const void* g2          = d_in[22];
  const void* b2          = d_in[23];
  const void* ffn_w1      = d_in[24];
  const void* ffn_b1      = d_in[25];
  const void* ffn_w2      = d_in[26];
  const void* ffn_b2      = d_in[27];

  // ---- workspace layout VERBATIM (R8..R18) ----
  float* ws = (float*)d_ws;
  float* P  = ws + 0;
  float* N  = ws + 589824;
  float* A  = ws + 1179648;
  float* Q  = ws + 1769472;
  float* FLAG = ws + 4128768;

  float* qkv   = Q;                 // 1,769,472
  float* L     = Q + 1769472;       // 589,824
  float* xc    = Q;
  float* qkvc  = Q + 36864;
  float* gatt  = Q + 147456;
  float* gproj = Q + 184320;
  float* kvx   = Q;                 // 1,179,648
  float* latf  = Q + 1179648;
  float* qlat  = Q + 1181696;
  float* latr  = Q + 1185792;
  float* kvlat = Q + 1189888;
  float* part  = Q + 1198080;       // 221,184 (S=48)
  float* ffh   = Q;                 // 2,359,296

  dim3 blk(256);
  dim3 blk512(512);
  dim3 blk64(64);

  detect_k<<<1, 64, 0, stream>>>(x_in, FLAG);
  cvt_k<<<2304, blk, 0, stream>>>(x_in, P, 589824, FLAG);

  // ---- BioAttentionFusion branch ----
  ln2dw_k<<<dim3(36,B), blk, 0, stream>>>(P, g1, b1, N, C, HW, FLAG);
  convmfma_k<<<dim3(144,6,B), blk64, 0, stream>>>(N,(long)C*HW,C, nullptr,0,0, loc_qkv_w,nullptr,nullptr, qkv,0,384,HW,0, FLAG);
  normk_k<<<dim3(9,8,B), blk, 0, stream>>>(qkv, (long)384*HW, 128, HW);
  flat_mfma_k<<<dim3(36,8,B), blk512, 0, stream>>>(qkv,(long)384*HW,0, qkv,(long)384*HW,128,256, A,(long)C*HW, HW,HW,0.25f);
  convmfma_k<<<dim3(144,2,B), blk64, 0, stream>>>(A,(long)C*HW,C, nullptr,0,0, loc_proj_w,loc_proj_b,nullptr, L,0,C,HW,0, FLAG);
  pool4_k<<<144, blk, 0, stream>>>(N, xc);
  conv1x1_k<<<dim3(1,384,B), blk, 0, stream>>>(xc,(long)C*144,C, nullptr,0,0, glob_qkv_w,nullptr,nullptr, qkvc,0,384,144,0, FLAG);
  normk_k<<<dim3(1,8,B), blk, 0, stream>>>(qkvc, (long)384*144, 128, 144);
  attn4_k<<<dim3(3,8,B), blk, 0, stream>>>(qkvc,(long)384*144,0, qkvc,(long)384*144,128,256, gatt,(long)C*144, 144,144,0.25f);
  conv1x1_k<<<dim3(1,128,B), blk, 0, stream>>>(gatt,(long)C*144,C, nullptr,0,0, glob_proj_w,glob_proj_b,nullptr, gproj,0,C,144,0, FLAG);
  ups_k<<<2304, blk, 0, stream>>>(gproj, A);                                          // A = upsampled global
  convmfma_k<<<dim3(144,2,B), blk64, 0, stream>>>(L,(long)C*HW,C, A,(long)C*HW,C, fuse_w1,fuse_b1,nullptr, N,0,C,HW,1, FLAG);  // N = gelu(fuse1)
  convmfma_k<<<dim3(144,2,B), blk64, 0, stream>>>(N,(long)C*HW,C, nullptr,0,0, fuse_w2,fuse_b2,P, P,0,C,HW,0, FLAG);           // P = x + f

  // ---- LatentMixer branch ----
  ln2dw_k<<<dim3(36,B), blk, 0, stream>>>(P, glat, blat, N, C, HW, FLAG);
  convmfma_k<<<dim3(144,4,B), blk64, 0, stream>>>(N,(long)C*HW,C, nullptr,0,0, kvx_w,nullptr,nullptr, kvx,0,256,HW,0, FLAG);
  normk_k<<<dim3(9,8,B), blk, 0, stream>>>(kvx, (long)256*HW, 0, HW);
  convmfma_k<<<dim3(144,2,B), blk64, 0, stream>>>(N,(long)C*HW,C, nullptr,0,0, qx_w,nullptr,nullptr, A,0,C,HW,0, FLAG);        // A = qx
  cvt_k<<<8, blk, 0, stream>>>(latents, latf, 2048, FLAG);
  conv1x1_k<<<dim3(1,128,B), blk, 0, stream>>>(latf,0L,C, nullptr,0,0, qlat_w,nullptr,nullptr, qlat,0,C,16,0, FLAG);
  latpart_k<<<dim3(48,8,B), 64, 0, stream>>>(qlat, kvx, (long)256*HW, part, HW, 48);
  latcomb_k<<<1, blk, 0, stream>>>(part, latr, 48);
  conv1x1_k<<<dim3(1,256,B), blk, 0, stream>>>(latr,(long)C*16,C, nullptr,0,0, kvlat_w,nullptr,nullptr, kvlat,0,256,16,0, FLAG);
  normk_k<<<dim3(1,8,B), blk, 0, stream>>>(kvlat, (long)256*16, 0, 16);
  attn4_k<<<dim3(36,8,B), blk, 0, stream>>>(A,(long)C*HW,0, kvlat,(long)256*16,0,128, N,(long)C*HW, HW,16,0.25f);           // N = xw
  convmfma_k<<<dim3(144,2,B), blk64, 0, stream>>>(N,(long)C*HW,C, nullptr,0,0, lat_proj_w,lat_proj_b,P, P,0,C,HW,0, FLAG);     // P = x2

  // ---- FFN branch ----
  ln2dw_k<<<dim3(36,B), blk, 0, stream>>>(P, g2, b2, N, C, HW, FLAG);
  convmfma_k<<<dim3(144,8,B), blk64, 0, stream>>>(N,(long)C*HW,C, nullptr,0,0, ffn_w1,ffn_b1,nullptr, ffh,0,512,HW,1, FLAG);
  convmfma_k<<<dim3(144,2,B), blk64, 0, stream>>>(ffh,(long)512*HW,512, nullptr,0,0, ffn_w2,ffn_b2,P, d_out,1,C,HW,0, FLAG);
}

// Round 6
// 531.012 us; speedup vs baseline: 1.4196x; 1.1544x over previous
//
#include <hip/hip_runtime.h>
#include <hip/hip_bf16.h>

typedef __hip_bfloat16 bf16;
typedef _Float16 f16;
typedef _Float16 f16x4 __attribute__((ext_vector_type(4)));
typedef float f32x4 __attribute__((ext_vector_type(4)));

#define HD 16
#define TK 128
#define KP 20            // attn LDS pitch: 16 dims + 4 pad, keeps float4 16B-aligned
#define MINIT (-1e30f)

__device__ __forceinline__ float b2f(bf16 v){ return __bfloat162float(v); }
__device__ __forceinline__ float gelu_f(float x){ return 0.5f*x*(1.0f+erff(x*0.70710678118654752f)); }
__device__ __forceinline__ float rdv(const void* p, size_t i, bool bf){
  return bf ? b2f(((const bf16*)p)[i]) : ((const float*)p)[i];
}
__device__ __forceinline__ float4 ld4f(const void* p, size_t i, bool bf){
  if (bf){
    const bf16* q = (const bf16*)p + i;
    return make_float4(b2f(q[0]), b2f(q[1]), b2f(q[2]), b2f(q[3]));
  }
  return *(const float4*)((const float*)p + i);
}

// ---------------- dtype detector (proven) ----------------
__global__ void detect_k(const void* __restrict__ x, float* __restrict__ flag){
  if (threadIdx.x == 0 && blockIdx.x == 0){
    const float* xf = (const float*)x;
    const bf16*  xb = (const bf16*)x;
    double sF = 0.0, sB = 0.0;
    for (int i = 0; i < 512; i++){ float v = fabsf(xf[i]);     if (!(v < 1e30f)) v = 1e30f; sF += v; }
    for (int i = 0; i < 1024; i++){ float v = fabsf(b2f(xb[i])); if (!(v < 1e30f)) v = 1e30f; sB += v; }
    float mF = (float)(sF/512.0), mB = (float)(sB/1024.0);
    float dF = fabsf(logf(fmaxf(mF, 1e-30f)));
    float dB = fabsf(logf(fmaxf(mB, 1e-30f)));
    *flag = (dB <= dF) ? 1.0f : 0.0f;
  }
}

// ---------------- input -> fp32 convert (proven) ----------------
__global__ void cvt_k(const void* __restrict__ in, float* __restrict__ out, int n,
                      const float* __restrict__ flagp){
  bool bf = *flagp > 0.5f;
  int i = blockIdx.x*blockDim.x + threadIdx.x;
  if (i < n) out[i] = rdv(in, i, bf);
}

// ---------------- wave-split LayerNorm (proven R18) ----------------
__global__ __launch_bounds__(256) void ln2dw_k(
    const float* __restrict__ x, const void* __restrict__ g,
    const void* __restrict__ b, float* __restrict__ y,
    int C, int HW, const float* __restrict__ flagp)
{
  __shared__ float redS[4][64];
  __shared__ float redQ[4][64];
  bool bf = *flagp > 0.5f;
  int t = threadIdx.x, pix = t & 63, sub = t >> 6;
  int p  = blockIdx.x*64 + pix;
  int bb = blockIdx.y;
  const float* xb = x + (size_t)bb*C*HW + p;
  float xv[32];
  float s = 0.f, s2 = 0.f;
  #pragma unroll
  for (int i = 0; i < 32; i++){
    float v = xb[(size_t)(sub*32 + i)*HW];
    xv[i] = v; s += v; s2 += v*v;
  }
  redS[sub][pix] = s; redQ[sub][pix] = s2;
  __syncthreads();
  float st = redS[0][pix] + redS[1][pix] + redS[2][pix] + redS[3][pix];
  float qt = redQ[0][pix] + redQ[1][pix] + redQ[2][pix] + redQ[3][pix];
  float mu  = st / (float)C;
  float var = fmaxf(qt / (float)C - mu*mu, 0.f);
  float inv = rsqrtf(var + 1e-5f);
  float* yb = y + (size_t)bb*C*HW + p;
  #pragma unroll
  for (int i = 0; i < 32; i++){
    int c = sub*32 + i;
    yb[(size_t)c*HW] = (xv[i] - mu)*inv*rdv(g, c, bf) + rdv(b, c, bf);
  }
}

// ---------------- K pre-normalization: k <- k/max(||k||,eps), per 16-dim head group ----------------
__global__ void normk_k(float* __restrict__ KV, long kbs, int koff, int NK){
  int p = blockIdx.x*blockDim.x + threadIdx.x;
  if (p >= NK) return;
  int h = blockIdx.y, bb = blockIdx.z;
  float* base = KV + (size_t)bb*kbs + (size_t)(koff + h*16)*NK + p;
  float v[16]; float s = 0.f;
  #pragma unroll
  for (int d = 0; d < 16; d++){ v[d] = base[(size_t)d*NK]; s += v[d]*v[d]; }
  float iv = 1.f / fmaxf(sqrtf(s), 1e-12f);
  #pragma unroll
  for (int d = 0; d < 16; d++) base[(size_t)d*NK] = v[d]*iv;
}

// ---------------- generic scalar 1x1 conv (proven; small NP cases) ----------------
__global__ void conv1x1_k(const float* __restrict__ in1, long in1_bs, int C1,
                          const float* __restrict__ in2, long in2_bs, int C2,
                          const void* __restrict__ w, const void* __restrict__ bias,
                          const float* __restrict__ res,
                          void* __restrict__ out, int to_out, int O, int NP, int act,
                          const float* __restrict__ flagp){
  bool bf = *flagp > 0.5f;
  int p = blockIdx.x*blockDim.x + threadIdx.x;
  if (p >= NP) return;
  int o = blockIdx.y, bb = blockIdx.z;
  size_t wrow = (size_t)o*(C1 + C2);
  float acc = bias ? rdv(bias, o, bf) : 0.f;
  const float* i1 = in1 + (size_t)bb*in1_bs + p;
  for (int c = 0; c < C1; c++) acc += rdv(w, wrow + c, bf) * i1[(size_t)c*NP];
  if (in2){
    const float* i2 = in2 + (size_t)bb*in2_bs + p;
    for (int c = 0; c < C2; c++) acc += rdv(w, wrow + C1 + c, bf) * i2[(size_t)c*NP];
  }
  if (act == 1) acc = gelu_f(acc);
  if (res) acc += res[((size_t)bb*O + o)*NP + p];
  size_t oi = ((size_t)bb*O + o)*NP + p;
  if (to_out){
    if (bf) ((bf16*)out)[oi] = __float2bfloat16(acc);
    else    ((float*)out)[oi] = acc;
  } else {
    ((float*)out)[oi] = acc;
  }
}

// ---------------- MFMA 1x1-conv GEMM (R24: 16o x 16p per wave) ----------------
// R23's 64o x 16p tiling gave only 576 waves (2.25/CU) -> latency-starved at 280 GB/s
// (Little's law: 0.3MB in flight / 900ns = 300 GB/s, matched measurement). R24 quarters the
// per-wave tile: one accumulator, grid (NP/16, O/16, B) -> 2304..9216 waves (9-36/CU),
// ~9MB in flight -> HBM-saturating. Per wave: CW/16 steps of {4 X dwords + 1 W float4 +
// 1 MFMA}, unroll 8 issues all loads up front (~24 VGPR). Fragment layout HW-verified by
// flat_mfma_k. f32 accumulate. Requirements: NP % 16 == 0, O % 16 == 0, CW % 16 == 0.
__global__ __launch_bounds__(64) void convmfma_k(
    const float* __restrict__ in1, long in1_bs, int C1,
    const float* __restrict__ in2, long in2_bs, int C2,
    const void* __restrict__ w, const void* __restrict__ bias,
    const float* __restrict__ res, void* __restrict__ out, int to_out,
    int O, int NP, int act, const float* __restrict__ flagp)
{
  bool bf = *flagp > 0.5f;
  int lane = threadIdx.x;
  int lm = lane & 15, lg = lane >> 4;
  int p0 = blockIdx.x*16, o0 = blockIdx.y*16, bb = blockIdx.z;
  int CW = C1 + C2;
  f32x4 d; d[0]=0.f; d[1]=0.f; d[2]=0.f; d[3]=0.f;
  const float* x1 = in1 + (size_t)bb*in1_bs + p0 + lm;
  const float* x2 = in2 ? (in2 + (size_t)bb*in2_bs + p0 + lm) : nullptr;
  #pragma unroll 8
  for (int kc = 0; kc < CW; kc += 16){
    f16x4 xb;
    #pragma unroll
    for (int i = 0; i < 4; i++){
      int c = kc + lg*4 + i;
      float v = (c < C1) ? x1[(size_t)c*NP] : x2[(size_t)(c - C1)*NP];
      xb[i] = (f16)v;
    }
    float4 wv = ld4f(w, (size_t)(o0 + lm)*CW + kc + lg*4, bf);
    f16x4 wa; wa[0]=(f16)wv.x; wa[1]=(f16)wv.y; wa[2]=(f16)wv.z; wa[3]=(f16)wv.w;
    d = __builtin_amdgcn_mfma_f32_16x16x16f16(wa, xb, d, 0, 0, 0);
  }
  #pragma unroll
  for (int r = 0; r < 4; r++){
    int o = o0 + lg*4 + r;
    float v = d[r] + (bias ? rdv(bias, o, bf) : 0.f);
    if (act == 1) v = gelu_f(v);
    size_t oi = ((size_t)bb*O + o)*NP + p0 + lm;
    if (res) v += res[oi];
    if (to_out && bf) ((bf16*)out)[oi] = __float2bfloat16(v);
    else              ((float*)out)[oi] = v;
  }
}

// ---------------- MFMA flash cosine attention (local attn, d=16) ----------------
// R22 (proven): S^T = mfma(A=K, B=Q^T); C layout == PV B-frag layout -> P feeds PV with zero
// cross-lane movement. V channel-major == V^T. No-max softmax. K pre-normalized.
__global__ __launch_bounds__(512) void flat_mfma_k(
    const float* __restrict__ Q, long qbs, int qoff,
    const float* __restrict__ KV, long kbs, int koff, int voff,
    float* __restrict__ Out, long obs, int NQ, int NK, float scale)
{
  __shared__ float OS[8*4*16*17];   // [wave][qt][q][d] pitch 17
  __shared__ float LS[8*4*16];      // [wave][qt][q]
  int t = threadIdx.x, lane = t & 63, wv = t >> 6;
  int h = blockIdx.y, bb = blockIdx.z;
  int qb = blockIdx.x*64;
  int lm = lane & 15, lg = lane >> 4;          // m/n index, k-group
  const float* qp  = Q  + (size_t)bb*qbs;
  const float* kvb = KV + (size_t)bb*kbs;
  f16x4 qf[4];
  #pragma unroll
  for (int qt = 0; qt < 4; qt++){
    float qv[4]; float ss = 0.f;
    #pragma unroll
    for (int i = 0; i < 4; i++){
      qv[i] = qp[(size_t)(qoff + h*16 + lg*4 + i)*NQ + qb + qt*16 + lm];
      ss += qv[i]*qv[i];
    }
    ss += __shfl_xor(ss, 16); ss += __shfl_xor(ss, 32);
    float inv = scale / fmaxf(sqrtf(ss), 1e-12f);
    #pragma unroll
    for (int i = 0; i < 4; i++) qf[qt][i] = (f16)(qv[i]*inv);
  }
  f32x4 of[4];
  float ls[4];
  #pragma unroll
  for (int qt = 0; qt < 4; qt++){
    of[qt][0]=0.f; of[qt][1]=0.f; of[qt][2]=0.f; of[qt][3]=0.f; ls[qt]=0.f;
  }
  int chunk = NK >> 3;
  int p0 = wv*chunk, p1 = p0 + chunk;
  const float* kc = kvb + (size_t)(koff + h*16)*NK;
  const float* vc = kvb + (size_t)(voff + h*16)*NK;
  for (int pos = p0; pos < p1; pos += 16){
    f16x4 kf;
    #pragma unroll
    for (int i = 0; i < 4; i++)
      kf[i] = (f16)kc[(size_t)(lg*4 + i)*NK + pos + lm];
    float4 vvv = *(const float4*)&vc[(size_t)lm*NK + pos + lg*4];
    f16x4 vf; vf[0]=(f16)vvv.x; vf[1]=(f16)vvv.y; vf[2]=(f16)vvv.z; vf[3]=(f16)vvv.w;
    #pragma unroll
    for (int qt = 0; qt < 4; qt++){
      f32x4 s; s[0]=0.f; s[1]=0.f; s[2]=0.f; s[3]=0.f;
      s = __builtin_amdgcn_mfma_f32_16x16x16f16(kf, qf[qt], s, 0, 0, 0);
      f16x4 pf;
      #pragma unroll
      for (int r = 0; r < 4; r++){
        float pp = __expf(s[r]);
        ls[qt] += pp;
        pf[r] = (f16)pp;
      }
      of[qt] = __builtin_amdgcn_mfma_f32_16x16x16f16(vf, pf, of[qt], 0, 0, 0);
    }
  }
  #pragma unroll
  for (int qt = 0; qt < 4; qt++){
    ls[qt] += __shfl_xor(ls[qt], 16);
    ls[qt] += __shfl_xor(ls[qt], 32);
    #pragma unroll
    for (int r = 0; r < 4; r++)
      OS[((wv*4 + qt)*16 + lm)*17 + lg*4 + r] = of[qt][r];
    if (lg == 0) LS[(wv*4 + qt)*16 + lm] = ls[qt];
  }
  __syncthreads();
  #pragma unroll
  for (int rep = 0; rep < 2; rep++){
    int o = t + rep*512;
    int d = o >> 6, qq = o & 63;
    int qt = qq >> 4, q = qq & 15;
    float acc = 0.f, lsum = 0.f;
    #pragma unroll
    for (int w = 0; w < 8; w++){
      acc  += OS[((w*4 + qt)*16 + q)*17 + d];
      lsum += LS[(w*4 + qt)*16 + q];
    }
    Out[(size_t)bb*obs + (size_t)(h*16 + d)*NQ + qb + qq] = acc / fmaxf(lsum, 1e-30f);
  }
}

// ---------------- attn4, no-max (global attn NK=144 and xw attention NK=16) ----------------
__global__ __launch_bounds__(256) void attn4_k(
    const float* __restrict__ Q, long qbs, int qoff,
    const float* __restrict__ KV, long kbs, int koff, int voff,
    float* __restrict__ Out, long obs, int NQ, int NK, float scale)
{
  __shared__ __align__(16) float Ks[TK*KP];
  __shared__ __align__(16) float Vs[TK*KP];
  int tid = threadIdx.x;
  int sub = tid & 3;
  int h = blockIdx.y, bb = blockIdx.z;
  int qi = blockIdx.x*64 + (tid >> 2);
  bool qv = qi < NQ;
  float qn[4] = {0,0,0,0}, acc[4] = {0,0,0,0};
  float l = 0.f;
  if (qv){
    float s = 0.f;
    #pragma unroll
    for (int j = 0; j < 4; j++){
      qn[j] = Q[(size_t)bb*qbs + (size_t)(qoff + h*16 + sub*4 + j)*NQ + qi];
      s += qn[j]*qn[j];
    }
    s += __shfl_xor(s, 1); s += __shfl_xor(s, 2);
    float inv = scale / fmaxf(sqrtf(s), 1e-12f);
    #pragma unroll
    for (int j = 0; j < 4; j++) qn[j] *= inv;
  }
  for (int k0 = 0; k0 < NK; k0 += TK){
    int lim = min(TK, NK - k0);
    for (int i = tid; i < 16*TK; i += 256){
      int pos = i & (TK-1), d = i >> 7;
      if (pos < lim){
        Ks[pos*KP + d] = KV[(size_t)bb*kbs + (size_t)(koff + h*16 + d)*NK + k0 + pos];
        Vs[pos*KP + d] = KV[(size_t)bb*kbs + (size_t)(voff + h*16 + d)*NK + k0 + pos];
      }
    }
    __syncthreads();
    for (int pos = 0; pos < lim; pos++){
      float4 k4 = *(const float4*)&Ks[pos*KP + sub*4];
      float dd = qn[0]*k4.x + qn[1]*k4.y + qn[2]*k4.z + qn[3]*k4.w;
      dd += __shfl_xor(dd, 1); dd += __shfl_xor(dd, 2);
      float pp = __expf(dd);
      l += pp;
      float4 v4 = *(const float4*)&Vs[pos*KP + sub*4];
      acc[0] += pp*v4.x;
      acc[1] += pp*v4.y;
      acc[2] += pp*v4.z;
      acc[3] += pp*v4.w;
    }
    __syncthreads();
  }
  if (qv){
    float li = 1.f / fmaxf(l, 1e-30f);
    #pragma unroll
    for (int j = 0; j < 4; j++)
      Out[(size_t)bb*obs + (size_t)(h*16 + sub*4 + j)*NQ + qi] = acc[j]*li;
  }
}

// ---------------- latent-read attention, split-K partials ----------------
__global__ void latpart_k(const float* __restrict__ ql, const float* __restrict__ kvx,
                          long kbs, float* __restrict__ part, int NK, int S){
  int s = blockIdx.x, h = blockIdx.y, bb = blockIdx.z;
  int t = threadIdx.x;
  int q = t & 15, sub = (t >> 4) & 3;
  float qn[16]; float ss = 0.f;
  #pragma unroll
  for (int d = 0; d < 16; d++){
    qn[d] = ql[(size_t)bb*2048 + (size_t)(h*16+d)*16 + q];
    ss += qn[d]*qn[d];
  }
  float inv = 0.25f / fmaxf(sqrtf(ss), 1e-12f);
  #pragma unroll
  for (int d = 0; d < 16; d++) qn[d] *= inv;
  float l = 0.f, acc[16];
  #pragma unroll
  for (int d = 0; d < 16; d++) acc[d] = 0.f;
  int chunk = NK / S, c4 = chunk >> 2;
  int k0 = s*chunk + sub*c4, k1 = k0 + c4;
  const float* kb = kvx + (size_t)bb*kbs;
  for (int pos = k0; pos < k1; pos++){
    float dot = 0.f;
    #pragma unroll
    for (int d = 0; d < 16; d++) dot += qn[d]*kb[(size_t)(h*16+d)*NK + pos];
    float pp = __expf(dot);
    l += pp;
    #pragma unroll
    for (int d = 0; d < 16; d++)
      acc[d] += pp*kb[(size_t)(128 + h*16+d)*NK + pos];
  }
  l += __shfl_xor(l, 16); l += __shfl_xor(l, 32);
  #pragma unroll
  for (int d = 0; d < 16; d++){
    acc[d] += __shfl_xor(acc[d], 16);
    acc[d] += __shfl_xor(acc[d], 32);
  }
  if ((t >> 4) == 0){
    size_t idx = (size_t)((((bb*8 + h)*16 + q)*S) + s)*18;
    part[idx] = l;
    #pragma unroll
    for (int d = 0; d < 16; d++) part[idx+1+d] = acc[d];
  }
}

__global__ void latcomb_k(const float* __restrict__ part, float* __restrict__ latr, int S){
  int t = threadIdx.x;
  int q = t & 15, h = (t >> 4) & 7, bb = t >> 7;
  size_t base = (size_t)(((bb*8 + h)*16 + q)*S)*18;
  float L = 0.f, acc[16];
  #pragma unroll
  for (int d = 0; d < 16; d++) acc[d] = 0.f;
  for (int s = 0; s < S; s++){
    const float* ps = part + base + (size_t)s*18;
    L += ps[0];
    #pragma unroll
    for (int d = 0; d < 16; d++) acc[d] += ps[1+d];
  }
  float li = 1.f / fmaxf(L, 1e-30f);
  #pragma unroll
  for (int d = 0; d < 16; d++)
    latr[(size_t)bb*2048 + (size_t)(h*16+d)*16 + q] = acc[d]*li;
}

// ---------------- 4x4 mean pool (proven) ----------------
__global__ void pool4_k(const float* __restrict__ xn, float* __restrict__ xc){
  int i = blockIdx.x*blockDim.x + threadIdx.x;
  if (i >= 2*128*144) return;
  int pc = i % 144; int bc = i / 144;
  int hc = pc / 12, wc = pc % 12;
  const float* s = xn + (size_t)bc*2304 + hc*4*48 + wc*4;
  float acc = 0.f;
  #pragma unroll
  for (int r = 0; r < 4; r++)
    #pragma unroll
    for (int c2 = 0; c2 < 4; c2++) acc += s[r*48 + c2];
  xc[i] = acc * 0.0625f;
}

// ---------------- bilinear upsample 12->48 (proven) ----------------
__global__ void ups_k(const float* __restrict__ g, float* __restrict__ out){
  int i = blockIdx.x*blockDim.x + threadIdx.x;
  if (i >= 2*128*2304) return;
  int p = i % 2304; int bc = i / 2304;
  int h = p / 48, w = p % 48;
  float sh = h*0.25f - 0.375f;
  float sw = w*0.25f - 0.375f;
  float fh0 = floorf(sh), fw0 = floorf(sw);
  float fh = sh - fh0, fw = sw - fw0;
  int h0 = (int)fh0, w0 = (int)fw0;
  int h0c = min(11, max(0, h0)),   h1c = min(11, max(0, h0+1));
  int w0c = min(11, max(0, w0)),   w1c = min(11, max(0, w0+1));
  const float* s = g + (size_t)bc*144;
  float v00 = s[h0c*12 + w0c], v01 = s[h0c*12 + w1c];
  float v10 = s[h1c*12 + w0c], v11 = s[h1c*12 + w1c];
  out[i] = (1.f-fh)*((1.f-fw)*v00 + fw*v01) + fh*((1.f-fw)*v10 + fw*v11);
}

extern "C" void kernel_launch(void* const* d_in, const int* in_sizes, int n_in,
                              void* d_out, int out_size, void* d_ws, size_t ws_size,
                              hipStream_t stream){
  const int B = 2, C = 128, HW = 2304;
  const void* x_in        = d_in[0];
  const void* g1          = d_in[1];
  const void* b1          = d_in[2];
  const void* loc_qkv_w   = d_in[3];
  const void* loc_proj_w  = d_in[4];
  const void* loc_proj_b  = d_in[5];
  const void* glob_qkv_w  = d_in[6];
  const void* glob_proj_w = d_in[7];
  const void* glob_proj_b = d_in[8];
  const void* fuse_w1     = d_in[9];
  const void* fuse_b1     = d_in[10];
  const void* fuse_w2     = d_in[11];
  const void* fuse_b2     = d_in[12];
  const void* glat        = d_in[13];
  const void* blat        = d_in[14];
  const void* latents     = d_in[15];
  const void* qlat_w      = d_in[16];
  const void* kvx_w       = d_in[17];
  const void* qx_w        = d_in[18];
  const void* kvlat_w     = d_in[19];
  const void* lat_proj_w  = d_in[20];
  const void* lat_proj_b  = d_in[21];
  const void* g2          = d_in[22];
  const void* b2          = d_in[23];
  const void* ffn_w1      = d_in[24];
  const void* ffn_b1      = d_in[25];
  const void* ffn_w2      = d_in[26];
  const void* ffn_b2      = d_in[27];

  // ---- workspace layout VERBATIM (R8..R18) ----
  float* ws = (float*)d_ws;
  float* P  = ws + 0;
  float* N  = ws + 589824;
  float* A  = ws + 1179648;
  float* Q  = ws + 1769472;
  float* FLAG = ws + 4128768;

  float* qkv   = Q;                 // 1,769,472
  float* L     = Q + 1769472;       // 589,824
  float* xc    = Q;
  float* qkvc  = Q + 36864;
  float* gatt  = Q + 147456;
  float* gproj = Q + 184320;
  float* kvx   = Q;                 // 1,179,648
  float* latf  = Q + 1179648;
  float* qlat  = Q + 1181696;
  float* latr  = Q + 1185792;
  float* kvlat = Q + 1189888;
  float* part  = Q + 1198080;       // 221,184 (S=48)
  float* ffh   = Q;                 // 2,359,296

  dim3 blk(256);
  dim3 blk512(512);
  dim3 blk64(64);

  detect_k<<<1, 64, 0, stream>>>(x_in, FLAG);
  cvt_k<<<2304, blk, 0, stream>>>(x_in, P, 589824, FLAG);

  // ---- BioAttentionFusion branch ----
  ln2dw_k<<<dim3(36,B), blk, 0, stream>>>(P, g1, b1, N, C, HW, FLAG);
  convmfma_k<<<dim3(144,24,B), blk64, 0, stream>>>(N,(long)C*HW,C, nullptr,0,0, loc_qkv_w,nullptr,nullptr, qkv,0,384,HW,0, FLAG);
  normk_k<<<dim3(9,8,B), blk, 0, stream>>>(qkv, (long)384*HW, 128, HW);
  flat_mfma_k<<<dim3(36,8,B), blk512, 0, stream>>>(qkv,(long)384*HW,0, qkv,(long)384*HW,128,256, A,(long)C*HW, HW,HW,0.25f);
  convmfma_k<<<dim3(144,8,B), blk64, 0, stream>>>(A,(long)C*HW,C, nullptr,0,0, loc_proj_w,loc_proj_b,nullptr, L,0,C,HW,0, FLAG);
  pool4_k<<<144, blk, 0, stream>>>(N, xc);
  conv1x1_k<<<dim3(1,384,B), blk, 0, stream>>>(xc,(long)C*144,C, nullptr,0,0, glob_qkv_w,nullptr,nullptr, qkvc,0,384,144,0, FLAG);
  normk_k<<<dim3(1,8,B), blk, 0, stream>>>(qkvc, (long)384*144, 128, 144);
  attn4_k<<<dim3(3,8,B), blk, 0, stream>>>(qkvc,(long)384*144,0, qkvc,(long)384*144,128,256, gatt,(long)C*144, 144,144,0.25f);
  conv1x1_k<<<dim3(1,128,B), blk, 0, stream>>>(gatt,(long)C*144,C, nullptr,0,0, glob_proj_w,glob_proj_b,nullptr, gproj,0,C,144,0, FLAG);
  ups_k<<<2304, blk, 0, stream>>>(gproj, A);                                          // A = upsampled global
  convmfma_k<<<dim3(144,8,B), blk64, 0, stream>>>(L,(long)C*HW,C, A,(long)C*HW,C, fuse_w1,fuse_b1,nullptr, N,0,C,HW,1, FLAG);  // N = gelu(fuse1)
  convmfma_k<<<dim3(144,8,B), blk64, 0, stream>>>(N,(long)C*HW,C, nullptr,0,0, fuse_w2,fuse_b2,P, P,0,C,HW,0, FLAG);           // P = x + f

  // ---- LatentMixer branch ----
  ln2dw_k<<<dim3(36,B), blk, 0, stream>>>(P, glat, blat, N, C, HW, FLAG);
  convmfma_k<<<dim3(144,16,B), blk64, 0, stream>>>(N,(long)C*HW,C, nullptr,0,0, kvx_w,nullptr,nullptr, kvx,0,256,HW,0, FLAG);
  normk_k<<<dim3(9,8,B), blk, 0, stream>>>(kvx, (long)256*HW, 0, HW);
  convmfma_k<<<dim3(144,8,B), blk64, 0, stream>>>(N,(long)C*HW,C, nullptr,0,0, qx_w,nullptr,nullptr, A,0,C,HW,0, FLAG);        // A = qx
  cvt_k<<<8, blk, 0, stream>>>(latents, latf, 2048, FLAG);
  conv1x1_k<<<dim3(1,128,B), blk, 0, stream>>>(latf,0L,C, nullptr,0,0, qlat_w,nullptr,nullptr, qlat,0,C,16,0, FLAG);
  latpart_k<<<dim3(48,8,B), 64, 0, stream>>>(qlat, kvx, (long)256*HW, part, HW, 48);
  latcomb_k<<<1, blk, 0, stream>>>(part, latr, 48);
  conv1x1_k<<<dim3(1,256,B), blk, 0, stream>>>(latr,(long)C*16,C, nullptr,0,0, kvlat_w,nullptr,nullptr, kvlat,0,256,16,0, FLAG);
  normk_k<<<dim3(1,8,B), blk, 0, stream>>>(kvlat, (long)256*16, 0, 16);
  attn4_k<<<dim3(36,8,B), blk, 0, stream>>>(A,(long)C*HW,0, kvlat,(long)256*16,0,128, N,(long)C*HW, HW,16,0.25f);           // N = xw
  convmfma_k<<<dim3(144,8,B), blk64, 0, stream>>>(N,(long)C*HW,C, nullptr,0,0, lat_proj_w,lat_proj_b,P, P,0,C,HW,0, FLAG);     // P = x2

  // ---- FFN branch ----
  ln2dw_k<<<dim3(36,B), blk, 0, stream>>>(P, g2, b2, N, C, HW, FLAG);
  convmfma_k<<<dim3(144,32,B), blk64, 0, stream>>>(N,(long)C*HW,C, nullptr,0,0, ffn_w1,ffn_b1,nullptr, ffh,0,512,HW,1, FLAG);
  convmfma_k<<<dim3(144,8,B), blk64, 0, stream>>>(ffh,(long)512*HW,512, nullptr,0,0, ffn_w2,ffn_b2,P, d_out,1,C,HW,0, FLAG);
}

// Round 7
// 462.719 us; speedup vs baseline: 1.6291x; 1.1476x over previous
//
#include <hip/hip_runtime.h>
#include <hip/hip_bf16.h>

typedef __hip_bfloat16 bf16;
typedef _Float16 f16;
typedef _Float16 f16x4 __attribute__((ext_vector_type(4)));
typedef float f32x4 __attribute__((ext_vector_type(4)));

#define HD 16
#define TK 128
#define KP 20            // attn LDS pitch: 16 dims + 4 pad, keeps float4 16B-aligned
#define MINIT (-1e30f)

__device__ __forceinline__ float b2f(bf16 v){ return __bfloat162float(v); }
__device__ __forceinline__ float gelu_f(float x){ return 0.5f*x*(1.0f+erff(x*0.70710678118654752f)); }
__device__ __forceinline__ float rdv(const void* p, size_t i, bool bf){
  return bf ? b2f(((const bf16*)p)[i]) : ((const float*)p)[i];
}
__device__ __forceinline__ float4 ld4f(const void* p, size_t i, bool bf){
  if (bf){
    const bf16* q = (const bf16*)p + i;
    return make_float4(b2f(q[0]), b2f(q[1]), b2f(q[2]), b2f(q[3]));
  }
  return *(const float4*)((const float*)p + i);
}

// ---------------- dtype detector (R25: wave-parallel; was 1-thread serial 1536-load chain) ----------------
__global__ void detect_k(const void* __restrict__ x, float* __restrict__ flag){
  if (blockIdx.x != 0) return;
  int l = threadIdx.x;   // 64 lanes
  const float* xf = (const float*)x;
  const bf16*  xb = (const bf16*)x;
  float sF = 0.f, sB = 0.f;
  for (int i = l; i < 512; i += 64){ float v = fabsf(xf[i]);      if (!(v < 1e30f)) v = 1e30f; sF += v; }
  for (int i = l; i < 1024; i += 64){ float v = fabsf(b2f(xb[i])); if (!(v < 1e30f)) v = 1e30f; sB += v; }
  #pragma unroll
  for (int o = 32; o; o >>= 1){ sF += __shfl_xor(sF, o); sB += __shfl_xor(sB, o); }
  if (l == 0){
    float mF = sF/512.f, mB = sB/1024.f;
    float dF = fabsf(logf(fmaxf(mF, 1e-30f)));
    float dB = fabsf(logf(fmaxf(mB, 1e-30f)));
    *flag = (dB <= dF) ? 1.0f : 0.0f;
  }
}

// ---------------- input -> fp32 convert (proven) ----------------
__global__ void cvt_k(const void* __restrict__ in, float* __restrict__ out, int n,
                      const float* __restrict__ flagp){
  bool bf = *flagp > 0.5f;
  int i = blockIdx.x*blockDim.x + threadIdx.x;
  if (i < n) out[i] = rdv(in, i, bf);
}

// ---------------- wave-split LayerNorm (R25: 16 pixels/block -> 288 blocks, was 72) ----------------
__global__ __launch_bounds__(256) void ln2dw_k(
    const float* __restrict__ x, const void* __restrict__ g,
    const void* __restrict__ b, float* __restrict__ y,
    int C, int HW, const float* __restrict__ flagp)
{
  __shared__ float redS[16][16];
  __shared__ float redQ[16][16];
  bool bf = *flagp > 0.5f;
  int t = threadIdx.x, pix = t & 15, sub = t >> 4;   // 16 pixels x 16 subgroups of 8 ch
  int p  = blockIdx.x*16 + pix;
  int bb = blockIdx.y;
  const float* xb = x + (size_t)bb*C*HW + p;
  float xv[8];
  float s = 0.f, s2 = 0.f;
  #pragma unroll
  for (int i = 0; i < 8; i++){
    float v = xb[(size_t)(sub*8 + i)*HW];
    xv[i] = v; s += v; s2 += v*v;
  }
  redS[sub][pix] = s; redQ[sub][pix] = s2;
  __syncthreads();
  float st = 0.f, qt = 0.f;
  #pragma unroll
  for (int j = 0; j < 16; j++){ st += redS[j][pix]; qt += redQ[j][pix]; }
  float mu  = st / (float)C;
  float var = fmaxf(qt / (float)C - mu*mu, 0.f);
  float inv = rsqrtf(var + 1e-5f);
  float* yb = y + (size_t)bb*C*HW + p;
  #pragma unroll
  for (int i = 0; i < 8; i++){
    int c = sub*8 + i;
    yb[(size_t)c*HW] = (xv[i] - mu)*inv*rdv(g, c, bf) + rdv(b, c, bf);
  }
}

// ---------------- K pre-normalization (kept only for small conv1x1 outputs: qkvc, kvlat) ----------------
__global__ void normk_k(float* __restrict__ KV, long kbs, int koff, int NK){
  int p = blockIdx.x*blockDim.x + threadIdx.x;
  if (p >= NK) return;
  int h = blockIdx.y, bb = blockIdx.z;
  float* base = KV + (size_t)bb*kbs + (size_t)(koff + h*16)*NK + p;
  float v[16]; float s = 0.f;
  #pragma unroll
  for (int d = 0; d < 16; d++){ v[d] = base[(size_t)d*NK]; s += v[d]*v[d]; }
  float iv = 1.f / fmaxf(sqrtf(s), 1e-12f);
  #pragma unroll
  for (int d = 0; d < 16; d++) base[(size_t)d*NK] = v[d]*iv;
}

// ---------------- generic scalar 1x1 conv (R25: raw1 flag reads in1 via rdv — folds cvt) ----------------
__global__ void conv1x1_k(const float* __restrict__ in1, long in1_bs, int C1,
                          const float* __restrict__ in2, long in2_bs, int C2,
                          const void* __restrict__ w, const void* __restrict__ bias,
                          const float* __restrict__ res,
                          void* __restrict__ out, int to_out, int O, int NP, int act,
                          int raw1, const float* __restrict__ flagp){
  bool bf = *flagp > 0.5f;
  int p = blockIdx.x*blockDim.x + threadIdx.x;
  if (p >= NP) return;
  int o = blockIdx.y, bb = blockIdx.z;
  size_t wrow = (size_t)o*(C1 + C2);
  float acc = bias ? rdv(bias, o, bf) : 0.f;
  if (raw1){
    for (int c = 0; c < C1; c++)
      acc += rdv(w, wrow + c, bf) * rdv(in1, (size_t)bb*in1_bs + (size_t)c*NP + p, bf);
  } else {
    const float* i1 = in1 + (size_t)bb*in1_bs + p;
    for (int c = 0; c < C1; c++) acc += rdv(w, wrow + c, bf) * i1[(size_t)c*NP];
  }
  if (in2){
    const float* i2 = in2 + (size_t)bb*in2_bs + p;
    for (int c = 0; c < C2; c++) acc += rdv(w, wrow + C1 + c, bf) * i2[(size_t)c*NP];
  }
  if (act == 1) acc = gelu_f(acc);
  if (res) acc += res[((size_t)bb*O + o)*NP + p];
  size_t oi = ((size_t)bb*O + o)*NP + p;
  if (to_out){
    if (bf) ((bf16*)out)[oi] = __float2bfloat16(acc);
    else    ((float*)out)[oi] = acc;
  } else {
    ((float*)out)[oi] = acc;
  }
}

// ---------------- MFMA 1x1-conv GEMM (R24 16o x 16p; R25: fused K-norm) ----------------
// When nlo <= o0 < nhi, the block's 16-o tile is exactly one head's K group: normalize
// columns to unit length before store (shfl_xor over the 4 lg groups = sum over 16 o).
// Bit-equivalent to the separate normk pass (same f32 conv outputs, same math). Only used
// on convs with no bias/act/res in the normalized range (qkv K, kvx K).
__global__ __launch_bounds__(64) void convmfma_k(
    const float* __restrict__ in1, long in1_bs, int C1,
    const float* __restrict__ in2, long in2_bs, int C2,
    const void* __restrict__ w, const void* __restrict__ bias,
    const float* __restrict__ res, void* __restrict__ out, int to_out,
    int O, int NP, int act, int nlo, int nhi, const float* __restrict__ flagp)
{
  bool bf = *flagp > 0.5f;
  int lane = threadIdx.x;
  int lm = lane & 15, lg = lane >> 4;
  int p0 = blockIdx.x*16, o0 = blockIdx.y*16, bb = blockIdx.z;
  int CW = C1 + C2;
  f32x4 d; d[0]=0.f; d[1]=0.f; d[2]=0.f; d[3]=0.f;
  const float* x1 = in1 + (size_t)bb*in1_bs + p0 + lm;
  const float* x2 = in2 ? (in2 + (size_t)bb*in2_bs + p0 + lm) : nullptr;
  #pragma unroll 8
  for (int kc = 0; kc < CW; kc += 16){
    f16x4 xb;
    #pragma unroll
    for (int i = 0; i < 4; i++){
      int c = kc + lg*4 + i;
      float v = (c < C1) ? x1[(size_t)c*NP] : x2[(size_t)(c - C1)*NP];
      xb[i] = (f16)v;
    }
    float4 wv = ld4f(w, (size_t)(o0 + lm)*CW + kc + lg*4, bf);
    f16x4 wa; wa[0]=(f16)wv.x; wa[1]=(f16)wv.y; wa[2]=(f16)wv.z; wa[3]=(f16)wv.w;
    d = __builtin_amdgcn_mfma_f32_16x16x16f16(wa, xb, d, 0, 0, 0);
  }
  if (o0 >= nlo && o0 < nhi){
    float ss = d[0]*d[0] + d[1]*d[1] + d[2]*d[2] + d[3]*d[3];
    ss += __shfl_xor(ss, 16); ss += __shfl_xor(ss, 32);
    float iv = 1.f / fmaxf(sqrtf(ss), 1e-12f);
    d[0]*=iv; d[1]*=iv; d[2]*=iv; d[3]*=iv;
  }
  #pragma unroll
  for (int r = 0; r < 4; r++){
    int o = o0 + lg*4 + r;
    float v = d[r] + (bias ? rdv(bias, o, bf) : 0.f);
    if (act == 1) v = gelu_f(v);
    size_t oi = ((size_t)bb*O + o)*NP + p0 + lm;
    if (res) v += res[oi];
    if (to_out && bf) ((bf16*)out)[oi] = __float2bfloat16(v);
    else              ((float*)out)[oi] = v;
  }
}

// ---------------- MFMA flash cosine attention (local attn, d=16) ----------------
// R22 (proven): S^T = mfma(A=K, B=Q^T); C layout == PV B-frag layout -> P feeds PV with zero
// cross-lane movement. V channel-major == V^T. No-max softmax. K pre-normalized.
__global__ __launch_bounds__(512) void flat_mfma_k(
    const float* __restrict__ Q, long qbs, int qoff,
    const float* __restrict__ KV, long kbs, int koff, int voff,
    float* __restrict__ Out, long obs, int NQ, int NK, float scale)
{
  __shared__ float OS[8*4*16*17];   // [wave][qt][q][d] pitch 17
  __shared__ float LS[8*4*16];      // [wave][qt][q]
  int t = threadIdx.x, lane = t & 63, wv = t >> 6;
  int h = blockIdx.y, bb = blockIdx.z;
  int qb = blockIdx.x*64;
  int lm = lane & 15, lg = lane >> 4;          // m/n index, k-group
  const float* qp  = Q  + (size_t)bb*qbs;
  const float* kvb = KV + (size_t)bb*kbs;
  f16x4 qf[4];
  #pragma unroll
  for (int qt = 0; qt < 4; qt++){
    float qv[4]; float ss = 0.f;
    #pragma unroll
    for (int i = 0; i < 4; i++){
      qv[i] = qp[(size_t)(qoff + h*16 + lg*4 + i)*NQ + qb + qt*16 + lm];
      ss += qv[i]*qv[i];
    }
    ss += __shfl_xor(ss, 16); ss += __shfl_xor(ss, 32);
    float inv = scale / fmaxf(sqrtf(ss), 1e-12f);
    #pragma unroll
    for (int i = 0; i < 4; i++) qf[qt][i] = (f16)(qv[i]*inv);
  }
  f32x4 of[4];
  float ls[4];
  #pragma unroll
  for (int qt = 0; qt < 4; qt++){
    of[qt][0]=0.f; of[qt][1]=0.f; of[qt][2]=0.f; of[qt][3]=0.f; ls[qt]=0.f;
  }
  int chunk = NK >> 3;
  int p0 = wv*chunk, p1 = p0 + chunk;
  const float* kc = kvb + (size_t)(koff + h*16)*NK;
  const float* vc = kvb + (size_t)(voff + h*16)*NK;
  for (int pos = p0; pos < p1; pos += 16){
    f16x4 kf;
    #pragma unroll
    for (int i = 0; i < 4; i++)
      kf[i] = (f16)kc[(size_t)(lg*4 + i)*NK + pos + lm];
    float4 vvv = *(const float4*)&vc[(size_t)lm*NK + pos + lg*4];
    f16x4 vf; vf[0]=(f16)vvv.x; vf[1]=(f16)vvv.y; vf[2]=(f16)vvv.z; vf[3]=(f16)vvv.w;
    #pragma unroll
    for (int qt = 0; qt < 4; qt++){
      f32x4 s; s[0]=0.f; s[1]=0.f; s[2]=0.f; s[3]=0.f;
      s = __builtin_amdgcn_mfma_f32_16x16x16f16(kf, qf[qt], s, 0, 0, 0);
      f16x4 pf;
      #pragma unroll
      for (int r = 0; r < 4; r++){
        float pp = __expf(s[r]);
        ls[qt] += pp;
        pf[r] = (f16)pp;
      }
      of[qt] = __builtin_amdgcn_mfma_f32_16x16x16f16(vf, pf, of[qt], 0, 0, 0);
    }
  }
  #pragma unroll
  for (int qt = 0; qt < 4; qt++){
    ls[qt] += __shfl_xor(ls[qt], 16);
    ls[qt] += __shfl_xor(ls[qt], 32);
    #pragma unroll
    for (int r = 0; r < 4; r++)
      OS[((wv*4 + qt)*16 + lm)*17 + lg*4 + r] = of[qt][r];
    if (lg == 0) LS[(wv*4 + qt)*16 + lm] = ls[qt];
  }
  __syncthreads();
  #pragma unroll
  for (int rep = 0; rep < 2; rep++){
    int o = t + rep*512;
    int d = o >> 6, qq = o & 63;
    int qt = qq >> 4, q = qq & 15;
    float acc = 0.f, lsum = 0.f;
    #pragma unroll
    for (int w = 0; w < 8; w++){
      acc  += OS[((w*4 + qt)*16 + q)*17 + d];
      lsum += LS[(w*4 + qt)*16 + q];
    }
    Out[(size_t)bb*obs + (size_t)(h*16 + d)*NQ + qb + qq] = acc / fmaxf(lsum, 1e-30f);
  }
}

// ---------------- attn4, no-max (global attn NK=144 and xw attention NK=16) ----------------
__global__ __launch_bounds__(256) void attn4_k(
    const float* __restrict__ Q, long qbs, int qoff,
    const float* __restrict__ KV, long kbs, int koff, int voff,
    float* __restrict__ Out, long obs, int NQ, int NK, float scale)
{
  __shared__ __align__(16) float Ks[TK*KP];
  __shared__ __align__(16) float Vs[TK*KP];
  int tid = threadIdx.x;
  int sub = tid & 3;
  int h = blockIdx.y, bb = blockIdx.z;
  int qi = blockIdx.x*64 + (tid >> 2);
  bool qv = qi < NQ;
  float qn[4] = {0,0,0,0}, acc[4] = {0,0,0,0};
  float l = 0.f;
  if (qv){
    float s = 0.f;
    #pragma unroll
    for (int j = 0; j < 4; j++){
      qn[j] = Q[(size_t)bb*qbs + (size_t)(qoff + h*16 + sub*4 + j)*NQ + qi];
      s += qn[j]*qn[j];
    }
    s += __shfl_xor(s, 1); s += __shfl_xor(s, 2);
    float inv = scale / fmaxf(sqrtf(s), 1e-12f);
    #pragma unroll
    for (int j = 0; j < 4; j++) qn[j] *= inv;
  }
  for (int k0 = 0; k0 < NK; k0 += TK){
    int lim = min(TK, NK - k0);
    for (int i = tid; i < 16*TK; i += 256){
      int pos = i & (TK-1), d = i >> 7;
      if (pos < lim){
        Ks[pos*KP + d] = KV[(size_t)bb*kbs + (size_t)(koff + h*16 + d)*NK + k0 + pos];
        Vs[pos*KP + d] = KV[(size_t)bb*kbs + (size_t)(voff + h*16 + d)*NK + k0 + pos];
      }
    }
    __syncthreads();
    for (int pos = 0; pos < lim; pos++){
      float4 k4 = *(const float4*)&Ks[pos*KP + sub*4];
      float dd = qn[0]*k4.x + qn[1]*k4.y + qn[2]*k4.z + qn[3]*k4.w;
      dd += __shfl_xor(dd, 1); dd += __shfl_xor(dd, 2);
      float pp = __expf(dd);
      l += pp;
      float4 v4 = *(const float4*)&Vs[pos*KP + sub*4];
      acc[0] += pp*v4.x;
      acc[1] += pp*v4.y;
      acc[2] += pp*v4.z;
      acc[3] += pp*v4.w;
    }
    __syncthreads();
  }
  if (qv){
    float li = 1.f / fmaxf(l, 1e-30f);
    #pragma unroll
    for (int j = 0; j < 4; j++)
      Out[(size_t)bb*obs + (size_t)(h*16 + sub*4 + j)*NQ + qi] = acc[j]*li;
  }
}

// ---------------- latent-read attention, split-K partials ----------------
__global__ void latpart_k(const float* __restrict__ ql, const float* __restrict__ kvx,
                          long kbs, float* __restrict__ part, int NK, int S){
  int s = blockIdx.x, h = blockIdx.y, bb = blockIdx.z;
  int t = threadIdx.x;
  int q = t & 15, sub = (t >> 4) & 3;
  float qn[16]; float ss = 0.f;
  #pragma unroll
  for (int d = 0; d < 16; d++){
    qn[d] = ql[(size_t)bb*2048 + (size_t)(h*16+d)*16 + q];
    ss += qn[d]*qn[d];
  }
  float inv = 0.25f / fmaxf(sqrtf(ss), 1e-12f);
  #pragma unroll
  for (int d = 0; d < 16; d++) qn[d] *= inv;
  float l = 0.f, acc[16];
  #pragma unroll
  for (int d = 0; d < 16; d++) acc[d] = 0.f;
  int chunk = NK / S, c4 = chunk >> 2;
  int k0 = s*chunk + sub*c4, k1 = k0 + c4;
  const float* kb = kvx + (size_t)bb*kbs;
  for (int pos = k0; pos < k1; pos++){
    float dot = 0.f;
    #pragma unroll
    for (int d = 0; d < 16; d++) dot += qn[d]*kb[(size_t)(h*16+d)*NK + pos];
    float pp = __expf(dot);
    l += pp;
    #pragma unroll
    for (int d = 0; d < 16; d++)
      acc[d] += pp*kb[(size_t)(128 + h*16+d)*NK + pos];
  }
  l += __shfl_xor(l, 16); l += __shfl_xor(l, 32);
  #pragma unroll
  for (int d = 0; d < 16; d++){
    acc[d] += __shfl_xor(acc[d], 16);
    acc[d] += __shfl_xor(acc[d], 32);
  }
  if ((t >> 4) == 0){
    size_t idx = (size_t)((((bb*8 + h)*16 + q)*S) + s)*18;
    part[idx] = l;
    #pragma unroll
    for (int d = 0; d < 16; d++) part[idx+1+d] = acc[d];
  }
}

// R25: widened — one thread per (bb,h,q,d); L re-summed per lane in identical order.
__global__ void latcomb_k(const float* __restrict__ part, float* __restrict__ latr, int S){
  int i = blockIdx.x*blockDim.x + threadIdx.x;   // 4096 total
  int d = i & 15, q = (i >> 4) & 15, h = (i >> 8) & 7, bb = i >> 11;
  size_t base = (size_t)(((bb*8 + h)*16 + q)*S)*18;
  float L = 0.f, a = 0.f;
  for (int s = 0; s < S; s++){
    const float* ps = part + base + (size_t)s*18;
    L += ps[0];
    a += ps[1+d];
  }
  latr[(size_t)bb*2048 + (size_t)(h*16+d)*16 + q] = a / fmaxf(L, 1e-30f);
}

// ---------------- 4x4 mean pool (proven) ----------------
__global__ void pool4_k(const float* __restrict__ xn, float* __restrict__ xc){
  int i = blockIdx.x*blockDim.x + threadIdx.x;
  if (i >= 2*128*144) return;
  int pc = i % 144; int bc = i / 144;
  int hc = pc / 12, wc = pc % 12;
  const float* s = xn + (size_t)bc*2304 + hc*4*48 + wc*4;
  float acc = 0.f;
  #pragma unroll
  for (int r = 0; r < 4; r++)
    #pragma unroll
    for (int c2 = 0; c2 < 4; c2++) acc += s[r*48 + c2];
  xc[i] = acc * 0.0625f;
}

// ---------------- bilinear upsample 12->48 (proven) ----------------
__global__ void ups_k(const float* __restrict__ g, float* __restrict__ out){
  int i = blockIdx.x*blockDim.x + threadIdx.x;
  if (i >= 2*128*2304) return;
  int p = i % 2304; int bc = i / 2304;
  int h = p / 48, w = p % 48;
  float sh = h*0.25f - 0.375f;
  float sw = w*0.25f - 0.375f;
  float fh0 = floorf(sh), fw0 = floorf(sw);
  float fh = sh - fh0, fw = sw - fw0;
  int h0 = (int)fh0, w0 = (int)fw0;
  int h0c = min(11, max(0, h0)),   h1c = min(11, max(0, h0+1));
  int w0c = min(11, max(0, w0)),   w1c = min(11, max(0, w0+1));
  const float* s = g + (size_t)bc*144;
  float v00 = s[h0c*12 + w0c], v01 = s[h0c*12 + w1c];
  float v10 = s[h1c*12 + w0c], v11 = s[h1c*12 + w1c];
  out[i] = (1.f-fh)*((1.f-fw)*v00 + fw*v01) + fh*((1.f-fw)*v10 + fw*v11);
}

extern "C" void kernel_launch(void* const* d_in, const int* in_sizes, int n_in,
                              void* d_out, int out_size, void* d_ws, size_t ws_size,
                              hipStream_t stream){
  const int B = 2, C = 128, HW = 2304;
  const void* x_in        = d_in[0];
  const void* g1          = d_in[1];
  const void* b1          = d_in[2];
  const void* loc_qkv_w   = d_in[3];
  const void* loc_proj_w  = d_in[4];
  const void* loc_proj_b  = d_in[5];
  const void* glob_qkv_w  = d_in[6];
  const void* glob_proj_w = d_in[7];
  const void* glob_proj_b = d_in[8];
  const void* fuse_w1     = d_in[9];
  const void* fuse_b1     = d_in[10];
  const void* fuse_w2     = d_in[11];
  const void* fuse_b2     = d_in[12];
  const void* glat        = d_in[13];
  const void* blat        = d_in[14];
  const void* latents     = d_in[15];
  const void* qlat_w      = d_in[16];
  const void* kvx_w       = d_in[17];
  const void* qx_w        = d_in[18];
  const void* kvlat_w     = d_in[19];
  const void* lat_proj_w  = d_in[20];
  const void* lat_proj_b  = d_in[21];
  const void* g2          = d_in[22];
  const void* b2          = d_in[23];
  const void* ffn_w1      = d_in[24];
  const void* ffn_b1      = d_in[25];
  const void* ffn_w2      = d_in[26];
  const void* ffn_b2      = d_in[27];

  // ---- workspace layout VERBATIM (R8..R18) ----
  float* ws = (float*)d_ws;
  float* P  = ws + 0;
  float* N  = ws + 589824;
  float* A  = ws + 1179648;
  float* Q  = ws + 1769472;
  float* FLAG = ws + 4128768;

  float* qkv   = Q;                 // 1,769,472
  float* L     = Q + 1769472;       // 589,824
  float* xc    = Q;
  float* qkvc  = Q + 36864;
  float* gatt  = Q + 147456;
  float* gproj = Q + 184320;
  float* kvx   = Q;                 // 1,179,648
  float* qlat  = Q + 1181696;
  float* latr  = Q + 1185792;
  float* kvlat = Q + 1189888;
  float* part  = Q + 1198080;       // 221,184 (S=48)
  float* ffh   = Q;                 // 2,359,296

  dim3 blk(256);
  dim3 blk512(512);
  dim3 blk64(64);

  detect_k<<<1, 64, 0, stream>>>(x_in, FLAG);
  cvt_k<<<2304, blk, 0, stream>>>(x_in, P, 589824, FLAG);

  // ---- BioAttentionFusion branch ----
  ln2dw_k<<<dim3(144,B), blk, 0, stream>>>(P, g1, b1, N, C, HW, FLAG);
  convmfma_k<<<dim3(144,24,B), blk64, 0, stream>>>(N,(long)C*HW,C, nullptr,0,0, loc_qkv_w,nullptr,nullptr, qkv,0,384,HW,0, 128,256, FLAG);
  flat_mfma_k<<<dim3(36,8,B), blk512, 0, stream>>>(qkv,(long)384*HW,0, qkv,(long)384*HW,128,256, A,(long)C*HW, HW,HW,0.25f);
  convmfma_k<<<dim3(144,8,B), blk64, 0, stream>>>(A,(long)C*HW,C, nullptr,0,0, loc_proj_w,loc_proj_b,nullptr, L,0,C,HW,0, 0,0, FLAG);
  pool4_k<<<144, blk, 0, stream>>>(N, xc);
  conv1x1_k<<<dim3(1,384,B), blk, 0, stream>>>(xc,(long)C*144,C, nullptr,0,0, glob_qkv_w,nullptr,nullptr, qkvc,0,384,144,0, 0, FLAG);
  normk_k<<<dim3(1,8,B), blk, 0, stream>>>(qkvc, (long)384*144, 128, 144);
  attn4_k<<<dim3(3,8,B), blk, 0, stream>>>(qkvc,(long)384*144,0, qkvc,(long)384*144,128,256, gatt,(long)C*144, 144,144,0.25f);
  conv1x1_k<<<dim3(1,128,B), blk, 0, stream>>>(gatt,(long)C*144,C, nullptr,0,0, glob_proj_w,glob_proj_b,nullptr, gproj,0,C,144,0, 0, FLAG);
  ups_k<<<2304, blk, 0, stream>>>(gproj, A);                                          // A = upsampled global
  convmfma_k<<<dim3(144,8,B), blk64, 0, stream>>>(L,(long)C*HW,C, A,(long)C*HW,C, fuse_w1,fuse_b1,nullptr, N,0,C,HW,1, 0,0, FLAG);  // N = gelu(fuse1)
  convmfma_k<<<dim3(144,8,B), blk64, 0, stream>>>(N,(long)C*HW,C, nullptr,0,0, fuse_w2,fuse_b2,P, P,0,C,HW,0, 0,0, FLAG);           // P = x + f

  // ---- LatentMixer branch ----
  ln2dw_k<<<dim3(144,B), blk, 0, stream>>>(P, glat, blat, N, C, HW, FLAG);
  convmfma_k<<<dim3(144,16,B), blk64, 0, stream>>>(N,(long)C*HW,C, nullptr,0,0, kvx_w,nullptr,nullptr, kvx,0,256,HW,0, 0,128, FLAG);
  convmfma_k<<<dim3(144,8,B), blk64, 0, stream>>>(N,(long)C*HW,C, nullptr,0,0, qx_w,nullptr,nullptr, A,0,C,HW,0, 0,0, FLAG);        // A = qx
  conv1x1_k<<<dim3(1,128,B), blk, 0, stream>>>((const float*)latents,0L,C, nullptr,0,0, qlat_w,nullptr,nullptr, qlat,0,C,16,0, 1, FLAG);
  latpart_k<<<dim3(48,8,B), 64, 0, stream>>>(qlat, kvx, (long)256*HW, part, HW, 48);
  latcomb_k<<<16, blk, 0, stream>>>(part, latr, 48);
  conv1x1_k<<<dim3(1,256,B), blk, 0, stream>>>(latr,(long)C*16,C, nullptr,0,0, kvlat_w,nullptr,nullptr, kvlat,0,256,16,0, 0, FLAG);
  normk_k<<<dim3(1,8,B), blk, 0, stream>>>(kvlat, (long)256*16, 0, 16);
  attn4_k<<<dim3(36,8,B), blk, 0, stream>>>(A,(long)C*HW,0, kvlat,(long)256*16,0,128, N,(long)C*HW, HW,16,0.25f);           // N = xw
  convmfma_k<<<dim3(144,8,B), blk64, 0, stream>>>(N,(long)C*HW,C, nullptr,0,0, lat_proj_w,lat_proj_b,P, P,0,C,HW,0, 0,0, FLAG);     // P = x2

  // ---- FFN branch ----
  ln2dw_k<<<dim3(144,B), blk, 0, stream>>>(P, g2, b2, N, C, HW, FLAG);
  convmfma_k<<<dim3(144,32,B), blk64, 0, stream>>>(N,(long)C*HW,C, nullptr,0,0, ffn_w1,ffn_b1,nullptr, ffh,0,512,HW,1, 0,0, FLAG);
  convmfma_k<<<dim3(144,8,B), blk64, 0, stream>>>(ffh,(long)512*HW,512, nullptr,0,0, ffn_w2,ffn_b2,P, d_out,1,C,HW,0, 0,0, FLAG);
}

// Round 8
// 437.997 us; speedup vs baseline: 1.7211x; 1.0564x over previous
//
#include <hip/hip_runtime.h>
#include <hip/hip_bf16.h>

typedef __hip_bfloat16 bf16;
typedef _Float16 f16;
typedef _Float16 f16x4 __attribute__((ext_vector_type(4)));
typedef float f32x4 __attribute__((ext_vector_type(4)));

#define HD 16
#define TK 128
#define KP 20
#define MINIT (-1e30f)

__device__ __forceinline__ float b2f(bf16 v){ return __bfloat162float(v); }
__device__ __forceinline__ float gelu_f(float x){ return 0.5f*x*(1.0f+erff(x*0.70710678118654752f)); }
__device__ __forceinline__ float rdv(const void* p, size_t i, bool bf){
  return bf ? b2f(((const bf16*)p)[i]) : ((const float*)p)[i];
}
__device__ __forceinline__ float4 ld4f(const void* p, size_t i, bool bf){
  if (bf){
    const bf16* q = (const bf16*)p + i;
    return make_float4(b2f(q[0]), b2f(q[1]), b2f(q[2]), b2f(q[3]));
  }
  return *(const float4*)((const float*)p + i);
}

// ---------------- dtype detector (wave-parallel, proven R25) ----------------
__global__ void detect_k(const void* __restrict__ x, float* __restrict__ flag){
  if (blockIdx.x != 0) return;
  int l = threadIdx.x;
  const float* xf = (const float*)x;
  const bf16*  xb = (const bf16*)x;
  float sF = 0.f, sB = 0.f;
  for (int i = l; i < 512; i += 64){ float v = fabsf(xf[i]);      if (!(v < 1e30f)) v = 1e30f; sF += v; }
  for (int i = l; i < 1024; i += 64){ float v = fabsf(b2f(xb[i])); if (!(v < 1e30f)) v = 1e30f; sB += v; }
  #pragma unroll
  for (int o = 32; o; o >>= 1){ sF += __shfl_xor(sF, o); sB += __shfl_xor(sB, o); }
  if (l == 0){
    float mF = sF/512.f, mB = sB/1024.f;
    float dF = fabsf(logf(fmaxf(mF, 1e-30f)));
    float dB = fabsf(logf(fmaxf(mB, 1e-30f)));
    *flag = (dB <= dF) ? 1.0f : 0.0f;
  }
}

// ---------------- input -> fp32 convert (proven) ----------------
__global__ void cvt_k(const void* __restrict__ in, float* __restrict__ out, int n,
                      const float* __restrict__ flagp){
  bool bf = *flagp > 0.5f;
  int i = blockIdx.x*blockDim.x + threadIdx.x;
  if (i < n) out[i] = rdv(in, i, bf);
}

// ---------------- wave-split LayerNorm (proven; only branch1 needs materialized N) ----------------
__global__ __launch_bounds__(256) void ln2dw_k(
    const float* __restrict__ x, const void* __restrict__ g,
    const void* __restrict__ b, float* __restrict__ y,
    int C, int HW, const float* __restrict__ flagp)
{
  __shared__ float redS[16][16];
  __shared__ float redQ[16][16];
  bool bf = *flagp > 0.5f;
  int t = threadIdx.x, pix = t & 15, sub = t >> 4;
  int p  = blockIdx.x*16 + pix;
  int bb = blockIdx.y;
  const float* xb = x + (size_t)bb*C*HW + p;
  float xv[8];
  float s = 0.f, s2 = 0.f;
  #pragma unroll
  for (int i = 0; i < 8; i++){
    float v = xb[(size_t)(sub*8 + i)*HW];
    xv[i] = v; s += v; s2 += v*v;
  }
  redS[sub][pix] = s; redQ[sub][pix] = s2;
  __syncthreads();
  float st = 0.f, qt = 0.f;
  #pragma unroll
  for (int j = 0; j < 16; j++){ st += redS[j][pix]; qt += redQ[j][pix]; }
  float mu  = st / (float)C;
  float var = fmaxf(qt / (float)C - mu*mu, 0.f);
  float inv = rsqrtf(var + 1e-5f);
  float* yb = y + (size_t)bb*C*HW + p;
  #pragma unroll
  for (int i = 0; i < 8; i++){
    int c = sub*8 + i;
    yb[(size_t)c*HW] = (xv[i] - mu)*inv*rdv(g, c, bf) + rdv(b, c, bf);
  }
}

// ---------------- generic scalar 1x1 conv (qlat only: raw latents, NP=16) ----------------
__global__ void conv1x1_k(const float* __restrict__ in1, long in1_bs, int C1,
                          const float* __restrict__ in2, long in2_bs, int C2,
                          const void* __restrict__ w, const void* __restrict__ bias,
                          const float* __restrict__ res,
                          void* __restrict__ out, int to_out, int O, int NP, int act,
                          int raw1, const float* __restrict__ flagp){
  bool bf = *flagp > 0.5f;
  int p = blockIdx.x*blockDim.x + threadIdx.x;
  if (p >= NP) return;
  int o = blockIdx.y, bb = blockIdx.z;
  size_t wrow = (size_t)o*(C1 + C2);
  float acc = bias ? rdv(bias, o, bf) : 0.f;
  if (raw1){
    for (int c = 0; c < C1; c++)
      acc += rdv(w, wrow + c, bf) * rdv(in1, (size_t)bb*in1_bs + (size_t)c*NP + p, bf);
  } else {
    const float* i1 = in1 + (size_t)bb*in1_bs + p;
    for (int c = 0; c < C1; c++) acc += rdv(w, wrow + c, bf) * i1[(size_t)c*NP];
  }
  if (in2){
    const float* i2 = in2 + (size_t)bb*in2_bs + p;
    for (int c = 0; c < C2; c++) acc += rdv(w, wrow + C1 + c, bf) * i2[(size_t)c*NP];
  }
  if (act == 1) acc = gelu_f(acc);
  if (res) acc += res[((size_t)bb*O + o)*NP + p];
  size_t oi = ((size_t)bb*O + o)*NP + p;
  if (to_out){
    if (bf) ((bf16*)out)[oi] = __float2bfloat16(acc);
    else    ((float*)out)[oi] = acc;
  } else {
    ((float*)out)[oi] = acc;
  }
}

// ---------------- MFMA 1x1-conv GEMM (R24 16o x 16p; R26: +lnf/pool/ups2 fusion flags) ----------------
// lnf : in1 is RAW pre-LN tensor; per-pixel mean/var computed inline (stride-4 channel sweep
//       + shfl_xor(16,32) = full-C sum), normalize with gamma/beta on the fly.
// pool: in1 X-element = 4x4 mean (NP=144 coarse, in1 fine 48x48) — replaces pool4+conv.
// ups2: in2 read via inline bilinear 12x12 -> 48x48 (gproj layout, stride 144).
// nlo/nhi: fused unit-norm of a head-aligned 16-o output tile (proven R25).
// All flags are wave-uniform SGPR branches. f32 accumulate. NP%16==0, O%16==0, CW%16==0.
__global__ __launch_bounds__(64) void convmfma_k(
    const float* __restrict__ in1, long in1_bs, int C1,
    const float* __restrict__ in2, long in2_bs, int C2,
    const void* __restrict__ w, const void* __restrict__ bias,
    const float* __restrict__ res, void* __restrict__ out, int to_out,
    int O, int NP, int act, int nlo, int nhi,
    int lnf, const void* __restrict__ lng, const void* __restrict__ lnb,
    int pool, int ups2, const float* __restrict__ flagp)
{
  bool bf = *flagp > 0.5f;
  int lane = threadIdx.x;
  int lm = lane & 15, lg = lane >> 4;
  int p0 = blockIdx.x*16, o0 = blockIdx.y*16, bb = blockIdx.z;
  int CW = C1 + C2;
  const float* x1 = in1 + (size_t)bb*in1_bs + p0 + lm;
  const float* x2b = in2 ? (in2 + (size_t)bb*in2_bs) : nullptr;
  // ups2 per-lane bilinear constants
  float fh = 0.f, fw = 0.f; int i00=0, i01=0, i10=0, i11=0;
  if (ups2){
    int p = p0 + lm; int hh = p/48, ww = p%48;
    float sh = hh*0.25f - 0.375f, sw = ww*0.25f - 0.375f;
    float fh0 = floorf(sh), fw0 = floorf(sw);
    fh = sh - fh0; fw = sw - fw0;
    int h0 = (int)fh0, w0 = (int)fw0;
    int h0c = min(11, max(0, h0)), h1c = min(11, max(0, h0+1));
    int w0c = min(11, max(0, w0)), w1c = min(11, max(0, w0+1));
    i00 = h0c*12 + w0c; i01 = h0c*12 + w1c; i10 = h1c*12 + w0c; i11 = h1c*12 + w1c;
  }
  // pool per-lane fine base
  const float* pN = nullptr;
  if (pool){
    int pc = p0 + lm; int hc = pc/12, wc = pc%12;
    pN = in1 + (size_t)bb*in1_bs + hc*192 + wc*4;
  }
  // inline LayerNorm stats (pixel = lm; lg groups cover c = lg, lg+4, ...)
  float mu = 0.f, linv = 0.f;
  if (lnf){
    float s = 0.f, s2 = 0.f;
    for (int c = lg; c < CW; c += 4){ float v = x1[(size_t)c*NP]; s += v; s2 += v*v; }
    s  += __shfl_xor(s, 16);  s  += __shfl_xor(s, 32);
    s2 += __shfl_xor(s2, 16); s2 += __shfl_xor(s2, 32);
    mu = s / (float)CW;
    float var = fmaxf(s2/(float)CW - mu*mu, 0.f);
    linv = rsqrtf(var + 1e-5f);
  }
  f32x4 d; d[0]=0.f; d[1]=0.f; d[2]=0.f; d[3]=0.f;
  #pragma unroll 4
  for (int kc = 0; kc < CW; kc += 16){
    f16x4 xb;
    #pragma unroll
    for (int i = 0; i < 4; i++){
      int c = kc + lg*4 + i;
      float v;
      if (pool){
        const float* s = pN + (size_t)c*2304;
        float a = 0.f;
        #pragma unroll
        for (int r = 0; r < 4; r++)
          #pragma unroll
          for (int cc = 0; cc < 4; cc++) a += s[r*48 + cc];
        v = a * 0.0625f;
      } else if (c < C1){
        v = x1[(size_t)c*NP];
        if (lnf) v = (v - mu)*linv*rdv(lng, c, bf) + rdv(lnb, c, bf);
      } else {
        int c2 = c - C1;
        if (ups2){
          const float* s = x2b + (size_t)c2*144;
          v = (1.f-fh)*((1.f-fw)*s[i00] + fw*s[i01]) + fh*((1.f-fw)*s[i10] + fw*s[i11]);
        } else {
          v = x2b[(size_t)c2*NP + p0 + lm];
        }
      }
      xb[i] = (f16)v;
    }
    float4 wv = ld4f(w, (size_t)(o0 + lm)*CW + kc + lg*4, bf);
    f16x4 wa; wa[0]=(f16)wv.x; wa[1]=(f16)wv.y; wa[2]=(f16)wv.z; wa[3]=(f16)wv.w;
    d = __builtin_amdgcn_mfma_f32_16x16x16f16(wa, xb, d, 0, 0, 0);
  }
  if (o0 >= nlo && o0 < nhi){
    float ss = d[0]*d[0] + d[1]*d[1] + d[2]*d[2] + d[3]*d[3];
    ss += __shfl_xor(ss, 16); ss += __shfl_xor(ss, 32);
    float iv = 1.f / fmaxf(sqrtf(ss), 1e-12f);
    d[0]*=iv; d[1]*=iv; d[2]*=iv; d[3]*=iv;
  }
  #pragma unroll
  for (int r = 0; r < 4; r++){
    int o = o0 + lg*4 + r;
    float v = d[r] + (bias ? rdv(bias, o, bf) : 0.f);
    if (act == 1) v = gelu_f(v);
    size_t oi = ((size_t)bb*O + o)*NP + p0 + lm;
    if (res) v += res[oi];
    if (to_out && bf) ((bf16*)out)[oi] = __float2bfloat16(v);
    else              ((float*)out)[oi] = v;
  }
}

// ---------------- MFMA flash cosine attention (local attn, d=16; proven R22) ----------------
__global__ __launch_bounds__(512) void flat_mfma_k(
    const float* __restrict__ Q, long qbs, int qoff,
    const float* __restrict__ KV, long kbs, int koff, int voff,
    float* __restrict__ Out, long obs, int NQ, int NK, float scale)
{
  __shared__ float OS[8*4*16*17];
  __shared__ float LS[8*4*16];
  int t = threadIdx.x, lane = t & 63, wv = t >> 6;
  int h = blockIdx.y, bb = blockIdx.z;
  int qb = blockIdx.x*64;
  int lm = lane & 15, lg = lane >> 4;
  const float* qp  = Q  + (size_t)bb*qbs;
  const float* kvb = KV + (size_t)bb*kbs;
  f16x4 qf[4];
  #pragma unroll
  for (int qt = 0; qt < 4; qt++){
    float qv[4]; float ss = 0.f;
    #pragma unroll
    for (int i = 0; i < 4; i++){
      qv[i] = qp[(size_t)(qoff + h*16 + lg*4 + i)*NQ + qb + qt*16 + lm];
      ss += qv[i]*qv[i];
    }
    ss += __shfl_xor(ss, 16); ss += __shfl_xor(ss, 32);
    float inv = scale / fmaxf(sqrtf(ss), 1e-12f);
    #pragma unroll
    for (int i = 0; i < 4; i++) qf[qt][i] = (f16)(qv[i]*inv);
  }
  f32x4 of[4];
  float ls[4];
  #pragma unroll
  for (int qt = 0; qt < 4; qt++){
    of[qt][0]=0.f; of[qt][1]=0.f; of[qt][2]=0.f; of[qt][3]=0.f; ls[qt]=0.f;
  }
  int chunk = NK >> 3;
  int p0 = wv*chunk, p1 = p0 + chunk;
  const float* kc = kvb + (size_t)(koff + h*16)*NK;
  const float* vc = kvb + (size_t)(voff + h*16)*NK;
  for (int pos = p0; pos < p1; pos += 16){
    f16x4 kf;
    #pragma unroll
    for (int i = 0; i < 4; i++)
      kf[i] = (f16)kc[(size_t)(lg*4 + i)*NK + pos + lm];
    float4 vvv = *(const float4*)&vc[(size_t)lm*NK + pos + lg*4];
    f16x4 vf; vf[0]=(f16)vvv.x; vf[1]=(f16)vvv.y; vf[2]=(f16)vvv.z; vf[3]=(f16)vvv.w;
    #pragma unroll
    for (int qt = 0; qt < 4; qt++){
      f32x4 s; s[0]=0.f; s[1]=0.f; s[2]=0.f; s[3]=0.f;
      s = __builtin_amdgcn_mfma_f32_16x16x16f16(kf, qf[qt], s, 0, 0, 0);
      f16x4 pf;
      #pragma unroll
      for (int r = 0; r < 4; r++){
        float pp = __expf(s[r]);
        ls[qt] += pp;
        pf[r] = (f16)pp;
      }
      of[qt] = __builtin_amdgcn_mfma_f32_16x16x16f16(vf, pf, of[qt], 0, 0, 0);
    }
  }
  #pragma unroll
  for (int qt = 0; qt < 4; qt++){
    ls[qt] += __shfl_xor(ls[qt], 16);
    ls[qt] += __shfl_xor(ls[qt], 32);
    #pragma unroll
    for (int r = 0; r < 4; r++)
      OS[((wv*4 + qt)*16 + lm)*17 + lg*4 + r] = of[qt][r];
    if (lg == 0) LS[(wv*4 + qt)*16 + lm] = ls[qt];
  }
  __syncthreads();
  #pragma unroll
  for (int rep = 0; rep < 2; rep++){
    int o = t + rep*512;
    int d = o >> 6, qq = o & 63;
    int qt = qq >> 4, q = qq & 15;
    float acc = 0.f, lsum = 0.f;
    #pragma unroll
    for (int w = 0; w < 8; w++){
      acc  += OS[((w*4 + qt)*16 + q)*17 + d];
      lsum += LS[(w*4 + qt)*16 + q];
    }
    Out[(size_t)bb*obs + (size_t)(h*16 + d)*NQ + qb + qq] = acc / fmaxf(lsum, 1e-30f);
  }
}

// ---------------- attn4, no-max (global attn NK=144 and xw attention NK=16) ----------------
__global__ __launch_bounds__(256) void attn4_k(
    const float* __restrict__ Q, long qbs, int qoff,
    const float* __restrict__ KV, long kbs, int koff, int voff,
    float* __restrict__ Out, long obs, int NQ, int NK, float scale)
{
  __shared__ __align__(16) float Ks[TK*KP];
  __shared__ __align__(16) float Vs[TK*KP];
  int tid = threadIdx.x;
  int sub = tid & 3;
  int h = blockIdx.y, bb = blockIdx.z;
  int qi = blockIdx.x*64 + (tid >> 2);
  bool qv = qi < NQ;
  float qn[4] = {0,0,0,0}, acc[4] = {0,0,0,0};
  float l = 0.f;
  if (qv){
    float s = 0.f;
    #pragma unroll
    for (int j = 0; j < 4; j++){
      qn[j] = Q[(size_t)bb*qbs + (size_t)(qoff + h*16 + sub*4 + j)*NQ + qi];
      s += qn[j]*qn[j];
    }
    s += __shfl_xor(s, 1); s += __shfl_xor(s, 2);
    float inv = scale / fmaxf(sqrtf(s), 1e-12f);
    #pragma unroll
    for (int j = 0; j < 4; j++) qn[j] *= inv;
  }
  for (int k0 = 0; k0 < NK; k0 += TK){
    int lim = min(TK, NK - k0);
    for (int i = tid; i < 16*TK; i += 256){
      int pos = i & (TK-1), d = i >> 7;
      if (pos < lim){
        Ks[pos*KP + d] = KV[(size_t)bb*kbs + (size_t)(koff + h*16 + d)*NK + k0 + pos];
        Vs[pos*KP + d] = KV[(size_t)bb*kbs + (size_t)(voff + h*16 + d)*NK + k0 + pos];
      }
    }
    __syncthreads();
    for (int pos = 0; pos < lim; pos++){
      float4 k4 = *(const float4*)&Ks[pos*KP + sub*4];
      float dd = qn[0]*k4.x + qn[1]*k4.y + qn[2]*k4.z + qn[3]*k4.w;
      dd += __shfl_xor(dd, 1); dd += __shfl_xor(dd, 2);
      float pp = __expf(dd);
      l += pp;
      float4 v4 = *(const float4*)&Vs[pos*KP + sub*4];
      acc[0] += pp*v4.x;
      acc[1] += pp*v4.y;
      acc[2] += pp*v4.z;
      acc[3] += pp*v4.w;
    }
    __syncthreads();
  }
  if (qv){
    float li = 1.f / fmaxf(l, 1e-30f);
    #pragma unroll
    for (int j = 0; j < 4; j++)
      Out[(size_t)bb*obs + (size_t)(h*16 + sub*4 + j)*NQ + qi] = acc[j]*li;
  }
}

// ---------------- latent-read attention, split-K partials ----------------
__global__ void latpart_k(const float* __restrict__ ql, const float* __restrict__ kvx,
                          long kbs, float* __restrict__ part, int NK, int S){
  int s = blockIdx.x, h = blockIdx.y, bb = blockIdx.z;
  int t = threadIdx.x;
  int q = t & 15, sub = (t >> 4) & 3;
  float qn[16]; float ss = 0.f;
  #pragma unroll
  for (int d = 0; d < 16; d++){
    qn[d] = ql[(size_t)bb*2048 + (size_t)(h*16+d)*16 + q];
    ss += qn[d]*qn[d];
  }
  float inv = 0.25f / fmaxf(sqrtf(ss), 1e-12f);
  #pragma unroll
  for (int d = 0; d < 16; d++) qn[d] *= inv;
  float l = 0.f, acc[16];
  #pragma unroll
  for (int d = 0; d < 16; d++) acc[d] = 0.f;
  int chunk = NK / S, c4 = chunk >> 2;
  int k0 = s*chunk + sub*c4, k1 = k0 + c4;
  const float* kb = kvx + (size_t)bb*kbs;
  for (int pos = k0; pos < k1; pos++){
    float dot = 0.f;
    #pragma unroll
    for (int d = 0; d < 16; d++) dot += qn[d]*kb[(size_t)(h*16+d)*NK + pos];
    float pp = __expf(dot);
    l += pp;
    #pragma unroll
    for (int d = 0; d < 16; d++)
      acc[d] += pp*kb[(size_t)(128 + h*16+d)*NK + pos];
  }
  l += __shfl_xor(l, 16); l += __shfl_xor(l, 32);
  #pragma unroll
  for (int d = 0; d < 16; d++){
    acc[d] += __shfl_xor(acc[d], 16);
    acc[d] += __shfl_xor(acc[d], 32);
  }
  if ((t >> 4) == 0){
    size_t idx = (size_t)((((bb*8 + h)*16 + q)*S) + s)*18;
    part[idx] = l;
    #pragma unroll
    for (int d = 0; d < 16; d++) part[idx+1+d] = acc[d];
  }
}

__global__ void latcomb_k(const float* __restrict__ part, float* __restrict__ latr, int S){
  int i = blockIdx.x*blockDim.x + threadIdx.x;   // 4096 total
  int d = i & 15, q = (i >> 4) & 15, h = (i >> 8) & 7, bb = i >> 11;
  size_t base = (size_t)(((bb*8 + h)*16 + q)*S)*18;
  float L = 0.f, a = 0.f;
  for (int s = 0; s < S; s++){
    const float* ps = part + base + (size_t)s*18;
    L += ps[0];
    a += ps[1+d];
  }
  latr[(size_t)bb*2048 + (size_t)(h*16+d)*16 + q] = a / fmaxf(L, 1e-30f);
}

extern "C" void kernel_launch(void* const* d_in, const int* in_sizes, int n_in,
                              void* d_out, int out_size, void* d_ws, size_t ws_size,
                              hipStream_t stream){
  const int B = 2, C = 128, HW = 2304;
  const void* x_in        = d_in[0];
  const void* g1          = d_in[1];
  const void* b1          = d_in[2];
  const void* loc_qkv_w   = d_in[3];
  const void* loc_proj_w  = d_in[4];
  const void* loc_proj_b  = d_in[5];
  const void* glob_qkv_w  = d_in[6];
  const void* glob_proj_w = d_in[7];
  const void* glob_proj_b = d_in[8];
  const void* fuse_w1     = d_in[9];
  const void* fuse_b1     = d_in[10];
  const void* fuse_w2     = d_in[11];
  const void* fuse_b2     = d_in[12];
  const void* glat        = d_in[13];
  const void* blat        = d_in[14];
  const void* latents     = d_in[15];
  const void* qlat_w      = d_in[16];
  const void* kvx_w       = d_in[17];
  const void* qx_w        = d_in[18];
  const void* kvlat_w     = d_in[19];
  const void* lat_proj_w  = d_in[20];
  const void* lat_proj_b  = d_in[21];
  const void* g2          = d_in[22];
  const void* b2          = d_in[23];
  const void* ffn_w1      = d_in[24];
  const void* ffn_b1      = d_in[25];
  const void* ffn_w2      = d_in[26];
  const void* ffn_b2      = d_in[27];

  // ---- workspace layout VERBATIM (R8..R18) ----
  float* ws = (float*)d_ws;
  float* P  = ws + 0;
  float* N  = ws + 589824;
  float* A  = ws + 1179648;
  float* Q  = ws + 1769472;
  float* FLAG = ws + 4128768;

  float* qkv   = Q;                 // 1,769,472
  float* L     = Q + 1769472;       // 589,824
  float* qkvc  = Q + 36864;
  float* gatt  = Q + 147456;
  float* gproj = Q + 184320;
  float* kvx   = Q;                 // 1,179,648
  float* qlat  = Q + 1181696;
  float* latr  = Q + 1185792;
  float* kvlat = Q + 1189888;
  float* part  = Q + 1198080;       // 221,184 (S=48)
  float* ffh   = Q;                 // 2,359,296

  dim3 blk(256);
  dim3 blk512(512);
  dim3 blk64(64);

  detect_k<<<1, 64, 0, stream>>>(x_in, FLAG);
  cvt_k<<<2304, blk, 0, stream>>>(x_in, P, 589824, FLAG);

  // ---- BioAttentionFusion branch ----
  ln2dw_k<<<dim3(144,B), blk, 0, stream>>>(P, g1, b1, N, C, HW, FLAG);
  convmfma_k<<<dim3(144,24,B), blk64, 0, stream>>>(N,(long)C*HW,C, nullptr,0,0, loc_qkv_w,nullptr,nullptr, qkv,0,384,HW,0, 128,256, 0,nullptr,nullptr, 0,0, FLAG);
  flat_mfma_k<<<dim3(36,8,B), blk512, 0, stream>>>(qkv,(long)384*HW,0, qkv,(long)384*HW,128,256, A,(long)C*HW, HW,HW,0.25f);
  convmfma_k<<<dim3(144,8,B), blk64, 0, stream>>>(A,(long)C*HW,C, nullptr,0,0, loc_proj_w,loc_proj_b,nullptr, L,0,C,HW,0, 0,0, 0,nullptr,nullptr, 0,0, FLAG);
  // pooled global qkv: pool4 + conv1x1 + normk fused (pool reads LN'd N; K heads unit-normed)
  convmfma_k<<<dim3(9,24,B), blk64, 0, stream>>>(N,(long)C*HW,C, nullptr,0,0, glob_qkv_w,nullptr,nullptr, qkvc,0,384,144,0, 128,256, 0,nullptr,nullptr, 1,0, FLAG);
  attn4_k<<<dim3(3,8,B), blk, 0, stream>>>(qkvc,(long)384*144,0, qkvc,(long)384*144,128,256, gatt,(long)C*144, 144,144,0.25f);
  convmfma_k<<<dim3(9,8,B), blk64, 0, stream>>>(gatt,(long)C*144,C, nullptr,0,0, glob_proj_w,glob_proj_b,nullptr, gproj,0,C,144,0, 0,0, 0,nullptr,nullptr, 0,0, FLAG);
  // fuse1: in2 = gproj with inline bilinear upsample (ups_k fused)
  convmfma_k<<<dim3(144,8,B), blk64, 0, stream>>>(L,(long)C*HW,C, gproj,(long)C*144,C, fuse_w1,fuse_b1,nullptr, N,0,C,HW,1, 0,0, 0,nullptr,nullptr, 0,1, FLAG);
  convmfma_k<<<dim3(144,8,B), blk64, 0, stream>>>(N,(long)C*HW,C, nullptr,0,0, fuse_w2,fuse_b2,P, P,0,C,HW,0, 0,0, 0,nullptr,nullptr, 0,0, FLAG);

  // ---- LatentMixer branch (LN fused into kvx/qx convs; no materialized N) ----
  convmfma_k<<<dim3(144,16,B), blk64, 0, stream>>>(P,(long)C*HW,C, nullptr,0,0, kvx_w,nullptr,nullptr, kvx,0,256,HW,0, 0,128, 1,glat,blat, 0,0, FLAG);
  convmfma_k<<<dim3(144,8,B), blk64, 0, stream>>>(P,(long)C*HW,C, nullptr,0,0, qx_w,nullptr,nullptr, A,0,C,HW,0, 0,0, 1,glat,blat, 0,0, FLAG);
  conv1x1_k<<<dim3(1,128,B), blk, 0, stream>>>((const float*)latents,0L,C, nullptr,0,0, qlat_w,nullptr,nullptr, qlat,0,C,16,0, 1, FLAG);
  latpart_k<<<dim3(48,8,B), 64, 0, stream>>>(qlat, kvx, (long)256*HW, part, HW, 48);
  latcomb_k<<<16, blk, 0, stream>>>(part, latr, 48);
  // kvlat conv + normk fused
  convmfma_k<<<dim3(1,16,B), blk64, 0, stream>>>(latr,(long)C*16,C, nullptr,0,0, kvlat_w,nullptr,nullptr, kvlat,0,256,16,0, 0,128, 0,nullptr,nullptr, 0,0, FLAG);
  attn4_k<<<dim3(36,8,B), blk, 0, stream>>>(A,(long)C*HW,0, kvlat,(long)256*16,0,128, N,(long)C*HW, HW,16,0.25f);           // N = xw
  convmfma_k<<<dim3(144,8,B), blk64, 0, stream>>>(N,(long)C*HW,C, nullptr,0,0, lat_proj_w,lat_proj_b,P, P,0,C,HW,0, 0,0, 0,nullptr,nullptr, 0,0, FLAG); // P = x2

  // ---- FFN branch (LN fused into ffn1) ----
  convmfma_k<<<dim3(144,32,B), blk64, 0, stream>>>(P,(long)C*HW,C, nullptr,0,0, ffn_w1,ffn_b1,nullptr, ffh,0,512,HW,1, 0,0, 1,g2,b2, 0,0, FLAG);
  convmfma_k<<<dim3(144,8,B), blk64, 0, stream>>>(ffh,(long)512*HW,512, nullptr,0,0, ffn_w2,ffn_b2,P, d_out,1,C,HW,0, 0,0, 0,nullptr,nullptr, 0,0, FLAG);
}

// Round 9
// 436.636 us; speedup vs baseline: 1.7264x; 1.0031x over previous
//
#include <hip/hip_runtime.h>
#include <hip/hip_bf16.h>

typedef __hip_bfloat16 bf16;
typedef _Float16 f16;
typedef _Float16 f16x4 __attribute__((ext_vector_type(4)));
typedef float f32x4 __attribute__((ext_vector_type(4)));

#define HD 16
#define TK 128
#define KP 20
#define MINIT (-1e30f)

__device__ __forceinline__ float b2f(bf16 v){ return __bfloat162float(v); }
__device__ __forceinline__ float gelu_f(float x){ return 0.5f*x*(1.0f+erff(x*0.70710678118654752f)); }
__device__ __forceinline__ float rdv(const void* p, size_t i, bool bf){
  return bf ? b2f(((const bf16*)p)[i]) : ((const float*)p)[i];
}
__device__ __forceinline__ float4 ld4f(const void* p, size_t i, bool bf){
  if (bf){
    const bf16* q = (const bf16*)p + i;
    return make_float4(b2f(q[0]), b2f(q[1]), b2f(q[2]), b2f(q[3]));
  }
  return *(const float4*)((const float*)p + i);
}

// ---------------- dtype detector (wave-parallel, proven R25) ----------------
__global__ void detect_k(const void* __restrict__ x, float* __restrict__ flag){
  if (blockIdx.x != 0) return;
  int l = threadIdx.x;
  const float* xf = (const float*)x;
  const bf16*  xb = (const bf16*)x;
  float sF = 0.f, sB = 0.f;
  for (int i = l; i < 512; i += 64){ float v = fabsf(xf[i]);      if (!(v < 1e30f)) v = 1e30f; sF += v; }
  for (int i = l; i < 1024; i += 64){ float v = fabsf(b2f(xb[i])); if (!(v < 1e30f)) v = 1e30f; sB += v; }
  #pragma unroll
  for (int o = 32; o; o >>= 1){ sF += __shfl_xor(sF, o); sB += __shfl_xor(sB, o); }
  if (l == 0){
    float mF = sF/512.f, mB = sB/1024.f;
    float dF = fabsf(logf(fmaxf(mF, 1e-30f)));
    float dB = fabsf(logf(fmaxf(mB, 1e-30f)));
    *flag = (dB <= dF) ? 1.0f : 0.0f;
  }
}

// ---------------- input -> fp32 convert (proven) ----------------
__global__ void cvt_k(const void* __restrict__ in, float* __restrict__ out, int n,
                      const float* __restrict__ flagp){
  bool bf = *flagp > 0.5f;
  int i = blockIdx.x*blockDim.x + threadIdx.x;
  if (i < n) out[i] = rdv(in, i, bf);
}

// ---------------- wave-split LayerNorm (proven; only branch1 needs materialized N) ----------------
__global__ __launch_bounds__(256) void ln2dw_k(
    const float* __restrict__ x, const void* __restrict__ g,
    const void* __restrict__ b, float* __restrict__ y,
    int C, int HW, const float* __restrict__ flagp)
{
  __shared__ float redS[16][16];
  __shared__ float redQ[16][16];
  bool bf = *flagp > 0.5f;
  int t = threadIdx.x, pix = t & 15, sub = t >> 4;
  int p  = blockIdx.x*16 + pix;
  int bb = blockIdx.y;
  const float* xb = x + (size_t)bb*C*HW + p;
  float xv[8];
  float s = 0.f, s2 = 0.f;
  #pragma unroll
  for (int i = 0; i < 8; i++){
    float v = xb[(size_t)(sub*8 + i)*HW];
    xv[i] = v; s += v; s2 += v*v;
  }
  redS[sub][pix] = s; redQ[sub][pix] = s2;
  __syncthreads();
  float st = 0.f, qt = 0.f;
  #pragma unroll
  for (int j = 0; j < 16; j++){ st += redS[j][pix]; qt += redQ[j][pix]; }
  float mu  = st / (float)C;
  float var = fmaxf(qt / (float)C - mu*mu, 0.f);
  float inv = rsqrtf(var + 1e-5f);
  float* yb = y + (size_t)bb*C*HW + p;
  #pragma unroll
  for (int i = 0; i < 8; i++){
    int c = sub*8 + i;
    yb[(size_t)c*HW] = (xv[i] - mu)*inv*rdv(g, c, bf) + rdv(b, c, bf);
  }
}

// ---------------- generic scalar 1x1 conv (qlat only: raw latents, NP=16) ----------------
__global__ void conv1x1_k(const float* __restrict__ in1, long in1_bs, int C1,
                          const float* __restrict__ in2, long in2_bs, int C2,
                          const void* __restrict__ w, const void* __restrict__ bias,
                          const float* __restrict__ res,
                          void* __restrict__ out, int to_out, int O, int NP, int act,
                          int raw1, const float* __restrict__ flagp){
  bool bf = *flagp > 0.5f;
  int p = blockIdx.x*blockDim.x + threadIdx.x;
  if (p >= NP) return;
  int o = blockIdx.y, bb = blockIdx.z;
  size_t wrow = (size_t)o*(C1 + C2);
  float acc = bias ? rdv(bias, o, bf) : 0.f;
  if (raw1){
    for (int c = 0; c < C1; c++)
      acc += rdv(w, wrow + c, bf) * rdv(in1, (size_t)bb*in1_bs + (size_t)c*NP + p, bf);
  } else {
    const float* i1 = in1 + (size_t)bb*in1_bs + p;
    for (int c = 0; c < C1; c++) acc += rdv(w, wrow + c, bf) * i1[(size_t)c*NP];
  }
  if (in2){
    const float* i2 = in2 + (size_t)bb*in2_bs + p;
    for (int c = 0; c < C2; c++) acc += rdv(w, wrow + C1 + c, bf) * i2[(size_t)c*NP];
  }
  if (act == 1) acc = gelu_f(acc);
  if (res) acc += res[((size_t)bb*O + o)*NP + p];
  size_t oi = ((size_t)bb*O + o)*NP + p;
  if (to_out){
    if (bf) ((bf16*)out)[oi] = __float2bfloat16(acc);
    else    ((float*)out)[oi] = acc;
  } else {
    ((float*)out)[oi] = acc;
  }
}

// ---------------- MFMA 1x1-conv GEMM (R27: 4 waves/block, 16o x 16p per wave) ----------------
// R8 counters: 1-wave (64-thr) workgroups cap at ~16 blocks/CU -> 16 waves/CU = the measured
// 50% occupancy; latency-bound convs had only 4 waves/SIMD to hide L2 chains. R27 packs 4
// INDEPENDENT wave-tiles per 256-thr block (no LDS, no barriers): wave wv owns o-tile
// o0 = blockIdx.y*64 + wv*16. Same total waves, 2x resident waves (32/CU cap), waves in a
// block share the X pixel-column (L1 locality). Grid (NP/16, O/64, B); O % 64 == 0.
// Flags (proven R25/R26): nlo/nhi fused head unit-norm; lnf inline LayerNorm; pool 4x4 mean
// input; ups2 bilinear in2. f32 accumulate.
__global__ __launch_bounds__(256) void convmfma_k(
    const float* __restrict__ in1, long in1_bs, int C1,
    const float* __restrict__ in2, long in2_bs, int C2,
    const void* __restrict__ w, const void* __restrict__ bias,
    const float* __restrict__ res, void* __restrict__ out, int to_out,
    int O, int NP, int act, int nlo, int nhi,
    int lnf, const void* __restrict__ lng, const void* __restrict__ lnb,
    int pool, int ups2, const float* __restrict__ flagp)
{
  bool bf = *flagp > 0.5f;
  int lane = threadIdx.x & 63, wv = threadIdx.x >> 6;
  int lm = lane & 15, lg = (lane >> 4) & 3;
  int p0 = blockIdx.x*16, o0 = blockIdx.y*64 + wv*16, bb = blockIdx.z;
  int CW = C1 + C2;
  const float* x1 = in1 + (size_t)bb*in1_bs + p0 + lm;
  const float* x2b = in2 ? (in2 + (size_t)bb*in2_bs) : nullptr;
  // ups2 per-lane bilinear constants
  float fh = 0.f, fw = 0.f; int i00=0, i01=0, i10=0, i11=0;
  if (ups2){
    int p = p0 + lm; int hh = p/48, ww = p%48;
    float sh = hh*0.25f - 0.375f, sw = ww*0.25f - 0.375f;
    float fh0 = floorf(sh), fw0 = floorf(sw);
    fh = sh - fh0; fw = sw - fw0;
    int h0 = (int)fh0, w0 = (int)fw0;
    int h0c = min(11, max(0, h0)), h1c = min(11, max(0, h0+1));
    int w0c = min(11, max(0, w0)), w1c = min(11, max(0, w0+1));
    i00 = h0c*12 + w0c; i01 = h0c*12 + w1c; i10 = h1c*12 + w0c; i11 = h1c*12 + w1c;
  }
  // pool per-lane fine base
  const float* pN = nullptr;
  if (pool){
    int pc = p0 + lm; int hc = pc/12, wc = pc%12;
    pN = in1 + (size_t)bb*in1_bs + hc*192 + wc*4;
  }
  // inline LayerNorm stats (pixel = lm; lg groups cover c = lg, lg+4, ...)
  float mu = 0.f, linv = 0.f;
  if (lnf){
    float s = 0.f, s2 = 0.f;
    for (int c = lg; c < CW; c += 4){ float v = x1[(size_t)c*NP]; s += v; s2 += v*v; }
    s  += __shfl_xor(s, 16);  s  += __shfl_xor(s, 32);
    s2 += __shfl_xor(s2, 16); s2 += __shfl_xor(s2, 32);
    mu = s / (float)CW;
    float var = fmaxf(s2/(float)CW - mu*mu, 0.f);
    linv = rsqrtf(var + 1e-5f);
  }
  f32x4 d; d[0]=0.f; d[1]=0.f; d[2]=0.f; d[3]=0.f;
  #pragma unroll 4
  for (int kc = 0; kc < CW; kc += 16){
    f16x4 xb;
    #pragma unroll
    for (int i = 0; i < 4; i++){
      int c = kc + lg*4 + i;
      float v;
      if (pool){
        const float* s = pN + (size_t)c*2304;
        float a = 0.f;
        #pragma unroll
        for (int r = 0; r < 4; r++)
          #pragma unroll
          for (int cc = 0; cc < 4; cc++) a += s[r*48 + cc];
        v = a * 0.0625f;
      } else if (c < C1){
        v = x1[(size_t)c*NP];
        if (lnf) v = (v - mu)*linv*rdv(lng, c, bf) + rdv(lnb, c, bf);
      } else {
        int c2 = c - C1;
        if (ups2){
          const float* s = x2b + (size_t)c2*144;
          v = (1.f-fh)*((1.f-fw)*s[i00] + fw*s[i01]) + fh*((1.f-fw)*s[i10] + fw*s[i11]);
        } else {
          v = x2b[(size_t)c2*NP + p0 + lm];
        }
      }
      xb[i] = (f16)v;
    }
    float4 wv4 = ld4f(w, (size_t)(o0 + lm)*CW + kc + lg*4, bf);
    f16x4 wa; wa[0]=(f16)wv4.x; wa[1]=(f16)wv4.y; wa[2]=(f16)wv4.z; wa[3]=(f16)wv4.w;
    d = __builtin_amdgcn_mfma_f32_16x16x16f16(wa, xb, d, 0, 0, 0);
  }
  if (o0 >= nlo && o0 < nhi){
    float ss = d[0]*d[0] + d[1]*d[1] + d[2]*d[2] + d[3]*d[3];
    ss += __shfl_xor(ss, 16); ss += __shfl_xor(ss, 32);
    float iv = 1.f / fmaxf(sqrtf(ss), 1e-12f);
    d[0]*=iv; d[1]*=iv; d[2]*=iv; d[3]*=iv;
  }
  #pragma unroll
  for (int r = 0; r < 4; r++){
    int o = o0 + lg*4 + r;
    float v = d[r] + (bias ? rdv(bias, o, bf) : 0.f);
    if (act == 1) v = gelu_f(v);
    size_t oi = ((size_t)bb*O + o)*NP + p0 + lm;
    if (res) v += res[oi];
    if (to_out && bf) ((bf16*)out)[oi] = __float2bfloat16(v);
    else              ((float*)out)[oi] = v;
  }
}

// ---------------- MFMA flash cosine attention (local attn, d=16; proven R22) ----------------
__global__ __launch_bounds__(512) void flat_mfma_k(
    const float* __restrict__ Q, long qbs, int qoff,
    const float* __restrict__ KV, long kbs, int koff, int voff,
    float* __restrict__ Out, long obs, int NQ, int NK, float scale)
{
  __shared__ float OS[8*4*16*17];
  __shared__ float LS[8*4*16];
  int t = threadIdx.x, lane = t & 63, wv = t >> 6;
  int h = blockIdx.y, bb = blockIdx.z;
  int qb = blockIdx.x*64;
  int lm = lane & 15, lg = lane >> 4;
  const float* qp  = Q  + (size_t)bb*qbs;
  const float* kvb = KV + (size_t)bb*kbs;
  f16x4 qf[4];
  #pragma unroll
  for (int qt = 0; qt < 4; qt++){
    float qv[4]; float ss = 0.f;
    #pragma unroll
    for (int i = 0; i < 4; i++){
      qv[i] = qp[(size_t)(qoff + h*16 + lg*4 + i)*NQ + qb + qt*16 + lm];
      ss += qv[i]*qv[i];
    }
    ss += __shfl_xor(ss, 16); ss += __shfl_xor(ss, 32);
    float inv = scale / fmaxf(sqrtf(ss), 1e-12f);
    #pragma unroll
    for (int i = 0; i < 4; i++) qf[qt][i] = (f16)(qv[i]*inv);
  }
  f32x4 of[4];
  float ls[4];
  #pragma unroll
  for (int qt = 0; qt < 4; qt++){
    of[qt][0]=0.f; of[qt][1]=0.f; of[qt][2]=0.f; of[qt][3]=0.f; ls[qt]=0.f;
  }
  int chunk = NK >> 3;
  int p0 = wv*chunk, p1 = p0 + chunk;
  const float* kc = kvb + (size_t)(koff + h*16)*NK;
  const float* vc = kvb + (size_t)(voff + h*16)*NK;
  for (int pos = p0; pos < p1; pos += 16){
    f16x4 kf;
    #pragma unroll
    for (int i = 0; i < 4; i++)
      kf[i] = (f16)kc[(size_t)(lg*4 + i)*NK + pos + lm];
    float4 vvv = *(const float4*)&vc[(size_t)lm*NK + pos + lg*4];
    f16x4 vf; vf[0]=(f16)vvv.x; vf[1]=(f16)vvv.y; vf[2]=(f16)vvv.z; vf[3]=(f16)vvv.w;
    #pragma unroll
    for (int qt = 0; qt < 4; qt++){
      f32x4 s; s[0]=0.f; s[1]=0.f; s[2]=0.f; s[3]=0.f;
      s = __builtin_amdgcn_mfma_f32_16x16x16f16(kf, qf[qt], s, 0, 0, 0);
      f16x4 pf;
      #pragma unroll
      for (int r = 0; r < 4; r++){
        float pp = __expf(s[r]);
        ls[qt] += pp;
        pf[r] = (f16)pp;
      }
      of[qt] = __builtin_amdgcn_mfma_f32_16x16x16f16(vf, pf, of[qt], 0, 0, 0);
    }
  }
  #pragma unroll
  for (int qt = 0; qt < 4; qt++){
    ls[qt] += __shfl_xor(ls[qt], 16);
    ls[qt] += __shfl_xor(ls[qt], 32);
    #pragma unroll
    for (int r = 0; r < 4; r++)
      OS[((wv*4 + qt)*16 + lm)*17 + lg*4 + r] = of[qt][r];
    if (lg == 0) LS[(wv*4 + qt)*16 + lm] = ls[qt];
  }
  __syncthreads();
  #pragma unroll
  for (int rep = 0; rep < 2; rep++){
    int o = t + rep*512;
    int d = o >> 6, qq = o & 63;
    int qt = qq >> 4, q = qq & 15;
    float acc = 0.f, lsum = 0.f;
    #pragma unroll
    for (int w = 0; w < 8; w++){
      acc  += OS[((w*4 + qt)*16 + q)*17 + d];
      lsum += LS[(w*4 + qt)*16 + q];
    }
    Out[(size_t)bb*obs + (size_t)(h*16 + d)*NQ + qb + qq] = acc / fmaxf(lsum, 1e-30f);
  }
}

// ---------------- attn4, no-max (global attn NK=144 and xw attention NK=16) ----------------
__global__ __launch_bounds__(256) void attn4_k(
    const float* __restrict__ Q, long qbs, int qoff,
    const float* __restrict__ KV, long kbs, int koff, int voff,
    float* __restrict__ Out, long obs, int NQ, int NK, float scale)
{
  __shared__ __align__(16) float Ks[TK*KP];
  __shared__ __align__(16) float Vs[TK*KP];
  int tid = threadIdx.x;
  int sub = tid & 3;
  int h = blockIdx.y, bb = blockIdx.z;
  int qi = blockIdx.x*64 + (tid >> 2);
  bool qv = qi < NQ;
  float qn[4] = {0,0,0,0}, acc[4] = {0,0,0,0};
  float l = 0.f;
  if (qv){
    float s = 0.f;
    #pragma unroll
    for (int j = 0; j < 4; j++){
      qn[j] = Q[(size_t)bb*qbs + (size_t)(qoff + h*16 + sub*4 + j)*NQ + qi];
      s += qn[j]*qn[j];
    }
    s += __shfl_xor(s, 1); s += __shfl_xor(s, 2);
    float inv = scale / fmaxf(sqrtf(s), 1e-12f);
    #pragma unroll
    for (int j = 0; j < 4; j++) qn[j] *= inv;
  }
  for (int k0 = 0; k0 < NK; k0 += TK){
    int lim = min(TK, NK - k0);
    for (int i = tid; i < 16*TK; i += 256){
      int pos = i & (TK-1), d = i >> 7;
      if (pos < lim){
        Ks[pos*KP + d] = KV[(size_t)bb*kbs + (size_t)(koff + h*16 + d)*NK + k0 + pos];
        Vs[pos*KP + d] = KV[(size_t)bb*kbs + (size_t)(voff + h*16 + d)*NK + k0 + pos];
      }
    }
    __syncthreads();
    for (int pos = 0; pos < lim; pos++){
      float4 k4 = *(const float4*)&Ks[pos*KP + sub*4];
      float dd = qn[0]*k4.x + qn[1]*k4.y + qn[2]*k4.z + qn[3]*k4.w;
      dd += __shfl_xor(dd, 1); dd += __shfl_xor(dd, 2);
      float pp = __expf(dd);
      l += pp;
      float4 v4 = *(const float4*)&Vs[pos*KP + sub*4];
      acc[0] += pp*v4.x;
      acc[1] += pp*v4.y;
      acc[2] += pp*v4.z;
      acc[3] += pp*v4.w;
    }
    __syncthreads();
  }
  if (qv){
    float li = 1.f / fmaxf(l, 1e-30f);
    #pragma unroll
    for (int j = 0; j < 4; j++)
      Out[(size_t)bb*obs + (size_t)(h*16 + sub*4 + j)*NQ + qi] = acc[j]*li;
  }
}

// ---------------- latent-read attention, split-K partials ----------------
__global__ void latpart_k(const float* __restrict__ ql, const float* __restrict__ kvx,
                          long kbs, float* __restrict__ part, int NK, int S){
  int s = blockIdx.x, h = blockIdx.y, bb = blockIdx.z;
  int t = threadIdx.x;
  int q = t & 15, sub = (t >> 4) & 3;
  float qn[16]; float ss = 0.f;
  #pragma unroll
  for (int d = 0; d < 16; d++){
    qn[d] = ql[(size_t)bb*2048 + (size_t)(h*16+d)*16 + q];
    ss += qn[d]*qn[d];
  }
  float inv = 0.25f / fmaxf(sqrtf(ss), 1e-12f);
  #pragma unroll
  for (int d = 0; d < 16; d++) qn[d] *= inv;
  float l = 0.f, acc[16];
  #pragma unroll
  for (int d = 0; d < 16; d++) acc[d] = 0.f;
  int chunk = NK / S, c4 = chunk >> 2;
  int k0 = s*chunk + sub*c4, k1 = k0 + c4;
  const float* kb = kvx + (size_t)bb*kbs;
  for (int pos = k0; pos < k1; pos++){
    float dot = 0.f;
    #pragma unroll
    for (int d = 0; d < 16; d++) dot += qn[d]*kb[(size_t)(h*16+d)*NK + pos];
    float pp = __expf(dot);
    l += pp;
    #pragma unroll
    for (int d = 0; d < 16; d++)
      acc[d] += pp*kb[(size_t)(128 + h*16+d)*NK + pos];
  }
  l += __shfl_xor(l, 16); l += __shfl_xor(l, 32);
  #pragma unroll
  for (int d = 0; d < 16; d++){
    acc[d] += __shfl_xor(acc[d], 16);
    acc[d] += __shfl_xor(acc[d], 32);
  }
  if ((t >> 4) == 0){
    size_t idx = (size_t)((((bb*8 + h)*16 + q)*S) + s)*18;
    part[idx] = l;
    #pragma unroll
    for (int d = 0; d < 16; d++) part[idx+1+d] = acc[d];
  }
}

__global__ void latcomb_k(const float* __restrict__ part, float* __restrict__ latr, int S){
  int i = blockIdx.x*blockDim.x + threadIdx.x;   // 4096 total
  int d = i & 15, q = (i >> 4) & 15, h = (i >> 8) & 7, bb = i >> 11;
  size_t base = (size_t)(((bb*8 + h)*16 + q)*S)*18;
  float L = 0.f, a = 0.f;
  for (int s = 0; s < S; s++){
    const float* ps = part + base + (size_t)s*18;
    L += ps[0];
    a += ps[1+d];
  }
  latr[(size_t)bb*2048 + (size_t)(h*16+d)*16 + q] = a / fmaxf(L, 1e-30f);
}

extern "C" void kernel_launch(void* const* d_in, const int* in_sizes, int n_in,
                              void* d_out, int out_size, void* d_ws, size_t ws_size,
                              hipStream_t stream){
  const int B = 2, C = 128, HW = 2304;
  const void* x_in        = d_in[0];
  const void* g1          = d_in[1];
  const void* b1          = d_in[2];
  const void* loc_qkv_w   = d_in[3];
  const void* loc_proj_w  = d_in[4];
  const void* loc_proj_b  = d_in[5];
  const void* glob_qkv_w  = d_in[6];
  const void* glob_proj_w = d_in[7];
  const void* glob_proj_b = d_in[8];
  const void* fuse_w1     = d_in[9];
  const void* fuse_b1     = d_in[10];
  const void* fuse_w2     = d_in[11];
  const void* fuse_b2     = d_in[12];
  const void* glat        = d_in[13];
  const void* blat        = d_in[14];
  const void* latents     = d_in[15];
  const void* qlat_w      = d_in[16];
  const void* kvx_w       = d_in[17];
  const void* qx_w        = d_in[18];
  const void* kvlat_w     = d_in[19];
  const void* lat_proj_w  = d_in[20];
  const void* lat_proj_b  = d_in[21];
  const void* g2          = d_in[22];
  const void* b2          = d_in[23];
  const void* ffn_w1      = d_in[24];
  const void* ffn_b1      = d_in[25];
  const void* ffn_w2      = d_in[26];
  const void* ffn_b2      = d_in[27];

  // ---- workspace layout VERBATIM (R8..R18) ----
  float* ws = (float*)d_ws;
  float* P  = ws + 0;
  float* N  = ws + 589824;
  float* A  = ws + 1179648;
  float* Q  = ws + 1769472;
  float* FLAG = ws + 4128768;

  float* qkv   = Q;                 // 1,769,472
  float* L     = Q + 1769472;       // 589,824
  float* qkvc  = Q + 36864;
  float* gatt  = Q + 147456;
  float* gproj = Q + 184320;
  float* kvx   = Q;                 // 1,179,648
  float* qlat  = Q + 1181696;
  float* latr  = Q + 1185792;
  float* kvlat = Q + 1189888;
  float* part  = Q + 1198080;       // 221,184 (S=48)
  float* ffh   = Q;                 // 2,359,296

  dim3 blk(256);
  dim3 blk512(512);

  detect_k<<<1, 64, 0, stream>>>(x_in, FLAG);
  cvt_k<<<2304, blk, 0, stream>>>(x_in, P, 589824, FLAG);

  // ---- BioAttentionFusion branch ----
  ln2dw_k<<<dim3(144,B), blk, 0, stream>>>(P, g1, b1, N, C, HW, FLAG);
  convmfma_k<<<dim3(144,6,B), blk, 0, stream>>>(N,(long)C*HW,C, nullptr,0,0, loc_qkv_w,nullptr,nullptr, qkv,0,384,HW,0, 128,256, 0,nullptr,nullptr, 0,0, FLAG);
  flat_mfma_k<<<dim3(36,8,B), blk512, 0, stream>>>(qkv,(long)384*HW,0, qkv,(long)384*HW,128,256, A,(long)C*HW, HW,HW,0.25f);
  convmfma_k<<<dim3(144,2,B), blk, 0, stream>>>(A,(long)C*HW,C, nullptr,0,0, loc_proj_w,loc_proj_b,nullptr, L,0,C,HW,0, 0,0, 0,nullptr,nullptr, 0,0, FLAG);
  // pooled global qkv: pool4 + conv1x1 + normk fused (pool reads LN'd N; K heads unit-normed)
  convmfma_k<<<dim3(9,6,B), blk, 0, stream>>>(N,(long)C*HW,C, nullptr,0,0, glob_qkv_w,nullptr,nullptr, qkvc,0,384,144,0, 128,256, 0,nullptr,nullptr, 1,0, FLAG);
  attn4_k<<<dim3(3,8,B), blk, 0, stream>>>(qkvc,(long)384*144,0, qkvc,(long)384*144,128,256, gatt,(long)C*144, 144,144,0.25f);
  convmfma_k<<<dim3(9,2,B), blk, 0, stream>>>(gatt,(long)C*144,C, nullptr,0,0, glob_proj_w,glob_proj_b,nullptr, gproj,0,C,144,0, 0,0, 0,nullptr,nullptr, 0,0, FLAG);
  // fuse1: in2 = gproj with inline bilinear upsample (ups_k fused)
  convmfma_k<<<dim3(144,2,B), blk, 0, stream>>>(L,(long)C*HW,C, gproj,(long)C*144,C, fuse_w1,fuse_b1,nullptr, N,0,C,HW,1, 0,0, 0,nullptr,nullptr, 0,1, FLAG);
  convmfma_k<<<dim3(144,2,B), blk, 0, stream>>>(N,(long)C*HW,C, nullptr,0,0, fuse_w2,fuse_b2,P, P,0,C,HW,0, 0,0, 0,nullptr,nullptr, 0,0, FLAG);

  // ---- LatentMixer branch (LN fused into kvx/qx convs; no materialized N) ----
  convmfma_k<<<dim3(144,4,B), blk, 0, stream>>>(P,(long)C*HW,C, nullptr,0,0, kvx_w,nullptr,nullptr, kvx,0,256,HW,0, 0,128, 1,glat,blat, 0,0, FLAG);
  convmfma_k<<<dim3(144,2,B), blk, 0, stream>>>(P,(long)C*HW,C, nullptr,0,0, qx_w,nullptr,nullptr, A,0,C,HW,0, 0,0, 1,glat,blat, 0,0, FLAG);
  conv1x1_k<<<dim3(1,128,B), blk, 0, stream>>>((const float*)latents,0L,C, nullptr,0,0, qlat_w,nullptr,nullptr, qlat,0,C,16,0, 1, FLAG);
  latpart_k<<<dim3(48,8,B), 64, 0, stream>>>(qlat, kvx, (long)256*HW, part, HW, 48);
  latcomb_k<<<16, blk, 0, stream>>>(part, latr, 48);
  // kvlat conv + normk fused
  convmfma_k<<<dim3(1,4,B), blk, 0, stream>>>(latr,(long)C*16,C, nullptr,0,0, kvlat_w,nullptr,nullptr, kvlat,0,256,16,0, 0,128, 0,nullptr,nullptr, 0,0, FLAG);
  attn4_k<<<dim3(36,8,B), blk, 0, stream>>>(A,(long)C*HW,0, kvlat,(long)256*16,0,128, N,(long)C*HW, HW,16,0.25f);           // N = xw
  convmfma_k<<<dim3(144,2,B), blk, 0, stream>>>(N,(long)C*HW,C, nullptr,0,0, lat_proj_w,lat_proj_b,P, P,0,C,HW,0, 0,0, 0,nullptr,nullptr, 0,0, FLAG); // P = x2

  // ---- FFN branch (LN fused into ffn1) ----
  convmfma_k<<<dim3(144,8,B), blk, 0, stream>>>(P,(long)C*HW,C, nullptr,0,0, ffn_w1,ffn_b1,nullptr, ffh,0,512,HW,1, 0,0, 1,g2,b2, 0,0, FLAG);
  convmfma_k<<<dim3(144,2,B), blk, 0, stream>>>(ffh,(long)512*HW,512, nullptr,0,0, ffn_w2,ffn_b2,P, d_out,1,C,HW,0, 0,0, 0,nullptr,nullptr, 0,0, FLAG);
}